// Round 3
// baseline (443.144 us; speedup 1.0000x reference)
//
#include <hip/hip_runtime.h>
#include <hip/hip_bf16.h>

#define BB 32
#define SS 1024
#define HHH 768
#define EE 128
#define WW 8
#define PP 512
#define ND1 128
#define NH1 2
#define ND2 64
#define RDD 32

// ---------------------------------------------------------------------------
// K1: window gather + mean-query attention pooling + type embedding
// grid = B*E blocks, 256 threads. Inputs fp32.
// ---------------------------------------------------------------------------
__global__ __launch_bounds__(256) void pool_kernel(
    const float* __restrict__ seq, const int* __restrict__ starts,
    const int* __restrict__ types, const float* __restrict__ temb,
    float* __restrict__ xout) {
    int be = blockIdx.x;
    int b = be >> 7;
    int tid = threadIdx.x;
    __shared__ float toks[WW][HHH];
    __shared__ float scred[WW];
    __shared__ float attn_s[WW];

    int start = starts[be];
    const float* basep = seq + ((size_t)b * SS + start) * HHH;
    for (int idx = tid; idx < WW * HHH; idx += 256) {
        int w = idx / HHH, h = idx % HHH;
        toks[w][h] = basep[(size_t)w * HHH + h];
    }
    __syncthreads();

    // each thread owns 3 columns h = tid + 256*c
    float sc[WW];
#pragma unroll
    for (int w = 0; w < WW; w++) sc[w] = 0.f;
#pragma unroll
    for (int c = 0; c < 3; c++) {
        int h = tid + 256 * c;
        float s = 0.f;
#pragma unroll
        for (int w = 0; w < WW; w++) s += toks[w][h];
        float m = s * (1.0f / WW);
#pragma unroll
        for (int w = 0; w < WW; w++) sc[w] += toks[w][h] * m;
    }
    if (tid < WW) scred[tid] = 0.f;
    __syncthreads();
    int lane = tid & 63;
#pragma unroll
    for (int w = 0; w < WW; w++) {
        float v = sc[w];
        for (int o = 32; o > 0; o >>= 1) v += __shfl_down(v, o, 64);
        if (lane == 0) atomicAdd(&scred[w], v);
    }
    __syncthreads();
    if (tid == 0) {
        float mx = scred[0];
        for (int w = 1; w < WW; w++) mx = fmaxf(mx, scred[w]);
        float ssum = 0.f;
        float a[WW];
        for (int w = 0; w < WW; w++) { a[w] = __expf(scred[w] - mx); ssum += a[w]; }
        float inv = 1.f / ssum;
        for (int w = 0; w < WW; w++) attn_s[w] = a[w] * inv;
    }
    __syncthreads();

    int t = types[be];
    const float* emb = temb + (size_t)t * HHH;
#pragma unroll
    for (int c = 0; c < 3; c++) {
        int h = tid + 256 * c;
        float p = 0.f;
#pragma unroll
        for (int w = 0; w < WW; w++) p += attn_s[w] * toks[w][h];
        xout[(size_t)be * HHH + h] = p + emb[h];
    }
}

// ---------------------------------------------------------------------------
// K2: GEMM1  x(4096x768) @ W1(768x256) -> h1(4096x256), all fp32
// 64x64 tile, 256 threads, 4x4 per thread
// ---------------------------------------------------------------------------
__global__ __launch_bounds__(256) void gemm1_kernel(
    const float* __restrict__ A, const float* __restrict__ Bw,
    float* __restrict__ C) {
    const int K = HHH, N = NH1 * ND1;
    __shared__ float As[16][64 + 1];  // [k][m]
    __shared__ float Bs[16][64 + 1];  // [k][n]
    int tx = threadIdx.x & 15, ty = threadIdx.x >> 4;
    int m0 = blockIdx.y * 64, n0 = blockIdx.x * 64;
    float acc[4][4] = {};

    for (int k0 = 0; k0 < K; k0 += 16) {
        {
            int idx = threadIdx.x * 4;
            int m = idx >> 4;
            int k = idx & 15;
            float4 v = *(const float4*)(A + (size_t)(m0 + m) * K + k0 + k);
            As[k + 0][m] = v.x; As[k + 1][m] = v.y;
            As[k + 2][m] = v.z; As[k + 3][m] = v.w;
        }
        {
            int idx = threadIdx.x * 4;
            int k = idx >> 6;
            int n = idx & 63;
            float4 v = *(const float4*)(Bw + (size_t)(k0 + k) * N + n0 + n);
            Bs[k][n + 0] = v.x; Bs[k][n + 1] = v.y;
            Bs[k][n + 2] = v.z; Bs[k][n + 3] = v.w;
        }
        __syncthreads();
#pragma unroll
        for (int k = 0; k < 16; k++) {
            float a[4], bv[4];
#pragma unroll
            for (int i = 0; i < 4; i++) a[i] = As[k][ty * 4 + i];
#pragma unroll
            for (int j = 0; j < 4; j++) bv[j] = Bs[k][tx * 4 + j];
#pragma unroll
            for (int i = 0; i < 4; i++)
#pragma unroll
                for (int j = 0; j < 4; j++) acc[i][j] += a[i] * bv[j];
        }
        __syncthreads();
    }
#pragma unroll
    for (int i = 0; i < 4; i++)
#pragma unroll
        for (int j = 0; j < 4; j++)
            C[(size_t)(m0 + ty * 4 + i) * N + n0 + tx * 4 + j] = acc[i][j];
}

// ---------------------------------------------------------------------------
// K3: per-(b,e,head) attention src/dst dots over D1=128
// grid = B*E*2 blocks of 64 threads
// ---------------------------------------------------------------------------
__global__ void sd1_kernel(const float* __restrict__ h1, const float* __restrict__ asrc,
                           const float* __restrict__ adst, float* __restrict__ s1,
                           float* __restrict__ d1) {
    int beh = blockIdx.x;
    int h = beh & 1;
    int be = beh >> 1;
    int lane = threadIdx.x;
    const float* row = h1 + (size_t)be * 256 + h * 128;
    float v0 = row[lane], v1 = row[lane + 64];
    float ss = v0 * asrc[h * 128 + lane] + v1 * asrc[h * 128 + lane + 64];
    float dd = v0 * adst[h * 128 + lane] + v1 * adst[h * 128 + lane + 64];
    for (int o = 32; o > 0; o >>= 1) {
        ss += __shfl_down(ss, o, 64);
        dd += __shfl_down(dd, o, 64);
    }
    if (lane == 0) { s1[beh] = ss; d1[beh] = dd; }
}

// ---------------------------------------------------------------------------
// K4: GAT1 attention: softmax over j (128) + matvec -> g1 pre-LN
// grid = B*E*2 blocks, 128 threads
// ---------------------------------------------------------------------------
__global__ __launch_bounds__(128) void gat1_attn_kernel(
    const float* __restrict__ h1, const float* __restrict__ s1,
    const float* __restrict__ d1, const float* __restrict__ b1,
    float* __restrict__ g1) {
    int id = blockIdx.x;
    int h = id & 1;
    int bi = id >> 1;
    int b = bi >> 7;
    int tid = threadIdx.x;
    __shared__ float alpha[128];
    __shared__ float red[2];

    float di = d1[bi * 2 + h];
    float sj = s1[((size_t)b * 128 + tid) * 2 + h];
    float ev = di + sj;
    ev = ev >= 0.f ? ev : 0.2f * ev;

    float mx = ev;
    for (int o = 32; o > 0; o >>= 1) mx = fmaxf(mx, __shfl_down(mx, o, 64));
    int lane = tid & 63, wid = tid >> 6;
    if (lane == 0) red[wid] = mx;
    __syncthreads();
    mx = fmaxf(red[0], red[1]);
    __syncthreads();
    float ex = __expf(ev - mx);
    float sm = ex;
    for (int o = 32; o > 0; o >>= 1) sm += __shfl_down(sm, o, 64);
    if (lane == 0) red[wid] = sm;
    __syncthreads();
    sm = red[0] + red[1];
    alpha[tid] = ex / sm;
    __syncthreads();

    const float* hb = h1 + (size_t)b * 128 * 256 + h * 128 + tid;
    float o = 0.f;
#pragma unroll 8
    for (int j = 0; j < 128; j++) o += alpha[j] * hb[(size_t)j * 256];
    g1[(size_t)bi * 256 + h * 128 + tid] = o + b1[h * 128 + tid];
}

// ---------------------------------------------------------------------------
// K5: LayerNorm(256) + ELU in place
// ---------------------------------------------------------------------------
__global__ __launch_bounds__(256) void ln_elu256_kernel(
    float* __restrict__ g1, const float* __restrict__ gamma,
    const float* __restrict__ beta) {
    int row = blockIdx.x;
    int tid = threadIdx.x;
    __shared__ float red[4];
    float v = g1[(size_t)row * 256 + tid];
    float s = v;
    for (int o = 32; o > 0; o >>= 1) s += __shfl_down(s, o, 64);
    int lane = tid & 63, wid = tid >> 6;
    if (lane == 0) red[wid] = s;
    __syncthreads();
    float mean = (red[0] + red[1] + red[2] + red[3]) * (1.f / 256.f);
    __syncthreads();
    float dv = v - mean;
    float sq = dv * dv;
    for (int o = 32; o > 0; o >>= 1) sq += __shfl_down(sq, o, 64);
    if (lane == 0) red[wid] = sq;
    __syncthreads();
    float var = (red[0] + red[1] + red[2] + red[3]) * (1.f / 256.f);
    float y = dv * rsqrtf(var + 1e-5f) * gamma[tid] + beta[tid];
    y = y > 0.f ? y : (__expf(y) - 1.f);
    g1[(size_t)row * 256 + tid] = y;
}

// ---------------------------------------------------------------------------
// K6: GEMM2  x1(4096x256)@W2(256x64) -> h2(4096x64)
// ---------------------------------------------------------------------------
__global__ void gemm2_kernel(const float* __restrict__ x1, const float* __restrict__ W2,
                             float* __restrict__ h2) {
    int row = blockIdx.x;
    int lane = threadIdx.x;
    __shared__ float xr[256];
    for (int k = lane; k < 256; k += 64) xr[k] = x1[(size_t)row * 256 + k];
    __syncthreads();
    float acc = 0.f;
#pragma unroll 8
    for (int k = 0; k < 256; k++) acc += xr[k] * W2[k * 64 + lane];
    h2[(size_t)row * 64 + lane] = acc;
}

// ---------------------------------------------------------------------------
// K7: GAT2 src/dst dots over D2=64
// ---------------------------------------------------------------------------
__global__ void sd2_kernel(const float* __restrict__ h2, const float* __restrict__ asrc,
                           const float* __restrict__ adst, float* __restrict__ s2,
                           float* __restrict__ d2) {
    int be = blockIdx.x;
    int lane = threadIdx.x;
    float v = h2[(size_t)be * 64 + lane];
    float ss = v * asrc[lane];
    float dd = v * adst[lane];
    for (int o = 32; o > 0; o >>= 1) {
        ss += __shfl_down(ss, o, 64);
        dd += __shfl_down(dd, o, 64);
    }
    if (lane == 0) { s2[be] = ss; d2[be] = dd; }
}

// ---------------------------------------------------------------------------
// K8: GAT2 attention + bias + LayerNorm(64) + ELU -> x2
// ---------------------------------------------------------------------------
__global__ __launch_bounds__(128) void gat2_kernel(
    const float* __restrict__ h2, const float* __restrict__ s2,
    const float* __restrict__ d2, const float* __restrict__ b2v,
    const float* __restrict__ gamma, const float* __restrict__ beta,
    float* __restrict__ x2) {
    int bi = blockIdx.x;
    int b = bi >> 7;
    int tid = threadIdx.x;
    __shared__ float alpha[128];
    __shared__ float red[2];

    float ev = d2[bi] + s2[(size_t)b * 128 + tid];
    ev = ev >= 0.f ? ev : 0.2f * ev;
    float mx = ev;
    for (int o = 32; o > 0; o >>= 1) mx = fmaxf(mx, __shfl_down(mx, o, 64));
    int lane = tid & 63, wid = tid >> 6;
    if (lane == 0) red[wid] = mx;
    __syncthreads();
    mx = fmaxf(red[0], red[1]);
    __syncthreads();
    float ex = __expf(ev - mx);
    float sm = ex;
    for (int o = 32; o > 0; o >>= 1) sm += __shfl_down(sm, o, 64);
    if (lane == 0) red[wid] = sm;
    __syncthreads();
    sm = red[0] + red[1];
    alpha[tid] = ex / sm;
    __syncthreads();

    if (tid < 64) {
        const float* hb = h2 + (size_t)b * 128 * 64 + tid;
        float o = 0.f;
#pragma unroll 8
        for (int j = 0; j < 128; j++) o += alpha[j] * hb[(size_t)j * 64];
        o += b2v[tid];
        // LayerNorm over 64 within wave 0
        float s = o;
        for (int off = 32; off > 0; off >>= 1) s += __shfl_down(s, off, 64);
        s = __shfl(s, 0, 64);
        float mean = s * (1.f / 64.f);
        float dv = o - mean;
        float sq = dv * dv;
        for (int off = 32; off > 0; off >>= 1) sq += __shfl_down(sq, off, 64);
        sq = __shfl(sq, 0, 64);
        float var = sq * (1.f / 64.f);
        float y = dv * rsqrtf(var + 1e-5f) * gamma[tid] + beta[tid];
        y = y > 0.f ? y : (__expf(y) - 1.f);
        x2[(size_t)bi * 64 + tid] = y;
    }
}

// ---------------------------------------------------------------------------
// K9: per-batch cls contribution: base[b,n] = br1[n] + sum_k cls[b,k]*Wr1[160+k,n]
// ---------------------------------------------------------------------------
__global__ __launch_bounds__(256) void base_kernel(
    const float* __restrict__ seq, const float* __restrict__ Wr1,
    const float* __restrict__ br1, float* __restrict__ baseo) {
    int b = blockIdx.x;
    int n = threadIdx.x;
    __shared__ float cls[HHH];
    for (int k = n; k < HHH; k += 256) cls[k] = seq[(size_t)b * SS * HHH + k];
    __syncthreads();
    float acc = br1[n];
    const float* w = Wr1 + (size_t)160 * 256 + n;
#pragma unroll 4
    for (int k = 0; k < HHH; k++) acc += cls[k] * w[(size_t)k * 256];
    baseo[(size_t)b * 256 + n] = acc;
}

// ---------------------------------------------------------------------------
// K10: final scores, 8 pairs per block; output fp32
// ---------------------------------------------------------------------------
__global__ __launch_bounds__(256) void score_kernel(
    const float* __restrict__ x2, const float* __restrict__ baseo,
    const int* __restrict__ pair_idx, const int* __restrict__ rel_ids,
    const float* __restrict__ rel_emb, const float* __restrict__ Wr1,
    const float* __restrict__ Wr2, const float* __restrict__ br2,
    float* __restrict__ out) {
    int blk = blockIdx.x;
    int b = blk >> 6;
    int p0 = (blk & 63) * 8;
    int tid = threadIdx.x;
    __shared__ float xv[8][160];
    __shared__ int prs[8][3];
    __shared__ float red[8][4];

    if (tid < 8) {
        int p = p0 + tid;
        prs[tid][0] = pair_idx[((size_t)b * PP + p) * 2 + 0];
        prs[tid][1] = pair_idx[((size_t)b * PP + p) * 2 + 1];
        prs[tid][2] = rel_ids[(size_t)b * PP + p];
    }
    __syncthreads();
    for (int idx = tid; idx < 8 * 160; idx += 256) {
        int q = idx / 160, k = idx % 160;
        float v;
        if (k < 64) v = x2[((size_t)b * EE + prs[q][0]) * 64 + k];
        else if (k < 128) v = x2[((size_t)b * EE + prs[q][1]) * 64 + (k - 64)];
        else v = rel_emb[prs[q][2] * RDD + (k - 128)];
        xv[q][k] = v;
    }
    __syncthreads();

    float acc[8];
    float bb = baseo[(size_t)b * 256 + tid];
#pragma unroll
    for (int q = 0; q < 8; q++) acc[q] = bb;
    const float* w = Wr1 + tid;
#pragma unroll 4
    for (int k = 0; k < 160; k++) {
        float wv = w[(size_t)k * 256];
#pragma unroll
        for (int q = 0; q < 8; q++) acc[q] += xv[q][k] * wv;
    }
    float w2v = Wr2[tid];
    int lane = tid & 63, wid = tid >> 6;
#pragma unroll
    for (int q = 0; q < 8; q++) {
        float pr = fmaxf(acc[q], 0.f) * w2v;
        for (int o = 32; o > 0; o >>= 1) pr += __shfl_down(pr, o, 64);
        if (lane == 0) red[q][wid] = pr;
    }
    __syncthreads();
    if (tid < 8) {
        float s = red[tid][0] + red[tid][1] + red[tid][2] + red[tid][3] + br2[0];
        out[(size_t)b * PP + p0 + tid] = s;
    }
}

// ---------------------------------------------------------------------------
extern "C" void kernel_launch(void* const* d_in, const int* in_sizes, int n_in,
                              void* d_out, int out_size, void* d_ws, size_t ws_size,
                              hipStream_t stream) {
    (void)in_sizes; (void)n_in; (void)out_size; (void)ws_size;
    const float* seq      = (const float*)d_in[0];
    const int*   starts   = (const int*)d_in[1];
    const int*   types    = (const int*)d_in[2];
    const int*   pair_idx = (const int*)d_in[3];
    const int*   rel_ids  = (const int*)d_in[4];
    const float* temb     = (const float*)d_in[5];
    const float* remb     = (const float*)d_in[6];
    const float* W1       = (const float*)d_in[7];
    const float* a_src1   = (const float*)d_in[8];
    const float* a_dst1   = (const float*)d_in[9];
    const float* b1       = (const float*)d_in[10];
    const float* ln1_g    = (const float*)d_in[11];
    const float* ln1_b    = (const float*)d_in[12];
    const float* W2       = (const float*)d_in[13];
    const float* a_src2   = (const float*)d_in[14];
    const float* a_dst2   = (const float*)d_in[15];
    const float* b2       = (const float*)d_in[16];
    const float* ln2_g    = (const float*)d_in[17];
    const float* ln2_b    = (const float*)d_in[18];
    const float* Wr1      = (const float*)d_in[19];
    const float* br1      = (const float*)d_in[20];
    const float* Wr2      = (const float*)d_in[21];
    const float* br2      = (const float*)d_in[22];
    float* out = (float*)d_out;

    float* ws = (float*)d_ws;
    float* x    = ws;                    // 4096*768
    float* h1   = x + 4096 * 768;        // 4096*256
    float* s1   = h1 + 4096 * 256;       // 8192
    float* d1   = s1 + 8192;             // 8192
    float* g1   = d1 + 8192;             // 4096*256
    float* h2   = g1 + 4096 * 256;       // 4096*64
    float* s2   = h2 + 4096 * 64;        // 4096
    float* d2   = s2 + 4096;             // 4096
    float* x2   = d2 + 4096;             // 4096*64
    float* baseo = x2 + 4096 * 64;       // 32*256

    pool_kernel<<<BB * EE, 256, 0, stream>>>(seq, starts, types, temb, x);
    gemm1_kernel<<<dim3(4, 64), 256, 0, stream>>>(x, W1, h1);
    sd1_kernel<<<BB * EE * 2, 64, 0, stream>>>(h1, a_src1, a_dst1, s1, d1);
    gat1_attn_kernel<<<BB * EE * 2, 128, 0, stream>>>(h1, s1, d1, b1, g1);
    ln_elu256_kernel<<<BB * EE, 256, 0, stream>>>(g1, ln1_g, ln1_b);
    gemm2_kernel<<<BB * EE, 64, 0, stream>>>(g1, W2, h2);
    sd2_kernel<<<BB * EE, 64, 0, stream>>>(h2, a_src2, a_dst2, s2, d2);
    gat2_kernel<<<BB * EE, 128, 0, stream>>>(h2, s2, d2, b2, ln2_g, ln2_b, x2);
    base_kernel<<<BB, 256, 0, stream>>>(seq, Wr1, br1, baseo);
    score_kernel<<<BB * PP / 8, 256, 0, stream>>>(x2, baseo, pair_idx, rel_ids,
                                                  remb, Wr1, Wr2, br2, out);
}

// Round 4
// 362.602 us; speedup vs baseline: 1.2221x; 1.2221x over previous
//
#include <hip/hip_runtime.h>
#include <hip/hip_bf16.h>

#define BB 32
#define SS 1024
#define HHH 768
#define EE 128
#define WW 8
#define PP 512
#define ND1 128
#define NH1 2
#define ND2 64
#define RDD 32

// ---------------------------------------------------------------------------
// K1: window gather + mean-query attention pooling + type embedding
// grid = B*E blocks, 256 threads. Inputs fp32.
// Blocks 0..31 additionally initialize baseo[b] = br1 (consumed by
// base_partial_kernel later in the stream).
// ---------------------------------------------------------------------------
__global__ __launch_bounds__(256) void pool_kernel(
    const float* __restrict__ seq, const int* __restrict__ starts,
    const int* __restrict__ types, const float* __restrict__ temb,
    const float* __restrict__ br1, float* __restrict__ baseo,
    float* __restrict__ xout) {
    int be = blockIdx.x;
    int b = be >> 7;
    int tid = threadIdx.x;
    __shared__ float toks[WW][HHH];
    __shared__ float scred[WW];
    __shared__ float attn_s[WW];

    if (be < BB) baseo[(size_t)be * 256 + tid] = br1[tid];

    int start = starts[be];
    const float* basep = seq + ((size_t)b * SS + start) * HHH;
    for (int idx = tid; idx < WW * HHH; idx += 256) {
        int w = idx / HHH, h = idx % HHH;
        toks[w][h] = basep[(size_t)w * HHH + h];
    }
    __syncthreads();

    // each thread owns 3 columns h = tid + 256*c
    float sc[WW];
#pragma unroll
    for (int w = 0; w < WW; w++) sc[w] = 0.f;
#pragma unroll
    for (int c = 0; c < 3; c++) {
        int h = tid + 256 * c;
        float s = 0.f;
#pragma unroll
        for (int w = 0; w < WW; w++) s += toks[w][h];
        float m = s * (1.0f / WW);
#pragma unroll
        for (int w = 0; w < WW; w++) sc[w] += toks[w][h] * m;
    }
    if (tid < WW) scred[tid] = 0.f;
    __syncthreads();
    int lane = tid & 63;
#pragma unroll
    for (int w = 0; w < WW; w++) {
        float v = sc[w];
        for (int o = 32; o > 0; o >>= 1) v += __shfl_down(v, o, 64);
        if (lane == 0) atomicAdd(&scred[w], v);
    }
    __syncthreads();
    if (tid == 0) {
        float mx = scred[0];
        for (int w = 1; w < WW; w++) mx = fmaxf(mx, scred[w]);
        float ssum = 0.f;
        float a[WW];
        for (int w = 0; w < WW; w++) { a[w] = __expf(scred[w] - mx); ssum += a[w]; }
        float inv = 1.f / ssum;
        for (int w = 0; w < WW; w++) attn_s[w] = a[w] * inv;
    }
    __syncthreads();

    int t = types[be];
    const float* emb = temb + (size_t)t * HHH;
#pragma unroll
    for (int c = 0; c < 3; c++) {
        int h = tid + 256 * c;
        float p = 0.f;
#pragma unroll
        for (int w = 0; w < WW; w++) p += attn_s[w] * toks[w][h];
        xout[(size_t)be * HHH + h] = p + emb[h];
    }
}

// ---------------------------------------------------------------------------
// K2: GEMM1  x(4096x768) @ W1(768x256) -> h1(4096x256), all fp32
// 64x64 tile, 256 threads, 4x4 per thread
// ---------------------------------------------------------------------------
__global__ __launch_bounds__(256) void gemm1_kernel(
    const float* __restrict__ A, const float* __restrict__ Bw,
    float* __restrict__ C) {
    const int K = HHH, N = NH1 * ND1;
    __shared__ float As[16][64 + 1];  // [k][m]
    __shared__ float Bs[16][64 + 1];  // [k][n]
    int tx = threadIdx.x & 15, ty = threadIdx.x >> 4;
    int m0 = blockIdx.y * 64, n0 = blockIdx.x * 64;
    float acc[4][4] = {};

    for (int k0 = 0; k0 < K; k0 += 16) {
        {
            int idx = threadIdx.x * 4;
            int m = idx >> 4;
            int k = idx & 15;
            float4 v = *(const float4*)(A + (size_t)(m0 + m) * K + k0 + k);
            As[k + 0][m] = v.x; As[k + 1][m] = v.y;
            As[k + 2][m] = v.z; As[k + 3][m] = v.w;
        }
        {
            int idx = threadIdx.x * 4;
            int k = idx >> 6;
            int n = idx & 63;
            float4 v = *(const float4*)(Bw + (size_t)(k0 + k) * N + n0 + n);
            Bs[k][n + 0] = v.x; Bs[k][n + 1] = v.y;
            Bs[k][n + 2] = v.z; Bs[k][n + 3] = v.w;
        }
        __syncthreads();
#pragma unroll
        for (int k = 0; k < 16; k++) {
            float a[4], bv[4];
#pragma unroll
            for (int i = 0; i < 4; i++) a[i] = As[k][ty * 4 + i];
#pragma unroll
            for (int j = 0; j < 4; j++) bv[j] = Bs[k][tx * 4 + j];
#pragma unroll
            for (int i = 0; i < 4; i++)
#pragma unroll
                for (int j = 0; j < 4; j++) acc[i][j] += a[i] * bv[j];
        }
        __syncthreads();
    }
#pragma unroll
    for (int i = 0; i < 4; i++)
#pragma unroll
        for (int j = 0; j < 4; j++)
            C[(size_t)(m0 + ty * 4 + i) * N + n0 + tx * 4 + j] = acc[i][j];
}

// ---------------------------------------------------------------------------
// K3: per-(b,e,head) attention src/dst dots over D1=128
// grid = B*E*2 blocks of 64 threads
// ---------------------------------------------------------------------------
__global__ void sd1_kernel(const float* __restrict__ h1, const float* __restrict__ asrc,
                           const float* __restrict__ adst, float* __restrict__ s1,
                           float* __restrict__ d1) {
    int beh = blockIdx.x;
    int h = beh & 1;
    int be = beh >> 1;
    int lane = threadIdx.x;
    const float* row = h1 + (size_t)be * 256 + h * 128;
    float v0 = row[lane], v1 = row[lane + 64];
    float ss = v0 * asrc[h * 128 + lane] + v1 * asrc[h * 128 + lane + 64];
    float dd = v0 * adst[h * 128 + lane] + v1 * adst[h * 128 + lane + 64];
    for (int o = 32; o > 0; o >>= 1) {
        ss += __shfl_down(ss, o, 64);
        dd += __shfl_down(dd, o, 64);
    }
    if (lane == 0) { s1[beh] = ss; d1[beh] = dd; }
}

// ---------------------------------------------------------------------------
// K4: GAT1 attention: softmax over j (128) + matvec -> g1 pre-LN
// grid = B*E*2 blocks, 128 threads
// ---------------------------------------------------------------------------
__global__ __launch_bounds__(128) void gat1_attn_kernel(
    const float* __restrict__ h1, const float* __restrict__ s1,
    const float* __restrict__ d1, const float* __restrict__ b1,
    float* __restrict__ g1) {
    int id = blockIdx.x;
    int h = id & 1;
    int bi = id >> 1;
    int b = bi >> 7;
    int tid = threadIdx.x;
    __shared__ float alpha[128];
    __shared__ float red[2];

    float di = d1[bi * 2 + h];
    float sj = s1[((size_t)b * 128 + tid) * 2 + h];
    float ev = di + sj;
    ev = ev >= 0.f ? ev : 0.2f * ev;

    float mx = ev;
    for (int o = 32; o > 0; o >>= 1) mx = fmaxf(mx, __shfl_down(mx, o, 64));
    int lane = tid & 63, wid = tid >> 6;
    if (lane == 0) red[wid] = mx;
    __syncthreads();
    mx = fmaxf(red[0], red[1]);
    __syncthreads();
    float ex = __expf(ev - mx);
    float sm = ex;
    for (int o = 32; o > 0; o >>= 1) sm += __shfl_down(sm, o, 64);
    if (lane == 0) red[wid] = sm;
    __syncthreads();
    sm = red[0] + red[1];
    alpha[tid] = ex / sm;
    __syncthreads();

    const float* hb = h1 + (size_t)b * 128 * 256 + h * 128 + tid;
    float o = 0.f;
#pragma unroll 8
    for (int j = 0; j < 128; j++) o += alpha[j] * hb[(size_t)j * 256];
    g1[(size_t)bi * 256 + h * 128 + tid] = o + b1[h * 128 + tid];
}

// ---------------------------------------------------------------------------
// K5: LayerNorm(256) + ELU in place
// ---------------------------------------------------------------------------
__global__ __launch_bounds__(256) void ln_elu256_kernel(
    float* __restrict__ g1, const float* __restrict__ gamma,
    const float* __restrict__ beta) {
    int row = blockIdx.x;
    int tid = threadIdx.x;
    __shared__ float red[4];
    float v = g1[(size_t)row * 256 + tid];
    float s = v;
    for (int o = 32; o > 0; o >>= 1) s += __shfl_down(s, o, 64);
    int lane = tid & 63, wid = tid >> 6;
    if (lane == 0) red[wid] = s;
    __syncthreads();
    float mean = (red[0] + red[1] + red[2] + red[3]) * (1.f / 256.f);
    __syncthreads();
    float dv = v - mean;
    float sq = dv * dv;
    for (int o = 32; o > 0; o >>= 1) sq += __shfl_down(sq, o, 64);
    if (lane == 0) red[wid] = sq;
    __syncthreads();
    float var = (red[0] + red[1] + red[2] + red[3]) * (1.f / 256.f);
    float y = dv * rsqrtf(var + 1e-5f) * gamma[tid] + beta[tid];
    y = y > 0.f ? y : (__expf(y) - 1.f);
    g1[(size_t)row * 256 + tid] = y;
}

// ---------------------------------------------------------------------------
// K6: GEMM2  x1(4096x256)@W2(256x64) -> h2(4096x64)
// ---------------------------------------------------------------------------
__global__ void gemm2_kernel(const float* __restrict__ x1, const float* __restrict__ W2,
                             float* __restrict__ h2) {
    int row = blockIdx.x;
    int lane = threadIdx.x;
    __shared__ float xr[256];
    for (int k = lane; k < 256; k += 64) xr[k] = x1[(size_t)row * 256 + k];
    __syncthreads();
    float acc = 0.f;
#pragma unroll 8
    for (int k = 0; k < 256; k++) acc += xr[k] * W2[k * 64 + lane];
    h2[(size_t)row * 64 + lane] = acc;
}

// ---------------------------------------------------------------------------
// K7: GAT2 src/dst dots over D2=64
// ---------------------------------------------------------------------------
__global__ void sd2_kernel(const float* __restrict__ h2, const float* __restrict__ asrc,
                           const float* __restrict__ adst, float* __restrict__ s2,
                           float* __restrict__ d2) {
    int be = blockIdx.x;
    int lane = threadIdx.x;
    float v = h2[(size_t)be * 64 + lane];
    float ss = v * asrc[lane];
    float dd = v * adst[lane];
    for (int o = 32; o > 0; o >>= 1) {
        ss += __shfl_down(ss, o, 64);
        dd += __shfl_down(dd, o, 64);
    }
    if (lane == 0) { s2[be] = ss; d2[be] = dd; }
}

// ---------------------------------------------------------------------------
// K8: GAT2 attention + bias + LayerNorm(64) + ELU -> x2
// ---------------------------------------------------------------------------
__global__ __launch_bounds__(128) void gat2_kernel(
    const float* __restrict__ h2, const float* __restrict__ s2,
    const float* __restrict__ d2, const float* __restrict__ b2v,
    const float* __restrict__ gamma, const float* __restrict__ beta,
    float* __restrict__ x2) {
    int bi = blockIdx.x;
    int b = bi >> 7;
    int tid = threadIdx.x;
    __shared__ float alpha[128];
    __shared__ float red[2];

    float ev = d2[bi] + s2[(size_t)b * 128 + tid];
    ev = ev >= 0.f ? ev : 0.2f * ev;
    float mx = ev;
    for (int o = 32; o > 0; o >>= 1) mx = fmaxf(mx, __shfl_down(mx, o, 64));
    int lane = tid & 63, wid = tid >> 6;
    if (lane == 0) red[wid] = mx;
    __syncthreads();
    mx = fmaxf(red[0], red[1]);
    __syncthreads();
    float ex = __expf(ev - mx);
    float sm = ex;
    for (int o = 32; o > 0; o >>= 1) sm += __shfl_down(sm, o, 64);
    if (lane == 0) red[wid] = sm;
    __syncthreads();
    sm = red[0] + red[1];
    alpha[tid] = ex / sm;
    __syncthreads();

    if (tid < 64) {
        const float* hb = h2 + (size_t)b * 128 * 64 + tid;
        float o = 0.f;
#pragma unroll 8
        for (int j = 0; j < 128; j++) o += alpha[j] * hb[(size_t)j * 64];
        o += b2v[tid];
        // LayerNorm over 64 within wave 0
        float s = o;
        for (int off = 32; off > 0; off >>= 1) s += __shfl_down(s, off, 64);
        s = __shfl(s, 0, 64);
        float mean = s * (1.f / 64.f);
        float dv = o - mean;
        float sq = dv * dv;
        for (int off = 32; off > 0; off >>= 1) sq += __shfl_down(sq, off, 64);
        sq = __shfl(sq, 0, 64);
        float var = sq * (1.f / 64.f);
        float y = dv * rsqrtf(var + 1e-5f) * gamma[tid] + beta[tid];
        y = y > 0.f ? y : (__expf(y) - 1.f);
        x2[(size_t)bi * 64 + tid] = y;
    }
}

// ---------------------------------------------------------------------------
// K9: per-batch cls contribution, K-split for occupancy:
// grid = (12 k-chunks, 32 batches), 256 threads. baseo pre-initialized to br1
// by pool_kernel; partial sums accumulated with atomicAdd.
// ---------------------------------------------------------------------------
__global__ __launch_bounds__(256) void base_partial_kernel(
    const float* __restrict__ seq, const float* __restrict__ Wr1,
    float* __restrict__ baseo) {
    int kc = blockIdx.x;   // 0..11, chunk of 64 k's
    int b  = blockIdx.y;   // 0..31
    int n = threadIdx.x;
    __shared__ float cls[64];
    if (n < 64) cls[n] = seq[(size_t)b * SS * HHH + kc * 64 + n];
    __syncthreads();
    float acc = 0.f;
    const float* w = Wr1 + (size_t)(160 + kc * 64) * 256 + n;
#pragma unroll 16
    for (int k = 0; k < 64; k++) acc += cls[k] * w[(size_t)k * 256];
    atomicAdd(&baseo[(size_t)b * 256 + n], acc);
}

// ---------------------------------------------------------------------------
// K10: final scores, 8 pairs per block; output fp32
// ---------------------------------------------------------------------------
__global__ __launch_bounds__(256) void score_kernel(
    const float* __restrict__ x2, const float* __restrict__ baseo,
    const int* __restrict__ pair_idx, const int* __restrict__ rel_ids,
    const float* __restrict__ rel_emb, const float* __restrict__ Wr1,
    const float* __restrict__ Wr2, const float* __restrict__ br2,
    float* __restrict__ out) {
    int blk = blockIdx.x;
    int b = blk >> 6;
    int p0 = (blk & 63) * 8;
    int tid = threadIdx.x;
    __shared__ float xv[8][160];
    __shared__ int prs[8][3];
    __shared__ float red[8][4];

    if (tid < 8) {
        int p = p0 + tid;
        prs[tid][0] = pair_idx[((size_t)b * PP + p) * 2 + 0];
        prs[tid][1] = pair_idx[((size_t)b * PP + p) * 2 + 1];
        prs[tid][2] = rel_ids[(size_t)b * PP + p];
    }
    __syncthreads();
    for (int idx = tid; idx < 8 * 160; idx += 256) {
        int q = idx / 160, k = idx % 160;
        float v;
        if (k < 64) v = x2[((size_t)b * EE + prs[q][0]) * 64 + k];
        else if (k < 128) v = x2[((size_t)b * EE + prs[q][1]) * 64 + (k - 64)];
        else v = rel_emb[prs[q][2] * RDD + (k - 128)];
        xv[q][k] = v;
    }
    __syncthreads();

    float acc[8];
    float bb = baseo[(size_t)b * 256 + tid];
#pragma unroll
    for (int q = 0; q < 8; q++) acc[q] = bb;
    const float* w = Wr1 + tid;
#pragma unroll 4
    for (int k = 0; k < 160; k++) {
        float wv = w[(size_t)k * 256];
#pragma unroll
        for (int q = 0; q < 8; q++) acc[q] += xv[q][k] * wv;
    }
    float w2v = Wr2[tid];
    int lane = tid & 63, wid = tid >> 6;
#pragma unroll
    for (int q = 0; q < 8; q++) {
        float pr = fmaxf(acc[q], 0.f) * w2v;
        for (int o = 32; o > 0; o >>= 1) pr += __shfl_down(pr, o, 64);
        if (lane == 0) red[q][wid] = pr;
    }
    __syncthreads();
    if (tid < 8) {
        float s = red[tid][0] + red[tid][1] + red[tid][2] + red[tid][3] + br2[0];
        out[(size_t)b * PP + p0 + tid] = s;
    }
}

// ---------------------------------------------------------------------------
extern "C" void kernel_launch(void* const* d_in, const int* in_sizes, int n_in,
                              void* d_out, int out_size, void* d_ws, size_t ws_size,
                              hipStream_t stream) {
    (void)in_sizes; (void)n_in; (void)out_size; (void)ws_size;
    const float* seq      = (const float*)d_in[0];
    const int*   starts   = (const int*)d_in[1];
    const int*   types    = (const int*)d_in[2];
    const int*   pair_idx = (const int*)d_in[3];
    const int*   rel_ids  = (const int*)d_in[4];
    const float* temb     = (const float*)d_in[5];
    const float* remb     = (const float*)d_in[6];
    const float* W1       = (const float*)d_in[7];
    const float* a_src1   = (const float*)d_in[8];
    const float* a_dst1   = (const float*)d_in[9];
    const float* b1       = (const float*)d_in[10];
    const float* ln1_g    = (const float*)d_in[11];
    const float* ln1_b    = (const float*)d_in[12];
    const float* W2       = (const float*)d_in[13];
    const float* a_src2   = (const float*)d_in[14];
    const float* a_dst2   = (const float*)d_in[15];
    const float* b2       = (const float*)d_in[16];
    const float* ln2_g    = (const float*)d_in[17];
    const float* ln2_b    = (const float*)d_in[18];
    const float* Wr1      = (const float*)d_in[19];
    const float* br1      = (const float*)d_in[20];
    const float* Wr2      = (const float*)d_in[21];
    const float* br2      = (const float*)d_in[22];
    float* out = (float*)d_out;

    float* ws = (float*)d_ws;
    float* x    = ws;                    // 4096*768
    float* h1   = x + 4096 * 768;        // 4096*256
    float* s1   = h1 + 4096 * 256;       // 8192
    float* d1   = s1 + 8192;             // 8192
    float* g1   = d1 + 8192;             // 4096*256
    float* h2   = g1 + 4096 * 256;       // 4096*64
    float* s2   = h2 + 4096 * 64;        // 4096
    float* d2   = s2 + 4096;             // 4096
    float* x2   = d2 + 4096;             // 4096*64
    float* baseo = x2 + 4096 * 64;       // 32*256

    pool_kernel<<<BB * EE, 256, 0, stream>>>(seq, starts, types, temb, br1, baseo, x);
    base_partial_kernel<<<dim3(12, 32), 256, 0, stream>>>(seq, Wr1, baseo);
    gemm1_kernel<<<dim3(4, 64), 256, 0, stream>>>(x, W1, h1);
    sd1_kernel<<<BB * EE * 2, 64, 0, stream>>>(h1, a_src1, a_dst1, s1, d1);
    gat1_attn_kernel<<<BB * EE * 2, 128, 0, stream>>>(h1, s1, d1, b1, g1);
    ln_elu256_kernel<<<BB * EE, 256, 0, stream>>>(g1, ln1_g, ln1_b);
    gemm2_kernel<<<BB * EE, 64, 0, stream>>>(g1, W2, h2);
    sd2_kernel<<<BB * EE, 64, 0, stream>>>(h2, a_src2, a_dst2, s2, d2);
    gat2_kernel<<<BB * EE, 128, 0, stream>>>(h2, s2, d2, b2, ln2_g, ln2_b, x2);
    score_kernel<<<BB * PP / 8, 256, 0, stream>>>(x2, baseo, pair_idx, rel_ids,
                                                  remb, Wr1, Wr2, br2, out);
}

// Round 5
// 307.400 us; speedup vs baseline: 1.4416x; 1.1796x over previous
//
#include <hip/hip_runtime.h>
#include <hip/hip_bf16.h>

#define BB 32
#define SS 1024
#define HHH 768
#define EE 128
#define WW 8
#define PP 512
#define ND1 128
#define NH1 2
#define ND2 64
#define RDD 32

typedef __attribute__((ext_vector_type(8))) short bf16x8;
typedef __attribute__((ext_vector_type(8))) unsigned short us8;
typedef __attribute__((ext_vector_type(4))) float f32x4;

__device__ __forceinline__ unsigned short f2bf(float v) {
    __hip_bfloat16 h = __float2bfloat16(v);
    return *(unsigned short*)&h;
}

// ---------------------------------------------------------------------------
// K0: one-shot W1 (768x256 fp32) -> Wt (256x768 bf16, n-major)
// ---------------------------------------------------------------------------
__global__ __launch_bounds__(256) void wt_conv_kernel(
    const float* __restrict__ W1, unsigned short* __restrict__ Wt) {
    int k = blockIdx.x;   // 0..767
    int n = threadIdx.x;  // 0..255
    Wt[(size_t)n * HHH + k] = f2bf(W1[(size_t)k * 256 + n]);
}

// ---------------------------------------------------------------------------
// K1: window gather + mean-query attention pooling + type embedding
// grid = B*E blocks, 256 threads. Writes x as bf16 (consumed only by MFMA gemm1).
// Blocks 0..31 initialize baseo[b] = br1.
// ---------------------------------------------------------------------------
__global__ __launch_bounds__(256) void pool_kernel(
    const float* __restrict__ seq, const int* __restrict__ starts,
    const int* __restrict__ types, const float* __restrict__ temb,
    const float* __restrict__ br1, float* __restrict__ baseo,
    unsigned short* __restrict__ xout) {
    int be = blockIdx.x;
    int b = be >> 7;
    int tid = threadIdx.x;
    __shared__ float toks[WW][HHH];
    __shared__ float scred[WW];
    __shared__ float attn_s[WW];

    if (be < BB) baseo[(size_t)be * 256 + tid] = br1[tid];

    int start = starts[be];
    const float* basep = seq + ((size_t)b * SS + start) * HHH;
    for (int idx = tid; idx < WW * HHH; idx += 256) {
        int w = idx / HHH, h = idx % HHH;
        toks[w][h] = basep[(size_t)w * HHH + h];
    }
    __syncthreads();

    float sc[WW];
#pragma unroll
    for (int w = 0; w < WW; w++) sc[w] = 0.f;
#pragma unroll
    for (int c = 0; c < 3; c++) {
        int h = tid + 256 * c;
        float s = 0.f;
#pragma unroll
        for (int w = 0; w < WW; w++) s += toks[w][h];
        float m = s * (1.0f / WW);
#pragma unroll
        for (int w = 0; w < WW; w++) sc[w] += toks[w][h] * m;
    }
    if (tid < WW) scred[tid] = 0.f;
    __syncthreads();
    int lane = tid & 63;
#pragma unroll
    for (int w = 0; w < WW; w++) {
        float v = sc[w];
        for (int o = 32; o > 0; o >>= 1) v += __shfl_down(v, o, 64);
        if (lane == 0) atomicAdd(&scred[w], v);
    }
    __syncthreads();
    if (tid == 0) {
        float mx = scred[0];
        for (int w = 1; w < WW; w++) mx = fmaxf(mx, scred[w]);
        float ssum = 0.f;
        float a[WW];
        for (int w = 0; w < WW; w++) { a[w] = __expf(scred[w] - mx); ssum += a[w]; }
        float inv = 1.f / ssum;
        for (int w = 0; w < WW; w++) attn_s[w] = a[w] * inv;
    }
    __syncthreads();

    int t = types[be];
    const float* emb = temb + (size_t)t * HHH;
#pragma unroll
    for (int c = 0; c < 3; c++) {
        int h = tid + 256 * c;
        float p = 0.f;
#pragma unroll
        for (int w = 0; w < WW; w++) p += attn_s[w] * toks[w][h];
        xout[(size_t)be * HHH + h] = f2bf(p + emb[h]);
    }
}

// ---------------------------------------------------------------------------
// K2: GEMM1 via MFMA bf16.  Xb(4096x768 bf16) @ Wt^T (Wt is 256x768 n-major)
// -> h1(4096x256 fp32).  64x64 tile per block, 4 waves, each wave a 32x32
// quadrant as 2x2 mfma_f32_16x16x32_bf16 fragments. LDS rows padded to 40
// bf16 (20 words -> bank stride 20, 2-way = free).
// ---------------------------------------------------------------------------
__global__ __launch_bounds__(256) void gemm1_mfma_kernel(
    const unsigned short* __restrict__ Xb, const unsigned short* __restrict__ Wt,
    float* __restrict__ C) {
    const int K = HHH;
    int n0 = blockIdx.x * 64;
    int m0 = blockIdx.y * 64;
    int tid = threadIdx.x;
    int wave = tid >> 6, lane = tid & 63;
    int wm = (wave >> 1) * 32, wn = (wave & 1) * 32;

    __shared__ __align__(16) unsigned short As[64][40];  // [m][k]
    __shared__ __align__(16) unsigned short Bs[64][40];  // [n][k]

    f32x4 acc[2][2] = {};

    int ar = tid >> 2;            // 0..63 row within tile
    int ac = (tid & 3) * 8;       // k-chunk

    int fr = lane & 15;           // fragment row/col
    int fk = (lane >> 4) * 8;     // fragment k offset

    for (int k0 = 0; k0 < K; k0 += 32) {
        us8 av = *(const us8*)(Xb + (size_t)(m0 + ar) * K + k0 + ac);
        us8 bv = *(const us8*)(Wt + (size_t)(n0 + ar) * K + k0 + ac);
        *(us8*)(&As[ar][ac]) = av;
        *(us8*)(&Bs[ar][ac]) = bv;
        __syncthreads();

        bf16x8 a0 = *(const bf16x8*)(&As[wm + fr][fk]);
        bf16x8 a1 = *(const bf16x8*)(&As[wm + 16 + fr][fk]);
        bf16x8 b0 = *(const bf16x8*)(&Bs[wn + fr][fk]);
        bf16x8 b1 = *(const bf16x8*)(&Bs[wn + 16 + fr][fk]);

        acc[0][0] = __builtin_amdgcn_mfma_f32_16x16x32_bf16(a0, b0, acc[0][0], 0, 0, 0);
        acc[0][1] = __builtin_amdgcn_mfma_f32_16x16x32_bf16(a0, b1, acc[0][1], 0, 0, 0);
        acc[1][0] = __builtin_amdgcn_mfma_f32_16x16x32_bf16(a1, b0, acc[1][0], 0, 0, 0);
        acc[1][1] = __builtin_amdgcn_mfma_f32_16x16x32_bf16(a1, b1, acc[1][1], 0, 0, 0);
        __syncthreads();
    }

    // C/D layout: col = lane&15, row = (lane>>4)*4 + reg
    int crow = (lane >> 4) * 4;
    int ccol = lane & 15;
#pragma unroll
    for (int mi = 0; mi < 2; mi++)
#pragma unroll
        for (int ni = 0; ni < 2; ni++)
#pragma unroll
            for (int r = 0; r < 4; r++)
                C[(size_t)(m0 + wm + mi * 16 + crow + r) * 256 +
                  n0 + wn + ni * 16 + ccol] = acc[mi][ni][r];
}

// ---------------------------------------------------------------------------
// K3: per-(b,e,head) attention src/dst dots over D1=128
// ---------------------------------------------------------------------------
__global__ void sd1_kernel(const float* __restrict__ h1, const float* __restrict__ asrc,
                           const float* __restrict__ adst, float* __restrict__ s1,
                           float* __restrict__ d1) {
    int beh = blockIdx.x;
    int h = beh & 1;
    int be = beh >> 1;
    int lane = threadIdx.x;
    const float* row = h1 + (size_t)be * 256 + h * 128;
    float v0 = row[lane], v1 = row[lane + 64];
    float ss = v0 * asrc[h * 128 + lane] + v1 * asrc[h * 128 + lane + 64];
    float dd = v0 * adst[h * 128 + lane] + v1 * adst[h * 128 + lane + 64];
    for (int o = 32; o > 0; o >>= 1) {
        ss += __shfl_down(ss, o, 64);
        dd += __shfl_down(dd, o, 64);
    }
    if (lane == 0) { s1[beh] = ss; d1[beh] = dd; }
}

// ---------------------------------------------------------------------------
// K4: GAT1 attention: softmax over j (128) + matvec -> g1 pre-LN
// ---------------------------------------------------------------------------
__global__ __launch_bounds__(128) void gat1_attn_kernel(
    const float* __restrict__ h1, const float* __restrict__ s1,
    const float* __restrict__ d1, const float* __restrict__ b1,
    float* __restrict__ g1) {
    int id = blockIdx.x;
    int h = id & 1;
    int bi = id >> 1;
    int b = bi >> 7;
    int tid = threadIdx.x;
    __shared__ float alpha[128];
    __shared__ float red[2];

    float di = d1[bi * 2 + h];
    float sj = s1[((size_t)b * 128 + tid) * 2 + h];
    float ev = di + sj;
    ev = ev >= 0.f ? ev : 0.2f * ev;

    float mx = ev;
    for (int o = 32; o > 0; o >>= 1) mx = fmaxf(mx, __shfl_down(mx, o, 64));
    int lane = tid & 63, wid = tid >> 6;
    if (lane == 0) red[wid] = mx;
    __syncthreads();
    mx = fmaxf(red[0], red[1]);
    __syncthreads();
    float ex = __expf(ev - mx);
    float sm = ex;
    for (int o = 32; o > 0; o >>= 1) sm += __shfl_down(sm, o, 64);
    if (lane == 0) red[wid] = sm;
    __syncthreads();
    sm = red[0] + red[1];
    alpha[tid] = ex / sm;
    __syncthreads();

    const float* hb = h1 + (size_t)b * 128 * 256 + h * 128 + tid;
    float o = 0.f;
#pragma unroll 8
    for (int j = 0; j < 128; j++) o += alpha[j] * hb[(size_t)j * 256];
    g1[(size_t)bi * 256 + h * 128 + tid] = o + b1[h * 128 + tid];
}

// ---------------------------------------------------------------------------
// K5: LayerNorm(256) + ELU in place
// ---------------------------------------------------------------------------
__global__ __launch_bounds__(256) void ln_elu256_kernel(
    float* __restrict__ g1, const float* __restrict__ gamma,
    const float* __restrict__ beta) {
    int row = blockIdx.x;
    int tid = threadIdx.x;
    __shared__ float red[4];
    float v = g1[(size_t)row * 256 + tid];
    float s = v;
    for (int o = 32; o > 0; o >>= 1) s += __shfl_down(s, o, 64);
    int lane = tid & 63, wid = tid >> 6;
    if (lane == 0) red[wid] = s;
    __syncthreads();
    float mean = (red[0] + red[1] + red[2] + red[3]) * (1.f / 256.f);
    __syncthreads();
    float dv = v - mean;
    float sq = dv * dv;
    for (int o = 32; o > 0; o >>= 1) sq += __shfl_down(sq, o, 64);
    if (lane == 0) red[wid] = sq;
    __syncthreads();
    float var = (red[0] + red[1] + red[2] + red[3]) * (1.f / 256.f);
    float y = dv * rsqrtf(var + 1e-5f) * gamma[tid] + beta[tid];
    y = y > 0.f ? y : (__expf(y) - 1.f);
    g1[(size_t)row * 256 + tid] = y;
}

// ---------------------------------------------------------------------------
// K6: GEMM2  x1(4096x256)@W2(256x64) -> h2(4096x64)
// ---------------------------------------------------------------------------
__global__ void gemm2_kernel(const float* __restrict__ x1, const float* __restrict__ W2,
                             float* __restrict__ h2) {
    int row = blockIdx.x;
    int lane = threadIdx.x;
    __shared__ float xr[256];
    for (int k = lane; k < 256; k += 64) xr[k] = x1[(size_t)row * 256 + k];
    __syncthreads();
    float acc = 0.f;
#pragma unroll 8
    for (int k = 0; k < 256; k++) acc += xr[k] * W2[k * 64 + lane];
    h2[(size_t)row * 64 + lane] = acc;
}

// ---------------------------------------------------------------------------
// K7: GAT2 src/dst dots over D2=64
// ---------------------------------------------------------------------------
__global__ void sd2_kernel(const float* __restrict__ h2, const float* __restrict__ asrc,
                           const float* __restrict__ adst, float* __restrict__ s2,
                           float* __restrict__ d2) {
    int be = blockIdx.x;
    int lane = threadIdx.x;
    float v = h2[(size_t)be * 64 + lane];
    float ss = v * asrc[lane];
    float dd = v * adst[lane];
    for (int o = 32; o > 0; o >>= 1) {
        ss += __shfl_down(ss, o, 64);
        dd += __shfl_down(dd, o, 64);
    }
    if (lane == 0) { s2[be] = ss; d2[be] = dd; }
}

// ---------------------------------------------------------------------------
// K8: GAT2 attention + bias + LayerNorm(64) + ELU -> x2
// ---------------------------------------------------------------------------
__global__ __launch_bounds__(128) void gat2_kernel(
    const float* __restrict__ h2, const float* __restrict__ s2,
    const float* __restrict__ d2, const float* __restrict__ b2v,
    const float* __restrict__ gamma, const float* __restrict__ beta,
    float* __restrict__ x2) {
    int bi = blockIdx.x;
    int b = bi >> 7;
    int tid = threadIdx.x;
    __shared__ float alpha[128];
    __shared__ float red[2];

    float ev = d2[bi] + s2[(size_t)b * 128 + tid];
    ev = ev >= 0.f ? ev : 0.2f * ev;
    float mx = ev;
    for (int o = 32; o > 0; o >>= 1) mx = fmaxf(mx, __shfl_down(mx, o, 64));
    int lane = tid & 63, wid = tid >> 6;
    if (lane == 0) red[wid] = mx;
    __syncthreads();
    mx = fmaxf(red[0], red[1]);
    __syncthreads();
    float ex = __expf(ev - mx);
    float sm = ex;
    for (int o = 32; o > 0; o >>= 1) sm += __shfl_down(sm, o, 64);
    if (lane == 0) red[wid] = sm;
    __syncthreads();
    sm = red[0] + red[1];
    alpha[tid] = ex / sm;
    __syncthreads();

    if (tid < 64) {
        const float* hb = h2 + (size_t)b * 128 * 64 + tid;
        float o = 0.f;
#pragma unroll 8
        for (int j = 0; j < 128; j++) o += alpha[j] * hb[(size_t)j * 64];
        o += b2v[tid];
        float s = o;
        for (int off = 32; off > 0; off >>= 1) s += __shfl_down(s, off, 64);
        s = __shfl(s, 0, 64);
        float mean = s * (1.f / 64.f);
        float dv = o - mean;
        float sq = dv * dv;
        for (int off = 32; off > 0; off >>= 1) sq += __shfl_down(sq, off, 64);
        sq = __shfl(sq, 0, 64);
        float var = sq * (1.f / 64.f);
        float y = dv * rsqrtf(var + 1e-5f) * gamma[tid] + beta[tid];
        y = y > 0.f ? y : (__expf(y) - 1.f);
        x2[(size_t)bi * 64 + tid] = y;
    }
}

// ---------------------------------------------------------------------------
// K9: per-batch cls contribution, K-split for occupancy:
// grid = (12 k-chunks, 32 batches). baseo pre-initialized to br1 by pool_kernel.
// ---------------------------------------------------------------------------
__global__ __launch_bounds__(256) void base_partial_kernel(
    const float* __restrict__ seq, const float* __restrict__ Wr1,
    float* __restrict__ baseo) {
    int kc = blockIdx.x;
    int b  = blockIdx.y;
    int n = threadIdx.x;
    __shared__ float cls[64];
    if (n < 64) cls[n] = seq[(size_t)b * SS * HHH + kc * 64 + n];
    __syncthreads();
    float acc = 0.f;
    const float* w = Wr1 + (size_t)(160 + kc * 64) * 256 + n;
#pragma unroll 16
    for (int k = 0; k < 64; k++) acc += cls[k] * w[(size_t)k * 256];
    atomicAdd(&baseo[(size_t)b * 256 + n], acc);
}

// ---------------------------------------------------------------------------
// K10: final scores, 8 pairs per block; output fp32
// ---------------------------------------------------------------------------
__global__ __launch_bounds__(256) void score_kernel(
    const float* __restrict__ x2, const float* __restrict__ baseo,
    const int* __restrict__ pair_idx, const int* __restrict__ rel_ids,
    const float* __restrict__ rel_emb, const float* __restrict__ Wr1,
    const float* __restrict__ Wr2, const float* __restrict__ br2,
    float* __restrict__ out) {
    int blk = blockIdx.x;
    int b = blk >> 6;
    int p0 = (blk & 63) * 8;
    int tid = threadIdx.x;
    __shared__ float xv[8][160];
    __shared__ int prs[8][3];
    __shared__ float red[8][4];

    if (tid < 8) {
        int p = p0 + tid;
        prs[tid][0] = pair_idx[((size_t)b * PP + p) * 2 + 0];
        prs[tid][1] = pair_idx[((size_t)b * PP + p) * 2 + 1];
        prs[tid][2] = rel_ids[(size_t)b * PP + p];
    }
    __syncthreads();
    for (int idx = tid; idx < 8 * 160; idx += 256) {
        int q = idx / 160, k = idx % 160;
        float v;
        if (k < 64) v = x2[((size_t)b * EE + prs[q][0]) * 64 + k];
        else if (k < 128) v = x2[((size_t)b * EE + prs[q][1]) * 64 + (k - 64)];
        else v = rel_emb[prs[q][2] * RDD + (k - 128)];
        xv[q][k] = v;
    }
    __syncthreads();

    float acc[8];
    float bb = baseo[(size_t)b * 256 + tid];
#pragma unroll
    for (int q = 0; q < 8; q++) acc[q] = bb;
    const float* w = Wr1 + tid;
#pragma unroll 4
    for (int k = 0; k < 160; k++) {
        float wv = w[(size_t)k * 256];
#pragma unroll
        for (int q = 0; q < 8; q++) acc[q] += xv[q][k] * wv;
    }
    float w2v = Wr2[tid];
    int lane = tid & 63, wid = tid >> 6;
#pragma unroll
    for (int q = 0; q < 8; q++) {
        float pr = fmaxf(acc[q], 0.f) * w2v;
        for (int o = 32; o > 0; o >>= 1) pr += __shfl_down(pr, o, 64);
        if (lane == 0) red[q][wid] = pr;
    }
    __syncthreads();
    if (tid < 8) {
        float s = red[tid][0] + red[tid][1] + red[tid][2] + red[tid][3] + br2[0];
        out[(size_t)b * PP + p0 + tid] = s;
    }
}

// ---------------------------------------------------------------------------
extern "C" void kernel_launch(void* const* d_in, const int* in_sizes, int n_in,
                              void* d_out, int out_size, void* d_ws, size_t ws_size,
                              hipStream_t stream) {
    (void)in_sizes; (void)n_in; (void)out_size; (void)ws_size;
    const float* seq      = (const float*)d_in[0];
    const int*   starts   = (const int*)d_in[1];
    const int*   types    = (const int*)d_in[2];
    const int*   pair_idx = (const int*)d_in[3];
    const int*   rel_ids  = (const int*)d_in[4];
    const float* temb     = (const float*)d_in[5];
    const float* remb     = (const float*)d_in[6];
    const float* W1       = (const float*)d_in[7];
    const float* a_src1   = (const float*)d_in[8];
    const float* a_dst1   = (const float*)d_in[9];
    const float* b1       = (const float*)d_in[10];
    const float* ln1_g    = (const float*)d_in[11];
    const float* ln1_b    = (const float*)d_in[12];
    const float* W2       = (const float*)d_in[13];
    const float* a_src2   = (const float*)d_in[14];
    const float* a_dst2   = (const float*)d_in[15];
    const float* b2       = (const float*)d_in[16];
    const float* ln2_g    = (const float*)d_in[17];
    const float* ln2_b    = (const float*)d_in[18];
    const float* Wr1      = (const float*)d_in[19];
    const float* br1      = (const float*)d_in[20];
    const float* Wr2      = (const float*)d_in[21];
    const float* br2      = (const float*)d_in[22];
    float* out = (float*)d_out;

    float* ws = (float*)d_ws;
    // x region (4096*768 floats) repurposed: first half = x bf16, then Wt bf16
    unsigned short* xb = (unsigned short*)ws;            // 4096*768 bf16
    unsigned short* Wt = xb + (size_t)4096 * 768;        // 256*768 bf16
    float* h1   = ws + (size_t)4096 * 768;   // 4096*256
    float* s1   = h1 + 4096 * 256;           // 8192
    float* d1   = s1 + 8192;                 // 8192
    float* g1   = d1 + 8192;                 // 4096*256
    float* h2   = g1 + 4096 * 256;           // 4096*64
    float* s2   = h2 + 4096 * 64;            // 4096
    float* d2   = s2 + 4096;                 // 4096
    float* x2   = d2 + 4096;                 // 4096*64
    float* baseo = x2 + 4096 * 64;           // 32*256

    wt_conv_kernel<<<HHH, 256, 0, stream>>>(W1, Wt);
    pool_kernel<<<BB * EE, 256, 0, stream>>>(seq, starts, types, temb, br1, baseo, xb);
    base_partial_kernel<<<dim3(12, 32), 256, 0, stream>>>(seq, Wr1, baseo);
    gemm1_mfma_kernel<<<dim3(4, 64), 256, 0, stream>>>(xb, Wt, h1);
    sd1_kernel<<<BB * EE * 2, 64, 0, stream>>>(h1, a_src1, a_dst1, s1, d1);
    gat1_attn_kernel<<<BB * EE * 2, 128, 0, stream>>>(h1, s1, d1, b1, g1);
    ln_elu256_kernel<<<BB * EE, 256, 0, stream>>>(g1, ln1_g, ln1_b);
    gemm2_kernel<<<BB * EE, 64, 0, stream>>>(g1, W2, h2);
    sd2_kernel<<<BB * EE, 64, 0, stream>>>(h2, a_src2, a_dst2, s2, d2);
    gat2_kernel<<<BB * EE, 128, 0, stream>>>(h2, s2, d2, b2, ln2_g, ln2_b, x2);
    score_kernel<<<BB * PP / 8, 256, 0, stream>>>(x2, baseo, pair_idx, rel_ids,
                                                  remb, Wr1, Wr2, br2, out);
}

// Round 6
// 301.004 us; speedup vs baseline: 1.4722x; 1.0212x over previous
//
#include <hip/hip_runtime.h>
#include <hip/hip_bf16.h>

#define BB 32
#define SS 1024
#define HHH 768
#define EE 128
#define WW 8
#define PP 512
#define ND1 128
#define NH1 2
#define ND2 64
#define RDD 32

typedef __attribute__((ext_vector_type(8))) short bf16x8;
typedef __attribute__((ext_vector_type(8))) unsigned short us8;
typedef __attribute__((ext_vector_type(4))) float f32x4;

__device__ __forceinline__ unsigned short f2bf(float v) {
    __hip_bfloat16 h = __float2bfloat16(v);
    return *(unsigned short*)&h;
}

// ---------------------------------------------------------------------------
// K1: window gather + mean-query attention pooling + type embedding.
// grid = B*E blocks, 256 threads. Writes x as bf16. Blocks 0..31 also init
// baseo[b] = br1 (consumed by prep_kernel's atomicAdds, next launch).
// ---------------------------------------------------------------------------
__global__ __launch_bounds__(256) void pool_kernel(
    const float* __restrict__ seq, const int* __restrict__ starts,
    const int* __restrict__ types, const float* __restrict__ temb,
    const float* __restrict__ br1, float* __restrict__ baseo,
    unsigned short* __restrict__ xout) {
    int be = blockIdx.x;
    int b = be >> 7;
    int tid = threadIdx.x;
    __shared__ float toks[WW][HHH];
    __shared__ float scred[WW];
    __shared__ float attn_s[WW];

    if (be < BB) baseo[(size_t)be * 256 + tid] = br1[tid];

    int start = starts[be];
    // window base is (b*1024+start)*768 floats = multiple of 3072 B -> f4 ok
    const float4* bp4 = (const float4*)(seq + ((size_t)b * SS + start) * HHH);
    for (int idx = tid; idx < WW * (HHH / 4); idx += 256) {
        int w = idx / (HHH / 4), h4 = idx % (HHH / 4);
        float4 v = bp4[(size_t)w * (HHH / 4) + h4];
        toks[w][h4 * 4 + 0] = v.x; toks[w][h4 * 4 + 1] = v.y;
        toks[w][h4 * 4 + 2] = v.z; toks[w][h4 * 4 + 3] = v.w;
    }
    __syncthreads();

    float sc[WW];
#pragma unroll
    for (int w = 0; w < WW; w++) sc[w] = 0.f;
#pragma unroll
    for (int c = 0; c < 3; c++) {
        int h = tid + 256 * c;
        float s = 0.f;
#pragma unroll
        for (int w = 0; w < WW; w++) s += toks[w][h];
        float m = s * (1.0f / WW);
#pragma unroll
        for (int w = 0; w < WW; w++) sc[w] += toks[w][h] * m;
    }
    if (tid < WW) scred[tid] = 0.f;
    __syncthreads();
    int lane = tid & 63;
#pragma unroll
    for (int w = 0; w < WW; w++) {
        float v = sc[w];
        for (int o = 32; o > 0; o >>= 1) v += __shfl_down(v, o, 64);
        if (lane == 0) atomicAdd(&scred[w], v);
    }
    __syncthreads();
    if (tid == 0) {
        float mx = scred[0];
        for (int w = 1; w < WW; w++) mx = fmaxf(mx, scred[w]);
        float ssum = 0.f;
        float a[WW];
        for (int w = 0; w < WW; w++) { a[w] = __expf(scred[w] - mx); ssum += a[w]; }
        float inv = 1.f / ssum;
        for (int w = 0; w < WW; w++) attn_s[w] = a[w] * inv;
    }
    __syncthreads();

    int t = types[be];
    const float* emb = temb + (size_t)t * HHH;
#pragma unroll
    for (int c = 0; c < 3; c++) {
        int h = tid + 256 * c;
        float p = 0.f;
#pragma unroll
        for (int w = 0; w < WW; w++) p += attn_s[w] * toks[w][h];
        xout[(size_t)be * HHH + h] = f2bf(p + emb[h]);
    }
}

// ---------------------------------------------------------------------------
// K2: prep = (a) W1 transpose+bf16 -> Wt (blocks 0..47, 16 k's each)
//            (b) cls@Wr1[160:928] partials into baseo (blocks 48..431)
// ---------------------------------------------------------------------------
__global__ __launch_bounds__(256) void prep_kernel(
    const float* __restrict__ W1, unsigned short* __restrict__ Wt,
    const float* __restrict__ seq, const float* __restrict__ Wr1,
    float* __restrict__ baseo) {
    int blk = blockIdx.x;
    int tid = threadIdx.x;
    if (blk < 48) {
        __shared__ float wbuf[16][256];
        int k0 = blk * 16;
        for (int i = tid; i < 16 * 256; i += 256)
            wbuf[i >> 8][i & 255] = W1[(size_t)(k0 + (i >> 8)) * 256 + (i & 255)];
        __syncthreads();
        int n = tid;
        us8 v0, v1;
#pragma unroll
        for (int kk = 0; kk < 8; kk++) v0[kk] = f2bf(wbuf[kk][n]);
#pragma unroll
        for (int kk = 0; kk < 8; kk++) v1[kk] = f2bf(wbuf[8 + kk][n]);
        *(us8*)(Wt + (size_t)n * HHH + k0) = v0;
        *(us8*)(Wt + (size_t)n * HHH + k0 + 8) = v1;
    } else {
        int pc = blk - 48;
        int kc = pc % 12;
        int b = pc / 12;
        int n = tid;
        __shared__ float cls[64];
        if (n < 64) cls[n] = seq[(size_t)b * SS * HHH + kc * 64 + n];
        __syncthreads();
        float acc = 0.f;
        const float* w = Wr1 + (size_t)(160 + kc * 64) * 256 + n;
#pragma unroll 16
        for (int k = 0; k < 64; k++) acc += cls[k] * w[(size_t)k * 256];
        atomicAdd(&baseo[(size_t)b * 256 + n], acc);
    }
}

// ---------------------------------------------------------------------------
// K3: GEMM1 via MFMA bf16. Xb(4096x768) @ Wt^T -> h1(4096x256 fp32).
// ---------------------------------------------------------------------------
__global__ __launch_bounds__(256) void gemm1_mfma_kernel(
    const unsigned short* __restrict__ Xb, const unsigned short* __restrict__ Wt,
    float* __restrict__ C) {
    const int K = HHH;
    int n0 = blockIdx.x * 64;
    int m0 = blockIdx.y * 64;
    int tid = threadIdx.x;
    int wave = tid >> 6, lane = tid & 63;
    int wm = (wave >> 1) * 32, wn = (wave & 1) * 32;

    __shared__ __align__(16) unsigned short As[64][40];
    __shared__ __align__(16) unsigned short Bs[64][40];

    f32x4 acc[2][2] = {};
    int ar = tid >> 2;
    int ac = (tid & 3) * 8;
    int fr = lane & 15;
    int fk = (lane >> 4) * 8;

    for (int k0 = 0; k0 < K; k0 += 32) {
        us8 av = *(const us8*)(Xb + (size_t)(m0 + ar) * K + k0 + ac);
        us8 bv = *(const us8*)(Wt + (size_t)(n0 + ar) * K + k0 + ac);
        *(us8*)(&As[ar][ac]) = av;
        *(us8*)(&Bs[ar][ac]) = bv;
        __syncthreads();

        bf16x8 a0 = *(const bf16x8*)(&As[wm + fr][fk]);
        bf16x8 a1 = *(const bf16x8*)(&As[wm + 16 + fr][fk]);
        bf16x8 b0 = *(const bf16x8*)(&Bs[wn + fr][fk]);
        bf16x8 b1 = *(const bf16x8*)(&Bs[wn + 16 + fr][fk]);

        acc[0][0] = __builtin_amdgcn_mfma_f32_16x16x32_bf16(a0, b0, acc[0][0], 0, 0, 0);
        acc[0][1] = __builtin_amdgcn_mfma_f32_16x16x32_bf16(a0, b1, acc[0][1], 0, 0, 0);
        acc[1][0] = __builtin_amdgcn_mfma_f32_16x16x32_bf16(a1, b0, acc[1][0], 0, 0, 0);
        acc[1][1] = __builtin_amdgcn_mfma_f32_16x16x32_bf16(a1, b1, acc[1][1], 0, 0, 0);
        __syncthreads();
    }

    int crow = (lane >> 4) * 4;
    int ccol = lane & 15;
#pragma unroll
    for (int mi = 0; mi < 2; mi++)
#pragma unroll
        for (int ni = 0; ni < 2; ni++)
#pragma unroll
            for (int r = 0; r < 4; r++)
                C[(size_t)(m0 + wm + mi * 16 + crow + r) * 256 +
                  n0 + wn + ni * 16 + ccol] = acc[mi][ni][r];
}

// ---------------------------------------------------------------------------
// K4: per-(b,e,head) attention src/dst dots over D1=128
// ---------------------------------------------------------------------------
__global__ void sd1_kernel(const float* __restrict__ h1, const float* __restrict__ asrc,
                           const float* __restrict__ adst, float* __restrict__ s1,
                           float* __restrict__ d1) {
    int beh = blockIdx.x;
    int h = beh & 1;
    int be = beh >> 1;
    int lane = threadIdx.x;
    const float* row = h1 + (size_t)be * 256 + h * 128;
    float v0 = row[lane], v1 = row[lane + 64];
    float ss = v0 * asrc[h * 128 + lane] + v1 * asrc[h * 128 + lane + 64];
    float dd = v0 * adst[h * 128 + lane] + v1 * adst[h * 128 + lane + 64];
    for (int o = 32; o > 0; o >>= 1) {
        ss += __shfl_down(ss, o, 64);
        dd += __shfl_down(dd, o, 64);
    }
    if (lane == 0) { s1[beh] = ss; d1[beh] = dd; }
}

// ---------------------------------------------------------------------------
// K5: GAT1 attention (both heads) + bias + LayerNorm(256) + ELU fused.
// grid = B*E blocks (one per (b,i)), 256 threads: h = tid>>7, jj = tid&127.
// ---------------------------------------------------------------------------
__global__ __launch_bounds__(256) void gat1_ln_kernel(
    const float* __restrict__ h1, const float* __restrict__ s1,
    const float* __restrict__ d1, const float* __restrict__ b1,
    const float* __restrict__ gamma, const float* __restrict__ beta,
    float* __restrict__ g1) {
    int bi = blockIdx.x;          // global entity index b*128+i
    int b = bi >> 7;
    int tid = threadIdx.x;
    int h = tid >> 7;
    int jj = tid & 127;
    int lane = tid & 63, wid = tid >> 6;   // waves 0,1 -> h=0; 2,3 -> h=1
    __shared__ float alpha[2][128];
    __shared__ float red[4];

    float di = d1[bi * 2 + h];
    float sj = s1[((size_t)b * 128 + jj) * 2 + h];
    float ev = di + sj;
    ev = ev >= 0.f ? ev : 0.2f * ev;

    // per-head max
    float mx = ev;
    for (int o = 32; o > 0; o >>= 1) mx = fmaxf(mx, __shfl_down(mx, o, 64));
    if (lane == 0) red[wid] = mx;
    __syncthreads();
    mx = fmaxf(red[h * 2], red[h * 2 + 1]);
    __syncthreads();
    // per-head sum
    float ex = __expf(ev - mx);
    float sm = ex;
    for (int o = 32; o > 0; o >>= 1) sm += __shfl_down(sm, o, 64);
    if (lane == 0) red[wid] = sm;
    __syncthreads();
    sm = red[h * 2] + red[h * 2 + 1];
    alpha[h][jj] = ex / sm;
    __syncthreads();

    // matvec: output dim = tid (head h = tid>>7 matches alpha row)
    const float* hb = h1 + (size_t)b * 128 * 256 + tid;
    float o = 0.f;
#pragma unroll 8
    for (int j = 0; j < 128; j++) o += alpha[h][j] * hb[(size_t)j * 256];
    o += b1[tid];

    // LayerNorm(256) + ELU
    float s = o;
    for (int off = 32; off > 0; off >>= 1) s += __shfl_down(s, off, 64);
    if (lane == 0) red[wid] = s;
    __syncthreads();
    float mean = (red[0] + red[1] + red[2] + red[3]) * (1.f / 256.f);
    __syncthreads();
    float dv = o - mean;
    float sq = dv * dv;
    for (int off = 32; off > 0; off >>= 1) sq += __shfl_down(sq, off, 64);
    if (lane == 0) red[wid] = sq;
    __syncthreads();
    float var = (red[0] + red[1] + red[2] + red[3]) * (1.f / 256.f);
    float y = dv * rsqrtf(var + 1e-5f) * gamma[tid] + beta[tid];
    y = y > 0.f ? y : (__expf(y) - 1.f);
    g1[(size_t)bi * 256 + tid] = y;
}

// ---------------------------------------------------------------------------
// K6: GEMM2 x1(4096x256)@W2(256x64) -> h2, + fused sd2 dots (row in regs)
// ---------------------------------------------------------------------------
__global__ void gemm2_sd2_kernel(const float* __restrict__ x1,
                                 const float* __restrict__ W2,
                                 const float* __restrict__ asrc,
                                 const float* __restrict__ adst,
                                 float* __restrict__ h2,
                                 float* __restrict__ s2, float* __restrict__ d2) {
    int row = blockIdx.x;
    int lane = threadIdx.x;
    __shared__ float xr[256];
    for (int k = lane; k < 256; k += 64) xr[k] = x1[(size_t)row * 256 + k];
    __syncthreads();
    float acc = 0.f;
#pragma unroll 8
    for (int k = 0; k < 256; k++) acc += xr[k] * W2[k * 64 + lane];
    h2[(size_t)row * 64 + lane] = acc;
    float ss = acc * asrc[lane];
    float dd = acc * adst[lane];
    for (int o = 32; o > 0; o >>= 1) {
        ss += __shfl_down(ss, o, 64);
        dd += __shfl_down(dd, o, 64);
    }
    if (lane == 0) { s2[row] = ss; d2[row] = dd; }
}

// ---------------------------------------------------------------------------
// K7: GAT2 attention + bias + LayerNorm(64) + ELU -> x2
// ---------------------------------------------------------------------------
__global__ __launch_bounds__(128) void gat2_kernel(
    const float* __restrict__ h2, const float* __restrict__ s2,
    const float* __restrict__ d2, const float* __restrict__ b2v,
    const float* __restrict__ gamma, const float* __restrict__ beta,
    float* __restrict__ x2) {
    int bi = blockIdx.x;
    int b = bi >> 7;
    int tid = threadIdx.x;
    __shared__ float alpha[128];
    __shared__ float red[2];

    float ev = d2[bi] + s2[(size_t)b * 128 + tid];
    ev = ev >= 0.f ? ev : 0.2f * ev;
    float mx = ev;
    for (int o = 32; o > 0; o >>= 1) mx = fmaxf(mx, __shfl_down(mx, o, 64));
    int lane = tid & 63, wid = tid >> 6;
    if (lane == 0) red[wid] = mx;
    __syncthreads();
    mx = fmaxf(red[0], red[1]);
    __syncthreads();
    float ex = __expf(ev - mx);
    float sm = ex;
    for (int o = 32; o > 0; o >>= 1) sm += __shfl_down(sm, o, 64);
    if (lane == 0) red[wid] = sm;
    __syncthreads();
    sm = red[0] + red[1];
    alpha[tid] = ex / sm;
    __syncthreads();

    if (tid < 64) {
        const float* hb = h2 + (size_t)b * 128 * 64 + tid;
        float o = 0.f;
#pragma unroll 8
        for (int j = 0; j < 128; j++) o += alpha[j] * hb[(size_t)j * 64];
        o += b2v[tid];
        float s = o;
        for (int off = 32; off > 0; off >>= 1) s += __shfl_down(s, off, 64);
        s = __shfl(s, 0, 64);
        float mean = s * (1.f / 64.f);
        float dv = o - mean;
        float sq = dv * dv;
        for (int off = 32; off > 0; off >>= 1) sq += __shfl_down(sq, off, 64);
        sq = __shfl(sq, 0, 64);
        float var = sq * (1.f / 64.f);
        float y = dv * rsqrtf(var + 1e-5f) * gamma[tid] + beta[tid];
        y = y > 0.f ? y : (__expf(y) - 1.f);
        x2[(size_t)bi * 64 + tid] = y;
    }
}

// ---------------------------------------------------------------------------
// K8: final scores, 16 pairs per block; output fp32
// ---------------------------------------------------------------------------
__global__ __launch_bounds__(256) void score_kernel(
    const float* __restrict__ x2, const float* __restrict__ baseo,
    const int* __restrict__ pair_idx, const int* __restrict__ rel_ids,
    const float* __restrict__ rel_emb, const float* __restrict__ Wr1,
    const float* __restrict__ Wr2, const float* __restrict__ br2,
    float* __restrict__ out) {
    const int Q = 16;
    int blk = blockIdx.x;
    int b = blk >> 5;                 // 32 blocks per batch
    int p0 = (blk & 31) * Q;
    int tid = threadIdx.x;
    __shared__ float xv[Q][160];
    __shared__ int prs[Q][3];
    __shared__ float red[Q][4];

    if (tid < Q) {
        int p = p0 + tid;
        prs[tid][0] = pair_idx[((size_t)b * PP + p) * 2 + 0];
        prs[tid][1] = pair_idx[((size_t)b * PP + p) * 2 + 1];
        prs[tid][2] = rel_ids[(size_t)b * PP + p];
    }
    __syncthreads();
    for (int idx = tid; idx < Q * 160; idx += 256) {
        int q = idx / 160, k = idx % 160;
        float v;
        if (k < 64) v = x2[((size_t)b * EE + prs[q][0]) * 64 + k];
        else if (k < 128) v = x2[((size_t)b * EE + prs[q][1]) * 64 + (k - 64)];
        else v = rel_emb[prs[q][2] * RDD + (k - 128)];
        xv[q][k] = v;
    }
    __syncthreads();

    float acc[Q];
    float bb = baseo[(size_t)b * 256 + tid];
#pragma unroll
    for (int q = 0; q < Q; q++) acc[q] = bb;
    const float* w = Wr1 + tid;
#pragma unroll 4
    for (int k = 0; k < 160; k++) {
        float wv = w[(size_t)k * 256];
#pragma unroll
        for (int q = 0; q < Q; q++) acc[q] += xv[q][k] * wv;
    }
    float w2v = Wr2[tid];
    int lane = tid & 63, wid = tid >> 6;
#pragma unroll
    for (int q = 0; q < Q; q++) {
        float pr = fmaxf(acc[q], 0.f) * w2v;
        for (int o = 32; o > 0; o >>= 1) pr += __shfl_down(pr, o, 64);
        if (lane == 0) red[q][wid] = pr;
    }
    __syncthreads();
    if (tid < Q) {
        float s = red[tid][0] + red[tid][1] + red[tid][2] + red[tid][3] + br2[0];
        out[(size_t)b * PP + p0 + tid] = s;
    }
}

// ---------------------------------------------------------------------------
extern "C" void kernel_launch(void* const* d_in, const int* in_sizes, int n_in,
                              void* d_out, int out_size, void* d_ws, size_t ws_size,
                              hipStream_t stream) {
    (void)in_sizes; (void)n_in; (void)out_size; (void)ws_size;
    const float* seq      = (const float*)d_in[0];
    const int*   starts   = (const int*)d_in[1];
    const int*   types    = (const int*)d_in[2];
    const int*   pair_idx = (const int*)d_in[3];
    const int*   rel_ids  = (const int*)d_in[4];
    const float* temb     = (const float*)d_in[5];
    const float* remb     = (const float*)d_in[6];
    const float* W1       = (const float*)d_in[7];
    const float* a_src1   = (const float*)d_in[8];
    const float* a_dst1   = (const float*)d_in[9];
    const float* b1       = (const float*)d_in[10];
    const float* ln1_g    = (const float*)d_in[11];
    const float* ln1_b    = (const float*)d_in[12];
    const float* W2       = (const float*)d_in[13];
    const float* a_src2   = (const float*)d_in[14];
    const float* a_dst2   = (const float*)d_in[15];
    const float* b2       = (const float*)d_in[16];
    const float* ln2_g    = (const float*)d_in[17];
    const float* ln2_b    = (const float*)d_in[18];
    const float* Wr1      = (const float*)d_in[19];
    const float* br1      = (const float*)d_in[20];
    const float* Wr2      = (const float*)d_in[21];
    const float* br2      = (const float*)d_in[22];
    float* out = (float*)d_out;

    float* ws = (float*)d_ws;
    unsigned short* xb = (unsigned short*)ws;            // 4096*768 bf16
    unsigned short* Wt = xb + (size_t)4096 * 768;        // 256*768 bf16
    float* h1   = ws + (size_t)4096 * 768;   // 4096*256
    float* s1   = h1 + 4096 * 256;           // 8192
    float* d1   = s1 + 8192;                 // 8192
    float* g1   = d1 + 8192;                 // 4096*256
    float* h2   = g1 + 4096 * 256;           // 4096*64
    float* s2   = h2 + 4096 * 64;            // 4096
    float* d2   = s2 + 4096;                 // 4096
    float* x2   = d2 + 4096;                 // 4096*64
    float* baseo = x2 + 4096 * 64;           // 32*256

    pool_kernel<<<BB * EE, 256, 0, stream>>>(seq, starts, types, temb, br1, baseo, xb);
    prep_kernel<<<48 + 12 * 32, 256, 0, stream>>>(W1, Wt, seq, Wr1, baseo);
    gemm1_mfma_kernel<<<dim3(4, 64), 256, 0, stream>>>(xb, Wt, h1);
    sd1_kernel<<<BB * EE * 2, 64, 0, stream>>>(h1, a_src1, a_dst1, s1, d1);
    gat1_ln_kernel<<<BB * EE, 256, 0, stream>>>(h1, s1, d1, b1, ln1_g, ln1_b, g1);
    gemm2_sd2_kernel<<<BB * EE, 64, 0, stream>>>(g1, W2, a_src2, a_dst2, h2, s2, d2);
    gat2_kernel<<<BB * EE, 128, 0, stream>>>(h2, s2, d2, b2, ln2_g, ln2_b, x2);
    score_kernel<<<BB * PP / 16, 256, 0, stream>>>(x2, baseo, pair_idx, rel_ids,
                                                   remb, Wr1, Wr2, br2, out);
}

// Round 7
// 274.623 us; speedup vs baseline: 1.6136x; 1.0961x over previous
//
#include <hip/hip_runtime.h>
#include <hip/hip_bf16.h>

#define BB 32
#define SS 1024
#define HHH 768
#define EE 128
#define WW 8
#define PP 512
#define ND1 128
#define NH1 2
#define ND2 64
#define RDD 32

typedef __attribute__((ext_vector_type(8))) short bf16x8;
typedef __attribute__((ext_vector_type(8))) unsigned short us8;
typedef __attribute__((ext_vector_type(4))) float f32x4;

__device__ __forceinline__ unsigned short f2bf(float v) {
    __hip_bfloat16 h = __float2bfloat16(v);
    return *(unsigned short*)&h;
}
__device__ __forceinline__ float bf2f(unsigned short u) {
    unsigned int x = ((unsigned int)u) << 16;
    float f; __builtin_memcpy(&f, &x, 4);
    return f;
}

// ---------------------------------------------------------------------------
// K1: window gather + pooling + type embedding -> xb (bf16).
// Blocks 0..31 init baseo[b] = br1.
// ---------------------------------------------------------------------------
__global__ __launch_bounds__(256) void pool_kernel(
    const float* __restrict__ seq, const int* __restrict__ starts,
    const int* __restrict__ types, const float* __restrict__ temb,
    const float* __restrict__ br1, float* __restrict__ baseo,
    unsigned short* __restrict__ xout) {
    int be = blockIdx.x;
    int b = be >> 7;
    int tid = threadIdx.x;
    __shared__ float toks[WW][HHH];
    __shared__ float scred[WW];
    __shared__ float attn_s[WW];

    if (be < BB) baseo[(size_t)be * 256 + tid] = br1[tid];

    int start = starts[be];
    const float4* bp4 = (const float4*)(seq + ((size_t)b * SS + start) * HHH);
    for (int idx = tid; idx < WW * (HHH / 4); idx += 256) {
        int w = idx / (HHH / 4), h4 = idx % (HHH / 4);
        float4 v = bp4[(size_t)w * (HHH / 4) + h4];
        toks[w][h4 * 4 + 0] = v.x; toks[w][h4 * 4 + 1] = v.y;
        toks[w][h4 * 4 + 2] = v.z; toks[w][h4 * 4 + 3] = v.w;
    }
    __syncthreads();

    float sc[WW];
#pragma unroll
    for (int w = 0; w < WW; w++) sc[w] = 0.f;
#pragma unroll
    for (int c = 0; c < 3; c++) {
        int h = tid + 256 * c;
        float s = 0.f;
#pragma unroll
        for (int w = 0; w < WW; w++) s += toks[w][h];
        float m = s * (1.0f / WW);
#pragma unroll
        for (int w = 0; w < WW; w++) sc[w] += toks[w][h] * m;
    }
    if (tid < WW) scred[tid] = 0.f;
    __syncthreads();
    int lane = tid & 63;
#pragma unroll
    for (int w = 0; w < WW; w++) {
        float v = sc[w];
        for (int o = 32; o > 0; o >>= 1) v += __shfl_down(v, o, 64);
        if (lane == 0) atomicAdd(&scred[w], v);
    }
    __syncthreads();
    if (tid == 0) {
        float mx = scred[0];
        for (int w = 1; w < WW; w++) mx = fmaxf(mx, scred[w]);
        float ssum = 0.f;
        float a[WW];
        for (int w = 0; w < WW; w++) { a[w] = __expf(scred[w] - mx); ssum += a[w]; }
        float inv = 1.f / ssum;
        for (int w = 0; w < WW; w++) attn_s[w] = a[w] * inv;
    }
    __syncthreads();

    int t = types[be];
    const float* emb = temb + (size_t)t * HHH;
#pragma unroll
    for (int c = 0; c < 3; c++) {
        int h = tid + 256 * c;
        float p = 0.f;
#pragma unroll
        for (int w = 0; w < WW; w++) p += attn_s[w] * toks[w][h];
        xout[(size_t)be * HHH + h] = f2bf(p + emb[h]);
    }
}

// ---------------------------------------------------------------------------
// K2: prep. blocks 0..47: W1 -> Wt (256x768 bf16). 48..57: Wr1[0:160] -> Wtr
// (256x160 bf16). 58..73: W2 -> W2t (64x256 bf16). 74..457: base partials.
// ---------------------------------------------------------------------------
__global__ __launch_bounds__(256) void prep_kernel(
    const float* __restrict__ W1, unsigned short* __restrict__ Wt,
    const float* __restrict__ Wr1, unsigned short* __restrict__ Wtr,
    const float* __restrict__ W2, unsigned short* __restrict__ W2t,
    const float* __restrict__ seq, float* __restrict__ baseo) {
    int blk = blockIdx.x;
    int tid = threadIdx.x;
    __shared__ float wbuf[16][256];
    if (blk < 48) {
        int k0 = blk * 16;
        for (int i = tid; i < 16 * 256; i += 256)
            wbuf[i >> 8][i & 255] = W1[(size_t)(k0 + (i >> 8)) * 256 + (i & 255)];
        __syncthreads();
        int n = tid;
        us8 v0, v1;
#pragma unroll
        for (int kk = 0; kk < 8; kk++) v0[kk] = f2bf(wbuf[kk][n]);
#pragma unroll
        for (int kk = 0; kk < 8; kk++) v1[kk] = f2bf(wbuf[8 + kk][n]);
        *(us8*)(Wt + (size_t)n * HHH + k0) = v0;
        *(us8*)(Wt + (size_t)n * HHH + k0 + 8) = v1;
    } else if (blk < 58) {
        int k0 = (blk - 48) * 16;
        for (int i = tid; i < 16 * 256; i += 256)
            wbuf[i >> 8][i & 255] = Wr1[(size_t)(k0 + (i >> 8)) * 256 + (i & 255)];
        __syncthreads();
        int n = tid;
        us8 v0, v1;
#pragma unroll
        for (int kk = 0; kk < 8; kk++) v0[kk] = f2bf(wbuf[kk][n]);
#pragma unroll
        for (int kk = 0; kk < 8; kk++) v1[kk] = f2bf(wbuf[8 + kk][n]);
        *(us8*)(Wtr + (size_t)n * 160 + k0) = v0;
        *(us8*)(Wtr + (size_t)n * 160 + k0 + 8) = v1;
    } else if (blk < 74) {
        int k0 = (blk - 58) * 16;
        for (int i = tid; i < 16 * 64; i += 256)
            wbuf[i >> 6][i & 63] = W2[(size_t)(k0 + (i >> 6)) * 64 + (i & 63)];
        __syncthreads();
        if (tid < 64) {
            int n = tid;
            us8 v0, v1;
#pragma unroll
            for (int kk = 0; kk < 8; kk++) v0[kk] = f2bf(wbuf[kk][n]);
#pragma unroll
            for (int kk = 0; kk < 8; kk++) v1[kk] = f2bf(wbuf[8 + kk][n]);
            *(us8*)(W2t + (size_t)n * 256 + k0) = v0;
            *(us8*)(W2t + (size_t)n * 256 + k0 + 8) = v1;
        }
    } else {
        int pc = blk - 74;
        int kc = pc % 12;
        int b = pc / 12;
        int n = tid;
        __shared__ float cls[64];
        if (n < 64) cls[n] = seq[(size_t)b * SS * HHH + kc * 64 + n];
        __syncthreads();
        float acc = 0.f;
        const float* w = Wr1 + (size_t)(160 + kc * 64) * 256 + n;
#pragma unroll 16
        for (int k = 0; k < 64; k++) acc += cls[k] * w[(size_t)k * 256];
        atomicAdd(&baseo[(size_t)b * 256 + n], acc);
    }
}

// ---------------------------------------------------------------------------
// K3: GEMM1 via MFMA bf16. Xb(4096x768) @ Wt^T -> h1(4096x256 fp32).
// ---------------------------------------------------------------------------
__global__ __launch_bounds__(256) void gemm1_mfma_kernel(
    const unsigned short* __restrict__ Xb, const unsigned short* __restrict__ Wt,
    float* __restrict__ C) {
    const int K = HHH;
    int n0 = blockIdx.x * 64;
    int m0 = blockIdx.y * 64;
    int tid = threadIdx.x;
    int wave = tid >> 6, lane = tid & 63;
    int wm = (wave >> 1) * 32, wn = (wave & 1) * 32;

    __shared__ __align__(16) unsigned short As[64][40];
    __shared__ __align__(16) unsigned short Bs[64][40];

    f32x4 acc[2][2] = {};
    int ar = tid >> 2;
    int ac = (tid & 3) * 8;
    int fr = lane & 15;
    int fk = (lane >> 4) * 8;

    for (int k0 = 0; k0 < K; k0 += 32) {
        us8 av = *(const us8*)(Xb + (size_t)(m0 + ar) * K + k0 + ac);
        us8 bv = *(const us8*)(Wt + (size_t)(n0 + ar) * K + k0 + ac);
        *(us8*)(&As[ar][ac]) = av;
        *(us8*)(&Bs[ar][ac]) = bv;
        __syncthreads();

        bf16x8 a0 = *(const bf16x8*)(&As[wm + fr][fk]);
        bf16x8 a1 = *(const bf16x8*)(&As[wm + 16 + fr][fk]);
        bf16x8 b0 = *(const bf16x8*)(&Bs[wn + fr][fk]);
        bf16x8 b1 = *(const bf16x8*)(&Bs[wn + 16 + fr][fk]);

        acc[0][0] = __builtin_amdgcn_mfma_f32_16x16x32_bf16(a0, b0, acc[0][0], 0, 0, 0);
        acc[0][1] = __builtin_amdgcn_mfma_f32_16x16x32_bf16(a0, b1, acc[0][1], 0, 0, 0);
        acc[1][0] = __builtin_amdgcn_mfma_f32_16x16x32_bf16(a1, b0, acc[1][0], 0, 0, 0);
        acc[1][1] = __builtin_amdgcn_mfma_f32_16x16x32_bf16(a1, b1, acc[1][1], 0, 0, 0);
        __syncthreads();
    }

    int crow = (lane >> 4) * 4;
    int ccol = lane & 15;
#pragma unroll
    for (int mi = 0; mi < 2; mi++)
#pragma unroll
        for (int ni = 0; ni < 2; ni++)
#pragma unroll
            for (int r = 0; r < 4; r++)
                C[(size_t)(m0 + wm + mi * 16 + crow + r) * 256 +
                  n0 + wn + ni * 16 + ccol] = acc[mi][ni][r];
}

// ---------------------------------------------------------------------------
// K4: per-(b,e,head) attention src/dst dots over D1=128
// ---------------------------------------------------------------------------
__global__ void sd1_kernel(const float* __restrict__ h1, const float* __restrict__ asrc,
                           const float* __restrict__ adst, float* __restrict__ s1,
                           float* __restrict__ d1) {
    int beh = blockIdx.x;
    int h = beh & 1;
    int be = beh >> 1;
    int lane = threadIdx.x;
    const float* row = h1 + (size_t)be * 256 + h * 128;
    float v0 = row[lane], v1 = row[lane + 64];
    float ss = v0 * asrc[h * 128 + lane] + v1 * asrc[h * 128 + lane + 64];
    float dd = v0 * adst[h * 128 + lane] + v1 * adst[h * 128 + lane + 64];
    for (int o = 32; o > 0; o >>= 1) {
        ss += __shfl_down(ss, o, 64);
        dd += __shfl_down(dd, o, 64);
    }
    if (lane == 0) { s1[beh] = ss; d1[beh] = dd; }
}

// ---------------------------------------------------------------------------
// K5: GAT1 attention (both heads) + bias + LayerNorm(256) + ELU -> g1b (bf16)
// ---------------------------------------------------------------------------
__global__ __launch_bounds__(256) void gat1_ln_kernel(
    const float* __restrict__ h1, const float* __restrict__ s1,
    const float* __restrict__ d1, const float* __restrict__ b1,
    const float* __restrict__ gamma, const float* __restrict__ beta,
    unsigned short* __restrict__ g1b) {
    int bi = blockIdx.x;
    int b = bi >> 7;
    int tid = threadIdx.x;
    int h = tid >> 7;
    int jj = tid & 127;
    int lane = tid & 63, wid = tid >> 6;
    __shared__ float alpha[2][128];
    __shared__ float red[4];

    float di = d1[bi * 2 + h];
    float sj = s1[((size_t)b * 128 + jj) * 2 + h];
    float ev = di + sj;
    ev = ev >= 0.f ? ev : 0.2f * ev;

    float mx = ev;
    for (int o = 32; o > 0; o >>= 1) mx = fmaxf(mx, __shfl_down(mx, o, 64));
    if (lane == 0) red[wid] = mx;
    __syncthreads();
    mx = fmaxf(red[h * 2], red[h * 2 + 1]);
    __syncthreads();
    float ex = __expf(ev - mx);
    float sm = ex;
    for (int o = 32; o > 0; o >>= 1) sm += __shfl_down(sm, o, 64);
    if (lane == 0) red[wid] = sm;
    __syncthreads();
    sm = red[h * 2] + red[h * 2 + 1];
    alpha[h][jj] = ex / sm;
    __syncthreads();

    const float* hb = h1 + (size_t)b * 128 * 256 + tid;
    float o = 0.f;
#pragma unroll 8
    for (int j = 0; j < 128; j++) o += alpha[h][j] * hb[(size_t)j * 256];
    o += b1[tid];

    float s = o;
    for (int off = 32; off > 0; off >>= 1) s += __shfl_down(s, off, 64);
    if (lane == 0) red[wid] = s;
    __syncthreads();
    float mean = (red[0] + red[1] + red[2] + red[3]) * (1.f / 256.f);
    __syncthreads();
    float dv = o - mean;
    float sq = dv * dv;
    for (int off = 32; off > 0; off >>= 1) sq += __shfl_down(sq, off, 64);
    if (lane == 0) red[wid] = sq;
    __syncthreads();
    float var = (red[0] + red[1] + red[2] + red[3]) * (1.f / 256.f);
    float y = dv * rsqrtf(var + 1e-5f) * gamma[tid] + beta[tid];
    y = y > 0.f ? y : (__expf(y) - 1.f);
    g1b[(size_t)bi * 256 + tid] = f2bf(y);
}

// ---------------------------------------------------------------------------
// K6: GEMM2 via MFMA: g1b(4096x256 bf16) @ W2t^T -> h2(4096x64 fp32),
// fused sd2 dots. grid = 64 blocks (64 rows each), 256 threads.
// ---------------------------------------------------------------------------
__global__ __launch_bounds__(256) void gemm2_mfma_kernel(
    const unsigned short* __restrict__ g1b, const unsigned short* __restrict__ W2t,
    const float* __restrict__ asrc, const float* __restrict__ adst,
    float* __restrict__ h2, float* __restrict__ s2, float* __restrict__ d2) {
    int m0 = blockIdx.x * 64;
    int tid = threadIdx.x;
    int wave = tid >> 6, lane = tid & 63;
    int wm = (wave >> 1) * 32, wn = (wave & 1) * 32;

    __shared__ __align__(16) unsigned short As[64][72];
    __shared__ __align__(16) unsigned short Bs[64][72];
    __shared__ float sdred[64][2][2];

    f32x4 acc[2][2] = {};
    int fr = lane & 15;
    int fk = (lane >> 4) * 8;

    for (int kc = 0; kc < 4; kc++) {
        // stage 64 rows x 64 k of A and B (8 us8 per row)
        for (int it = 0; it < 2; it++) {
            int i = tid + it * 256;          // 0..511
            int row = i >> 3, c = i & 7;
            *(us8*)(&As[row][c * 8]) =
                *(const us8*)(g1b + (size_t)(m0 + row) * 256 + kc * 64 + c * 8);
            *(us8*)(&Bs[row][c * 8]) =
                *(const us8*)(W2t + (size_t)row * 256 + kc * 64 + c * 8);
        }
        __syncthreads();
#pragma unroll
        for (int ks = 0; ks < 2; ks++) {
            int kb = ks * 32 + fk;
            bf16x8 a0 = *(const bf16x8*)(&As[wm + fr][kb]);
            bf16x8 a1 = *(const bf16x8*)(&As[wm + 16 + fr][kb]);
            bf16x8 b0 = *(const bf16x8*)(&Bs[wn + fr][kb]);
            bf16x8 b1 = *(const bf16x8*)(&Bs[wn + 16 + fr][kb]);
            acc[0][0] = __builtin_amdgcn_mfma_f32_16x16x32_bf16(a0, b0, acc[0][0], 0, 0, 0);
            acc[0][1] = __builtin_amdgcn_mfma_f32_16x16x32_bf16(a0, b1, acc[0][1], 0, 0, 0);
            acc[1][0] = __builtin_amdgcn_mfma_f32_16x16x32_bf16(a1, b0, acc[1][0], 0, 0, 0);
            acc[1][1] = __builtin_amdgcn_mfma_f32_16x16x32_bf16(a1, b1, acc[1][1], 0, 0, 0);
        }
        __syncthreads();
    }

    int crow = (lane >> 4) * 4;
    int ccol = lane & 15;
    float asv[2], adv[2];
#pragma unroll
    for (int ni = 0; ni < 2; ni++) {
        int n = wn + ni * 16 + ccol;
        asv[ni] = asrc[n];
        adv[ni] = adst[n];
    }
#pragma unroll
    for (int mi = 0; mi < 2; mi++) {
#pragma unroll
        for (int r = 0; r < 4; r++) {
            float sp = 0.f, dp = 0.f;
#pragma unroll
            for (int ni = 0; ni < 2; ni++) {
                float v = acc[mi][ni][r];
                h2[(size_t)(m0 + wm + mi * 16 + crow + r) * 64 +
                   wn + ni * 16 + ccol] = v;
                sp += v * asv[ni];
                dp += v * adv[ni];
            }
            // reduce over 16 lanes of the quad
            for (int msk = 1; msk < 16; msk <<= 1) {
                sp += __shfl_xor(sp, msk, 64);
                dp += __shfl_xor(dp, msk, 64);
            }
            if ((lane & 15) == 0) {
                int row = wm + mi * 16 + crow + r;
                sdred[row][wn >> 5][0] = sp;
                sdred[row][wn >> 5][1] = dp;
            }
        }
    }
    __syncthreads();
    if (tid < 64 && wave == 0) {
        s2[m0 + tid] = sdred[tid][0][0] + sdred[tid][1][0];
        d2[m0 + tid] = sdred[tid][0][1] + sdred[tid][1][1];
    }
}

// ---------------------------------------------------------------------------
// K7: GAT2 attention + bias + LayerNorm(64) + ELU -> x2
// ---------------------------------------------------------------------------
__global__ __launch_bounds__(128) void gat2_kernel(
    const float* __restrict__ h2, const float* __restrict__ s2,
    const float* __restrict__ d2, const float* __restrict__ b2v,
    const float* __restrict__ gamma, const float* __restrict__ beta,
    float* __restrict__ x2) {
    int bi = blockIdx.x;
    int b = bi >> 7;
    int tid = threadIdx.x;
    __shared__ float alpha[128];
    __shared__ float red[2];

    float ev = d2[bi] + s2[(size_t)b * 128 + tid];
    ev = ev >= 0.f ? ev : 0.2f * ev;
    float mx = ev;
    for (int o = 32; o > 0; o >>= 1) mx = fmaxf(mx, __shfl_down(mx, o, 64));
    int lane = tid & 63, wid = tid >> 6;
    if (lane == 0) red[wid] = mx;
    __syncthreads();
    mx = fmaxf(red[0], red[1]);
    __syncthreads();
    float ex = __expf(ev - mx);
    float sm = ex;
    for (int o = 32; o > 0; o >>= 1) sm += __shfl_down(sm, o, 64);
    if (lane == 0) red[wid] = sm;
    __syncthreads();
    sm = red[0] + red[1];
    alpha[tid] = ex / sm;
    __syncthreads();

    if (tid < 64) {
        const float* hb = h2 + (size_t)b * 128 * 64 + tid;
        float o = 0.f;
#pragma unroll 8
        for (int j = 0; j < 128; j++) o += alpha[j] * hb[(size_t)j * 64];
        o += b2v[tid];
        float s = o;
        for (int off = 32; off > 0; off >>= 1) s += __shfl_down(s, off, 64);
        s = __shfl(s, 0, 64);
        float mean = s * (1.f / 64.f);
        float dv = o - mean;
        float sq = dv * dv;
        for (int off = 32; off > 0; off >>= 1) sq += __shfl_down(sq, off, 64);
        sq = __shfl(sq, 0, 64);
        float var = sq * (1.f / 64.f);
        float y = dv * rsqrtf(var + 1e-5f) * gamma[tid] + beta[tid];
        y = y > 0.f ? y : (__expf(y) - 1.f);
        x2[(size_t)bi * 64 + tid] = y;
    }
}

// ---------------------------------------------------------------------------
// K8: scores via MFMA. 64 pairs per block, N=256 (4 waves x 64), K=160.
// As staged once (pair vectors, bf16); Bs (Wtr) chunked by 32.
// Epilogue: relu(acc+base)*Wr2, quad-reduce, LDS combine -> out.
// ---------------------------------------------------------------------------
__global__ __launch_bounds__(256) void score_mfma_kernel(
    const float* __restrict__ x2, const float* __restrict__ baseo,
    const int* __restrict__ pair_idx, const int* __restrict__ rel_ids,
    const float* __restrict__ rel_emb, const unsigned short* __restrict__ Wtr,
    const float* __restrict__ Wr2, const float* __restrict__ br2,
    float* __restrict__ out) {
    int blk = blockIdx.x;
    int b = blk >> 3;
    int p0 = (blk & 7) * 64;
    int tid = threadIdx.x;
    int wave = tid >> 6, lane = tid & 63;
    int wn = wave * 64;

    __shared__ __align__(16) unsigned short As[64][168];
    __shared__ __align__(16) unsigned short Bs[256][40];
    __shared__ float sred[64][4];
    __shared__ int prs[64][3];

    if (tid < 64) {
        int p = p0 + tid;
        prs[tid][0] = pair_idx[((size_t)b * PP + p) * 2 + 0];
        prs[tid][1] = pair_idx[((size_t)b * PP + p) * 2 + 1];
        prs[tid][2] = rel_ids[(size_t)b * PP + p];
    }
    __syncthreads();
    // stage As: 64 pairs x 160 (bf16)
    for (int it = 0; it < 40; it++) {
        int i = tid + it * 256;
        int m = i / 160, k = i % 160;
        float v;
        if (k < 64) v = x2[((size_t)b * EE + prs[m][0]) * 64 + k];
        else if (k < 128) v = x2[((size_t)b * EE + prs[m][1]) * 64 + (k - 64)];
        else v = rel_emb[prs[m][2] * RDD + (k - 128)];
        As[m][k] = f2bf(v);
    }

    f32x4 acc[4][4] = {};
    int fr = lane & 15;
    int fk = (lane >> 4) * 8;

    for (int kc = 0; kc < 5; kc++) {
        // stage Bs chunk: 256 n x 32 k
        for (int it = 0; it < 4; it++) {
            int i = tid + it * 256;     // 0..1023
            int n = i >> 2, c = i & 3;
            *(us8*)(&Bs[n][c * 8]) =
                *(const us8*)(Wtr + (size_t)n * 160 + kc * 32 + c * 8);
        }
        __syncthreads();
        bf16x8 a[4], bv[4];
#pragma unroll
        for (int mi = 0; mi < 4; mi++)
            a[mi] = *(const bf16x8*)(&As[mi * 16 + fr][kc * 32 + fk]);
#pragma unroll
        for (int ni = 0; ni < 4; ni++)
            bv[ni] = *(const bf16x8*)(&Bs[wn + ni * 16 + fr][fk]);
#pragma unroll
        for (int mi = 0; mi < 4; mi++)
#pragma unroll
            for (int ni = 0; ni < 4; ni++)
                acc[mi][ni] = __builtin_amdgcn_mfma_f32_16x16x32_bf16(
                    a[mi], bv[ni], acc[mi][ni], 0, 0, 0);
        __syncthreads();
    }

    int crow = (lane >> 4) * 4;
    int ccol = lane & 15;
    float basev[4], w2v[4];
#pragma unroll
    for (int ni = 0; ni < 4; ni++) {
        int n = wn + ni * 16 + ccol;
        basev[ni] = baseo[(size_t)b * 256 + n];
        w2v[ni] = Wr2[n];
    }
#pragma unroll
    for (int mi = 0; mi < 4; mi++) {
#pragma unroll
        for (int r = 0; r < 4; r++) {
            float p = 0.f;
#pragma unroll
            for (int ni = 0; ni < 4; ni++)
                p += fmaxf(acc[mi][ni][r] + basev[ni], 0.f) * w2v[ni];
            for (int msk = 1; msk < 16; msk <<= 1)
                p += __shfl_xor(p, msk, 64);
            if ((lane & 15) == 0)
                sred[mi * 16 + crow + r][wave] = p;
        }
    }
    __syncthreads();
    if (tid < 64) {
        float s = sred[tid][0] + sred[tid][1] + sred[tid][2] + sred[tid][3] + br2[0];
        out[(size_t)b * PP + p0 + tid] = s;
    }
}

// ---------------------------------------------------------------------------
extern "C" void kernel_launch(void* const* d_in, const int* in_sizes, int n_in,
                              void* d_out, int out_size, void* d_ws, size_t ws_size,
                              hipStream_t stream) {
    (void)in_sizes; (void)n_in; (void)out_size; (void)ws_size;
    const float* seq      = (const float*)d_in[0];
    const int*   starts   = (const int*)d_in[1];
    const int*   types    = (const int*)d_in[2];
    const int*   pair_idx = (const int*)d_in[3];
    const int*   rel_ids  = (const int*)d_in[4];
    const float* temb     = (const float*)d_in[5];
    const float* remb     = (const float*)d_in[6];
    const float* W1       = (const float*)d_in[7];
    const float* a_src1   = (const float*)d_in[8];
    const float* a_dst1   = (const float*)d_in[9];
    const float* b1       = (const float*)d_in[10];
    const float* ln1_g    = (const float*)d_in[11];
    const float* ln1_b    = (const float*)d_in[12];
    const float* W2       = (const float*)d_in[13];
    const float* a_src2   = (const float*)d_in[14];
    const float* a_dst2   = (const float*)d_in[15];
    const float* b2       = (const float*)d_in[16];
    const float* ln2_g    = (const float*)d_in[17];
    const float* ln2_b    = (const float*)d_in[18];
    const float* Wr1      = (const float*)d_in[19];
    const float* br1      = (const float*)d_in[20];
    const float* Wr2      = (const float*)d_in[21];
    const float* br2      = (const float*)d_in[22];
    float* out = (float*)d_out;

    unsigned short* xb  = (unsigned short*)d_ws;         // 4096*768
    unsigned short* Wt  = xb + (size_t)4096 * 768;       // 256*768
    unsigned short* Wtr = Wt + (size_t)256 * 768;        // 256*160
    unsigned short* W2t = Wtr + (size_t)256 * 160;       // 64*256
    unsigned short* g1b = W2t + (size_t)64 * 256;        // 4096*256
    float* fbase = (float*)(g1b + (size_t)4096 * 256);
    float* h1   = fbase;                     // 4096*256
    float* s1   = h1 + (size_t)4096 * 256;   // 8192
    float* d1   = s1 + 8192;                 // 8192
    float* h2   = d1 + 8192;                 // 4096*64
    float* s2   = h2 + (size_t)4096 * 64;    // 4096
    float* d2   = s2 + 4096;                 // 4096
    float* x2   = d2 + 4096;                 // 4096*64
    float* baseo = x2 + (size_t)4096 * 64;   // 32*256

    pool_kernel<<<BB * EE, 256, 0, stream>>>(seq, starts, types, temb, br1, baseo, xb);
    prep_kernel<<<74 + 12 * 32, 256, 0, stream>>>(W1, Wt, Wr1, Wtr, W2, W2t, seq, baseo);
    gemm1_mfma_kernel<<<dim3(4, 64), 256, 0, stream>>>(xb, Wt, h1);
    sd1_kernel<<<BB * EE * 2, 64, 0, stream>>>(h1, a_src1, a_dst1, s1, d1);
    gat1_ln_kernel<<<BB * EE, 256, 0, stream>>>(h1, s1, d1, b1, ln1_g, ln1_b, g1b);
    gemm2_mfma_kernel<<<64, 256, 0, stream>>>(g1b, W2t, a_src2, a_dst2, h2, s2, d2);
    gat2_kernel<<<BB * EE, 128, 0, stream>>>(h2, s2, d2, b2, ln2_g, ln2_b, x2);
    score_mfma_kernel<<<BB * PP / 64, 256, 0, stream>>>(x2, baseo, pair_idx, rel_ids,
                                                        remb, Wtr, Wr2, br2, out);
}

// Round 8
// 260.221 us; speedup vs baseline: 1.7030x; 1.0553x over previous
//
#include <hip/hip_runtime.h>
#include <hip/hip_bf16.h>

#define BB 32
#define SS 1024
#define HHH 768
#define EE 128
#define WW 8
#define PP 512
#define ND1 128
#define NH1 2
#define ND2 64
#define RDD 32

typedef __attribute__((ext_vector_type(8))) short bf16x8;
typedef __attribute__((ext_vector_type(8))) unsigned short us8;
typedef __attribute__((ext_vector_type(4))) float f32x4;

__device__ __forceinline__ unsigned short f2bf(float v) {
    __hip_bfloat16 h = __float2bfloat16(v);
    return *(unsigned short*)&h;
}
__device__ __forceinline__ float bf2f(unsigned short u) {
    unsigned int x = ((unsigned int)u) << 16;
    float f; __builtin_memcpy(&f, &x, 4);
    return f;
}

// ---------------------------------------------------------------------------
// K1: window gather + pooling + type embedding -> xb (bf16).
// Blocks 0..31 init baseo[b] = br1.
// ---------------------------------------------------------------------------
__global__ __launch_bounds__(256) void pool_kernel(
    const float* __restrict__ seq, const int* __restrict__ starts,
    const int* __restrict__ types, const float* __restrict__ temb,
    const float* __restrict__ br1, float* __restrict__ baseo,
    unsigned short* __restrict__ xout) {
    int be = blockIdx.x;
    int b = be >> 7;
    int tid = threadIdx.x;
    __shared__ float toks[WW][HHH];
    __shared__ float scred[WW];
    __shared__ float attn_s[WW];

    if (be < BB) baseo[(size_t)be * 256 + tid] = br1[tid];

    int start = starts[be];
    const float4* bp4 = (const float4*)(seq + ((size_t)b * SS + start) * HHH);
    for (int idx = tid; idx < WW * (HHH / 4); idx += 256) {
        int w = idx / (HHH / 4), h4 = idx % (HHH / 4);
        float4 v = bp4[(size_t)w * (HHH / 4) + h4];
        toks[w][h4 * 4 + 0] = v.x; toks[w][h4 * 4 + 1] = v.y;
        toks[w][h4 * 4 + 2] = v.z; toks[w][h4 * 4 + 3] = v.w;
    }
    __syncthreads();

    float sc[WW];
#pragma unroll
    for (int w = 0; w < WW; w++) sc[w] = 0.f;
#pragma unroll
    for (int c = 0; c < 3; c++) {
        int h = tid + 256 * c;
        float s = 0.f;
#pragma unroll
        for (int w = 0; w < WW; w++) s += toks[w][h];
        float m = s * (1.0f / WW);
#pragma unroll
        for (int w = 0; w < WW; w++) sc[w] += toks[w][h] * m;
    }
    if (tid < WW) scred[tid] = 0.f;
    __syncthreads();
    int lane = tid & 63;
#pragma unroll
    for (int w = 0; w < WW; w++) {
        float v = sc[w];
        for (int o = 32; o > 0; o >>= 1) v += __shfl_down(v, o, 64);
        if (lane == 0) atomicAdd(&scred[w], v);
    }
    __syncthreads();
    if (tid == 0) {
        float mx = scred[0];
        for (int w = 1; w < WW; w++) mx = fmaxf(mx, scred[w]);
        float ssum = 0.f;
        float a[WW];
        for (int w = 0; w < WW; w++) { a[w] = __expf(scred[w] - mx); ssum += a[w]; }
        float inv = 1.f / ssum;
        for (int w = 0; w < WW; w++) attn_s[w] = a[w] * inv;
    }
    __syncthreads();

    int t = types[be];
    const float* emb = temb + (size_t)t * HHH;
#pragma unroll
    for (int c = 0; c < 3; c++) {
        int h = tid + 256 * c;
        float p = 0.f;
#pragma unroll
        for (int w = 0; w < WW; w++) p += attn_s[w] * toks[w][h];
        xout[(size_t)be * HHH + h] = f2bf(p + emb[h]);
    }
}

// ---------------------------------------------------------------------------
// K2: prep. blocks 0..47: W1 -> Wt. 48..57: Wr1[0:160] -> Wtr. 58..73: W2 ->
// W2t. 74..457: base partials.
// ---------------------------------------------------------------------------
__global__ __launch_bounds__(256) void prep_kernel(
    const float* __restrict__ W1, unsigned short* __restrict__ Wt,
    const float* __restrict__ Wr1, unsigned short* __restrict__ Wtr,
    const float* __restrict__ W2, unsigned short* __restrict__ W2t,
    const float* __restrict__ seq, float* __restrict__ baseo) {
    int blk = blockIdx.x;
    int tid = threadIdx.x;
    __shared__ float wbuf[16][256];
    if (blk < 48) {
        int k0 = blk * 16;
        for (int i = tid; i < 16 * 256; i += 256)
            wbuf[i >> 8][i & 255] = W1[(size_t)(k0 + (i >> 8)) * 256 + (i & 255)];
        __syncthreads();
        int n = tid;
        us8 v0, v1;
#pragma unroll
        for (int kk = 0; kk < 8; kk++) v0[kk] = f2bf(wbuf[kk][n]);
#pragma unroll
        for (int kk = 0; kk < 8; kk++) v1[kk] = f2bf(wbuf[8 + kk][n]);
        *(us8*)(Wt + (size_t)n * HHH + k0) = v0;
        *(us8*)(Wt + (size_t)n * HHH + k0 + 8) = v1;
    } else if (blk < 58) {
        int k0 = (blk - 48) * 16;
        for (int i = tid; i < 16 * 256; i += 256)
            wbuf[i >> 8][i & 255] = Wr1[(size_t)(k0 + (i >> 8)) * 256 + (i & 255)];
        __syncthreads();
        int n = tid;
        us8 v0, v1;
#pragma unroll
        for (int kk = 0; kk < 8; kk++) v0[kk] = f2bf(wbuf[kk][n]);
#pragma unroll
        for (int kk = 0; kk < 8; kk++) v1[kk] = f2bf(wbuf[8 + kk][n]);
        *(us8*)(Wtr + (size_t)n * 160 + k0) = v0;
        *(us8*)(Wtr + (size_t)n * 160 + k0 + 8) = v1;
    } else if (blk < 74) {
        int k0 = (blk - 58) * 16;
        for (int i = tid; i < 16 * 64; i += 256)
            wbuf[i >> 6][i & 63] = W2[(size_t)(k0 + (i >> 6)) * 64 + (i & 63)];
        __syncthreads();
        if (tid < 64) {
            int n = tid;
            us8 v0, v1;
#pragma unroll
            for (int kk = 0; kk < 8; kk++) v0[kk] = f2bf(wbuf[kk][n]);
#pragma unroll
            for (int kk = 0; kk < 8; kk++) v1[kk] = f2bf(wbuf[8 + kk][n]);
            *(us8*)(W2t + (size_t)n * 256 + k0) = v0;
            *(us8*)(W2t + (size_t)n * 256 + k0 + 8) = v1;
        }
    } else {
        int pc = blk - 74;
        int kc = pc % 12;
        int b = pc / 12;
        int n = tid;
        __shared__ float cls[64];
        if (n < 64) cls[n] = seq[(size_t)b * SS * HHH + kc * 64 + n];
        __syncthreads();
        float acc = 0.f;
        const float* w = Wr1 + (size_t)(160 + kc * 64) * 256 + n;
#pragma unroll 16
        for (int k = 0; k < 64; k++) acc += cls[k] * w[(size_t)k * 256];
        atomicAdd(&baseo[(size_t)b * 256 + n], acc);
    }
}

// ---------------------------------------------------------------------------
// K3: GEMM1 via MFMA bf16. Xb(4096x768) @ Wt^T -> h1(4096x256 fp32).
// ---------------------------------------------------------------------------
__global__ __launch_bounds__(256) void gemm1_mfma_kernel(
    const unsigned short* __restrict__ Xb, const unsigned short* __restrict__ Wt,
    float* __restrict__ C) {
    const int K = HHH;
    int n0 = blockIdx.x * 64;
    int m0 = blockIdx.y * 64;
    int tid = threadIdx.x;
    int wave = tid >> 6, lane = tid & 63;
    int wm = (wave >> 1) * 32, wn = (wave & 1) * 32;

    __shared__ __align__(16) unsigned short As[64][40];
    __shared__ __align__(16) unsigned short Bs[64][40];

    f32x4 acc[2][2] = {};
    int ar = tid >> 2;
    int ac = (tid & 3) * 8;
    int fr = lane & 15;
    int fk = (lane >> 4) * 8;

    for (int k0 = 0; k0 < K; k0 += 32) {
        us8 av = *(const us8*)(Xb + (size_t)(m0 + ar) * K + k0 + ac);
        us8 bv = *(const us8*)(Wt + (size_t)(n0 + ar) * K + k0 + ac);
        *(us8*)(&As[ar][ac]) = av;
        *(us8*)(&Bs[ar][ac]) = bv;
        __syncthreads();

        bf16x8 a0 = *(const bf16x8*)(&As[wm + fr][fk]);
        bf16x8 a1 = *(const bf16x8*)(&As[wm + 16 + fr][fk]);
        bf16x8 b0 = *(const bf16x8*)(&Bs[wn + fr][fk]);
        bf16x8 b1 = *(const bf16x8*)(&Bs[wn + 16 + fr][fk]);

        acc[0][0] = __builtin_amdgcn_mfma_f32_16x16x32_bf16(a0, b0, acc[0][0], 0, 0, 0);
        acc[0][1] = __builtin_amdgcn_mfma_f32_16x16x32_bf16(a0, b1, acc[0][1], 0, 0, 0);
        acc[1][0] = __builtin_amdgcn_mfma_f32_16x16x32_bf16(a1, b0, acc[1][0], 0, 0, 0);
        acc[1][1] = __builtin_amdgcn_mfma_f32_16x16x32_bf16(a1, b1, acc[1][1], 0, 0, 0);
        __syncthreads();
    }

    int crow = (lane >> 4) * 4;
    int ccol = lane & 15;
#pragma unroll
    for (int mi = 0; mi < 2; mi++)
#pragma unroll
        for (int ni = 0; ni < 2; ni++)
#pragma unroll
            for (int r = 0; r < 4; r++)
                C[(size_t)(m0 + wm + mi * 16 + crow + r) * 256 +
                  n0 + wn + ni * 16 + ccol] = acc[mi][ni][r];
}

// ---------------------------------------------------------------------------
// K4: GAT1 fused: per (b,h) block. Stage h1 slab transposed to LDS (bf16),
// compute s/d dots in-block, softmax in A-fragment register layout,
// alpha @ h1 via MFMA -> g1pre fp32 (pre-bias/LN).
// ---------------------------------------------------------------------------
__global__ __launch_bounds__(256) void gat1_fused_kernel(
    const float* __restrict__ h1, const float* __restrict__ a_src1,
    const float* __restrict__ a_dst1, float* __restrict__ g1pre) {
    int b = blockIdx.x >> 1;
    int h = blockIdx.x & 1;
    int tid = threadIdx.x;
    int wave = tid >> 6, lane = tid & 63;
    int wm = wave * 32;
    int fr = lane & 15;
    int fk = (lane >> 4) * 8;

    __shared__ __align__(16) unsigned short h1T[128][136];  // [d][j] bf16
    __shared__ float s_sh[128];   // src dot per j
    __shared__ float dd_sh[128];  // dst dot per i

    // --- stage h1T: thread owns fixed d, 8 j-chunks of 8 ---
    {
        int d = tid & 127;
        int mb = (tid >> 7) * 8;  // 0 or 8
        const float* hsrc = h1 + ((size_t)b * 128) * 256 + h * 128 + d;
#pragma unroll
        for (int m = 0; m < 8; m++) {
            int j0 = (mb + m) * 8;
            us8 pk;
#pragma unroll
            for (int jj = 0; jj < 8; jj++)
                pk[jj] = f2bf(hsrc[(size_t)(j0 + jj) * 256]);
            *(us8*)(&h1T[d][j0]) = pk;
        }
    }
    __syncthreads();

    // --- s/d dots: threads 0..127 -> s_j, 128..255 -> d_j ---
    {
        int j = tid & 127;
        const float* av = (tid < 128) ? (a_src1 + h * 128) : (a_dst1 + h * 128);
        float accd = 0.f;
        for (int d2 = 0; d2 < 128; d2++)
            accd += bf2f(h1T[d2][j]) * av[d2];
        if (tid < 128) s_sh[j] = accd;
        else dd_sh[j] = accd;
    }
    __syncthreads();

    // --- softmax directly into A-fragment registers ---
    bf16x8 afrag[2][4];
#pragma unroll
    for (int mi = 0; mi < 2; mi++) {
        int i = wm + mi * 16 + fr;
        float dd = dd_sh[i];
        float ev[4][8];
        float mx = -1e30f;
#pragma unroll
        for (int ks = 0; ks < 4; ks++)
#pragma unroll
            for (int jj = 0; jj < 8; jj++) {
                float e = dd + s_sh[ks * 32 + fk + jj];
                e = e >= 0.f ? e : 0.2f * e;
                ev[ks][jj] = e;
                mx = fmaxf(mx, e);
            }
        mx = fmaxf(mx, __shfl_xor(mx, 16, 64));
        mx = fmaxf(mx, __shfl_xor(mx, 32, 64));
        float sm = 0.f;
#pragma unroll
        for (int ks = 0; ks < 4; ks++)
#pragma unroll
            for (int jj = 0; jj < 8; jj++) {
                float e = __expf(ev[ks][jj] - mx);
                ev[ks][jj] = e;
                sm += e;
            }
        sm += __shfl_xor(sm, 16, 64);
        sm += __shfl_xor(sm, 32, 64);
        float inv = 1.f / sm;
#pragma unroll
        for (int ks = 0; ks < 4; ks++) {
            bf16x8 a;
#pragma unroll
            for (int jj = 0; jj < 8; jj++)
                a[jj] = (short)f2bf(ev[ks][jj] * inv);
            afrag[mi][ks] = a;
        }
    }

    // --- MFMA: o[i][d] = sum_j alpha[i][j] * h1T[d][j] ---
    f32x4 acc[2][8] = {};
#pragma unroll
    for (int ks = 0; ks < 4; ks++) {
#pragma unroll
        for (int ni = 0; ni < 8; ni++) {
            bf16x8 bv = *(const bf16x8*)(&h1T[ni * 16 + fr][ks * 32 + fk]);
            acc[0][ni] = __builtin_amdgcn_mfma_f32_16x16x32_bf16(
                afrag[0][ks], bv, acc[0][ni], 0, 0, 0);
            acc[1][ni] = __builtin_amdgcn_mfma_f32_16x16x32_bf16(
                afrag[1][ks], bv, acc[1][ni], 0, 0, 0);
        }
    }

    int crow = (lane >> 4) * 4;
    int ccol = lane & 15;
#pragma unroll
    for (int mi = 0; mi < 2; mi++)
#pragma unroll
        for (int ni = 0; ni < 8; ni++)
#pragma unroll
            for (int r = 0; r < 4; r++)
                g1pre[(size_t)(b * 128 + wm + mi * 16 + crow + r) * 256 +
                      h * 128 + ni * 16 + ccol] = acc[mi][ni][r];
}

// ---------------------------------------------------------------------------
// K5: bias + LayerNorm(256) + ELU -> g1b (bf16)
// ---------------------------------------------------------------------------
__global__ __launch_bounds__(256) void ln_elu256b_kernel(
    const float* __restrict__ g1pre, const float* __restrict__ b1,
    const float* __restrict__ gamma, const float* __restrict__ beta,
    unsigned short* __restrict__ g1b) {
    int row = blockIdx.x;
    int tid = threadIdx.x;
    __shared__ float red[4];
    float v = g1pre[(size_t)row * 256 + tid] + b1[tid];
    float s = v;
    for (int o = 32; o > 0; o >>= 1) s += __shfl_down(s, o, 64);
    int lane = tid & 63, wid = tid >> 6;
    if (lane == 0) red[wid] = s;
    __syncthreads();
    float mean = (red[0] + red[1] + red[2] + red[3]) * (1.f / 256.f);
    __syncthreads();
    float dv = v - mean;
    float sq = dv * dv;
    for (int o = 32; o > 0; o >>= 1) sq += __shfl_down(sq, o, 64);
    if (lane == 0) red[wid] = sq;
    __syncthreads();
    float var = (red[0] + red[1] + red[2] + red[3]) * (1.f / 256.f);
    float y = dv * rsqrtf(var + 1e-5f) * gamma[tid] + beta[tid];
    y = y > 0.f ? y : (__expf(y) - 1.f);
    g1b[(size_t)row * 256 + tid] = f2bf(y);
}

// ---------------------------------------------------------------------------
// K6: GEMM2 via MFMA + fused sd2 dots.
// ---------------------------------------------------------------------------
__global__ __launch_bounds__(256) void gemm2_mfma_kernel(
    const unsigned short* __restrict__ g1b, const unsigned short* __restrict__ W2t,
    const float* __restrict__ asrc, const float* __restrict__ adst,
    float* __restrict__ h2, float* __restrict__ s2, float* __restrict__ d2) {
    int m0 = blockIdx.x * 64;
    int tid = threadIdx.x;
    int wave = tid >> 6, lane = tid & 63;
    int wm = (wave >> 1) * 32, wn = (wave & 1) * 32;

    __shared__ __align__(16) unsigned short As[64][72];
    __shared__ __align__(16) unsigned short Bs[64][72];
    __shared__ float sdred[64][2][2];

    f32x4 acc[2][2] = {};
    int fr = lane & 15;
    int fk = (lane >> 4) * 8;

    for (int kc = 0; kc < 4; kc++) {
        for (int it = 0; it < 2; it++) {
            int i = tid + it * 256;
            int row = i >> 3, c = i & 7;
            *(us8*)(&As[row][c * 8]) =
                *(const us8*)(g1b + (size_t)(m0 + row) * 256 + kc * 64 + c * 8);
            *(us8*)(&Bs[row][c * 8]) =
                *(const us8*)(W2t + (size_t)row * 256 + kc * 64 + c * 8);
        }
        __syncthreads();
#pragma unroll
        for (int ks = 0; ks < 2; ks++) {
            int kb = ks * 32 + fk;
            bf16x8 a0 = *(const bf16x8*)(&As[wm + fr][kb]);
            bf16x8 a1 = *(const bf16x8*)(&As[wm + 16 + fr][kb]);
            bf16x8 b0 = *(const bf16x8*)(&Bs[wn + fr][kb]);
            bf16x8 b1 = *(const bf16x8*)(&Bs[wn + 16 + fr][kb]);
            acc[0][0] = __builtin_amdgcn_mfma_f32_16x16x32_bf16(a0, b0, acc[0][0], 0, 0, 0);
            acc[0][1] = __builtin_amdgcn_mfma_f32_16x16x32_bf16(a0, b1, acc[0][1], 0, 0, 0);
            acc[1][0] = __builtin_amdgcn_mfma_f32_16x16x32_bf16(a1, b0, acc[1][0], 0, 0, 0);
            acc[1][1] = __builtin_amdgcn_mfma_f32_16x16x32_bf16(a1, b1, acc[1][1], 0, 0, 0);
        }
        __syncthreads();
    }

    int crow = (lane >> 4) * 4;
    int ccol = lane & 15;
    float asv[2], adv[2];
#pragma unroll
    for (int ni = 0; ni < 2; ni++) {
        int n = wn + ni * 16 + ccol;
        asv[ni] = asrc[n];
        adv[ni] = adst[n];
    }
#pragma unroll
    for (int mi = 0; mi < 2; mi++) {
#pragma unroll
        for (int r = 0; r < 4; r++) {
            float sp = 0.f, dp = 0.f;
#pragma unroll
            for (int ni = 0; ni < 2; ni++) {
                float v = acc[mi][ni][r];
                h2[(size_t)(m0 + wm + mi * 16 + crow + r) * 64 +
                   wn + ni * 16 + ccol] = v;
                sp += v * asv[ni];
                dp += v * adv[ni];
            }
            for (int msk = 1; msk < 16; msk <<= 1) {
                sp += __shfl_xor(sp, msk, 64);
                dp += __shfl_xor(dp, msk, 64);
            }
            if ((lane & 15) == 0) {
                int row = wm + mi * 16 + crow + r;
                sdred[row][wn >> 5][0] = sp;
                sdred[row][wn >> 5][1] = dp;
            }
        }
    }
    __syncthreads();
    if (tid < 64 && wave == 0) {
        s2[m0 + tid] = sdred[tid][0][0] + sdred[tid][1][0];
        d2[m0 + tid] = sdred[tid][0][1] + sdred[tid][1][1];
    }
}

// ---------------------------------------------------------------------------
// K7: GAT2 attention + bias + LayerNorm(64) + ELU -> x2
// ---------------------------------------------------------------------------
__global__ __launch_bounds__(128) void gat2_kernel(
    const float* __restrict__ h2, const float* __restrict__ s2,
    const float* __restrict__ d2, const float* __restrict__ b2v,
    const float* __restrict__ gamma, const float* __restrict__ beta,
    float* __restrict__ x2) {
    int bi = blockIdx.x;
    int b = bi >> 7;
    int tid = threadIdx.x;
    __shared__ float alpha[128];
    __shared__ float red[2];

    float ev = d2[bi] + s2[(size_t)b * 128 + tid];
    ev = ev >= 0.f ? ev : 0.2f * ev;
    float mx = ev;
    for (int o = 32; o > 0; o >>= 1) mx = fmaxf(mx, __shfl_down(mx, o, 64));
    int lane = tid & 63, wid = tid >> 6;
    if (lane == 0) red[wid] = mx;
    __syncthreads();
    mx = fmaxf(red[0], red[1]);
    __syncthreads();
    float ex = __expf(ev - mx);
    float sm = ex;
    for (int o = 32; o > 0; o >>= 1) sm += __shfl_down(sm, o, 64);
    if (lane == 0) red[wid] = sm;
    __syncthreads();
    sm = red[0] + red[1];
    alpha[tid] = ex / sm;
    __syncthreads();

    if (tid < 64) {
        const float* hb = h2 + (size_t)b * 128 * 64 + tid;
        float o = 0.f;
#pragma unroll 8
        for (int j = 0; j < 128; j++) o += alpha[j] * hb[(size_t)j * 64];
        o += b2v[tid];
        float s = o;
        for (int off = 32; off > 0; off >>= 1) s += __shfl_down(s, off, 64);
        s = __shfl(s, 0, 64);
        float mean = s * (1.f / 64.f);
        float dv = o - mean;
        float sq = dv * dv;
        for (int off = 32; off > 0; off >>= 1) sq += __shfl_down(sq, off, 64);
        sq = __shfl(sq, 0, 64);
        float var = sq * (1.f / 64.f);
        float y = dv * rsqrtf(var + 1e-5f) * gamma[tid] + beta[tid];
        y = y > 0.f ? y : (__expf(y) - 1.f);
        x2[(size_t)bi * 64 + tid] = y;
    }
}

// ---------------------------------------------------------------------------
// K8: scores via MFMA. 64 pairs per block, N=256, K=160.
// ---------------------------------------------------------------------------
__global__ __launch_bounds__(256) void score_mfma_kernel(
    const float* __restrict__ x2, const float* __restrict__ baseo,
    const int* __restrict__ pair_idx, const int* __restrict__ rel_ids,
    const float* __restrict__ rel_emb, const unsigned short* __restrict__ Wtr,
    const float* __restrict__ Wr2, const float* __restrict__ br2,
    float* __restrict__ out) {
    int blk = blockIdx.x;
    int b = blk >> 3;
    int p0 = (blk & 7) * 64;
    int tid = threadIdx.x;
    int wave = tid >> 6, lane = tid & 63;
    int wn = wave * 64;

    __shared__ __align__(16) unsigned short As[64][168];
    __shared__ __align__(16) unsigned short Bs[256][40];
    __shared__ float sred[64][4];
    __shared__ int prs[64][3];

    if (tid < 64) {
        int p = p0 + tid;
        prs[tid][0] = pair_idx[((size_t)b * PP + p) * 2 + 0];
        prs[tid][1] = pair_idx[((size_t)b * PP + p) * 2 + 1];
        prs[tid][2] = rel_ids[(size_t)b * PP + p];
    }
    __syncthreads();
    for (int it = 0; it < 40; it++) {
        int i = tid + it * 256;
        int m = i / 160, k = i % 160;
        float v;
        if (k < 64) v = x2[((size_t)b * EE + prs[m][0]) * 64 + k];
        else if (k < 128) v = x2[((size_t)b * EE + prs[m][1]) * 64 + (k - 64)];
        else v = rel_emb[prs[m][2] * RDD + (k - 128)];
        As[m][k] = f2bf(v);
    }

    f32x4 acc[4][4] = {};
    int fr = lane & 15;
    int fk = (lane >> 4) * 8;

    for (int kc = 0; kc < 5; kc++) {
        for (int it = 0; it < 4; it++) {
            int i = tid + it * 256;
            int n = i >> 2, c = i & 3;
            *(us8*)(&Bs[n][c * 8]) =
                *(const us8*)(Wtr + (size_t)n * 160 + kc * 32 + c * 8);
        }
        __syncthreads();
        bf16x8 a[4], bv[4];
#pragma unroll
        for (int mi = 0; mi < 4; mi++)
            a[mi] = *(const bf16x8*)(&As[mi * 16 + fr][kc * 32 + fk]);
#pragma unroll
        for (int ni = 0; ni < 4; ni++)
            bv[ni] = *(const bf16x8*)(&Bs[wn + ni * 16 + fr][fk]);
#pragma unroll
        for (int mi = 0; mi < 4; mi++)
#pragma unroll
            for (int ni = 0; ni < 4; ni++)
                acc[mi][ni] = __builtin_amdgcn_mfma_f32_16x16x32_bf16(
                    a[mi], bv[ni], acc[mi][ni], 0, 0, 0);
        __syncthreads();
    }

    int crow = (lane >> 4) * 4;
    int ccol = lane & 15;
    float basev[4], w2v[4];
#pragma unroll
    for (int ni = 0; ni < 4; ni++) {
        int n = wn + ni * 16 + ccol;
        basev[ni] = baseo[(size_t)b * 256 + n];
        w2v[ni] = Wr2[n];
    }
#pragma unroll
    for (int mi = 0; mi < 4; mi++) {
#pragma unroll
        for (int r = 0; r < 4; r++) {
            float p = 0.f;
#pragma unroll
            for (int ni = 0; ni < 4; ni++)
                p += fmaxf(acc[mi][ni][r] + basev[ni], 0.f) * w2v[ni];
            for (int msk = 1; msk < 16; msk <<= 1)
                p += __shfl_xor(p, msk, 64);
            if ((lane & 15) == 0)
                sred[mi * 16 + crow + r][wave] = p;
        }
    }
    __syncthreads();
    if (tid < 64) {
        float s = sred[tid][0] + sred[tid][1] + sred[tid][2] + sred[tid][3] + br2[0];
        out[(size_t)b * PP + p0 + tid] = s;
    }
}

// ---------------------------------------------------------------------------
extern "C" void kernel_launch(void* const* d_in, const int* in_sizes, int n_in,
                              void* d_out, int out_size, void* d_ws, size_t ws_size,
                              hipStream_t stream) {
    (void)in_sizes; (void)n_in; (void)out_size; (void)ws_size;
    const float* seq      = (const float*)d_in[0];
    const int*   starts   = (const int*)d_in[1];
    const int*   types    = (const int*)d_in[2];
    const int*   pair_idx = (const int*)d_in[3];
    const int*   rel_ids  = (const int*)d_in[4];
    const float* temb     = (const float*)d_in[5];
    const float* remb     = (const float*)d_in[6];
    const float* W1       = (const float*)d_in[7];
    const float* a_src1   = (const float*)d_in[8];
    const float* a_dst1   = (const float*)d_in[9];
    const float* b1       = (const float*)d_in[10];
    const float* ln1_g    = (const float*)d_in[11];
    const float* ln1_b    = (const float*)d_in[12];
    const float* W2       = (const float*)d_in[13];
    const float* a_src2   = (const float*)d_in[14];
    const float* a_dst2   = (const float*)d_in[15];
    const float* b2       = (const float*)d_in[16];
    const float* ln2_g    = (const float*)d_in[17];
    const float* ln2_b    = (const float*)d_in[18];
    const float* Wr1      = (const float*)d_in[19];
    const float* br1      = (const float*)d_in[20];
    const float* Wr2      = (const float*)d_in[21];
    const float* br2      = (const float*)d_in[22];
    float* out = (float*)d_out;

    unsigned short* xb  = (unsigned short*)d_ws;         // 4096*768
    unsigned short* Wt  = xb + (size_t)4096 * 768;       // 256*768
    unsigned short* Wtr = Wt + (size_t)256 * 768;        // 256*160
    unsigned short* W2t = Wtr + (size_t)256 * 160;       // 64*256
    unsigned short* g1b = W2t + (size_t)64 * 256;        // 4096*256
    float* fbase = (float*)(g1b + (size_t)4096 * 256);
    float* h1    = fbase;                      // 4096*256
    float* g1pre = h1 + (size_t)4096 * 256;    // 4096*256
    float* h2    = g1pre + (size_t)4096 * 256; // 4096*64
    float* s2    = h2 + (size_t)4096 * 64;     // 4096
    float* d2    = s2 + 4096;                  // 4096
    float* x2    = d2 + 4096;                  // 4096*64
    float* baseo = x2 + (size_t)4096 * 64;     // 32*256

    pool_kernel<<<BB * EE, 256, 0, stream>>>(seq, starts, types, temb, br1, baseo, xb);
    prep_kernel<<<74 + 12 * 32, 256, 0, stream>>>(W1, Wt, Wr1, Wtr, W2, W2t, seq, baseo);
    gemm1_mfma_kernel<<<dim3(4, 64), 256, 0, stream>>>(xb, Wt, h1);
    gat1_fused_kernel<<<BB * 2, 256, 0, stream>>>(h1, a_src1, a_dst1, g1pre);
    ln_elu256b_kernel<<<BB * EE, 256, 0, stream>>>(g1pre, b1, ln1_g, ln1_b, g1b);
    gemm2_mfma_kernel<<<64, 256, 0, stream>>>(g1b, W2t, a_src2, a_dst2, h2, s2, d2);
    gat2_kernel<<<BB * EE, 128, 0, stream>>>(h2, s2, d2, b2, ln2_g, ln2_b, x2);
    score_mfma_kernel<<<BB * PP / 64, 256, 0, stream>>>(x2, baseo, pair_idx, rel_ids,
                                                        remb, Wtr, Wr2, br2, out);
}

// Round 9
// 250.899 us; speedup vs baseline: 1.7662x; 1.0372x over previous
//
#include <hip/hip_runtime.h>
#include <hip/hip_bf16.h>

#define BB 32
#define SS 1024
#define HHH 768
#define EE 128
#define WW 8
#define PP 512
#define RDD 32

typedef __attribute__((ext_vector_type(8))) short bf16x8;
typedef __attribute__((ext_vector_type(8))) unsigned short us8;
typedef __attribute__((ext_vector_type(4))) unsigned short us4;
typedef __attribute__((ext_vector_type(4))) float f32x4;

__device__ __forceinline__ unsigned short f2bf(float v) {
    __hip_bfloat16 h = __float2bfloat16(v);
    return *(unsigned short*)&h;
}
__device__ __forceinline__ float bf2f(unsigned short u) {
    unsigned int x = ((unsigned int)u) << 16;
    float f; __builtin_memcpy(&f, &x, 4);
    return f;
}

// ---------------------------------------------------------------------------
// K1: merged pool + prep.
// blocks 0..4095: pooling -> xb bf16.
// blocks 4096+: 0..47 W1->Wt; 48..57 Wr1[0:160]->Wtr; 58..73 W2->W2t;
//               74 remb->rembb; 75..458 cls@Wr1[160:928] -> basep (no atomics).
// ---------------------------------------------------------------------------
__global__ __launch_bounds__(256) void pool_prep_kernel(
    const float* __restrict__ seq, const int* __restrict__ starts,
    const int* __restrict__ types, const float* __restrict__ temb,
    unsigned short* __restrict__ xout,
    const float* __restrict__ W1, unsigned short* __restrict__ Wt,
    const float* __restrict__ Wr1, unsigned short* __restrict__ Wtr,
    const float* __restrict__ W2, unsigned short* __restrict__ W2t,
    const float* __restrict__ remb, unsigned short* __restrict__ rembb,
    float* __restrict__ basep) {
    int tid = threadIdx.x;
    __shared__ float sbuf[WW * HHH];      // pool: toks; prep: wbuf/cls
    __shared__ float scred[WW];
    __shared__ float attn_s[WW];

    if (blockIdx.x < BB * EE) {
        int be = blockIdx.x;
        int b = be >> 7;
        int start = starts[be];
        const float4* bp4 = (const float4*)(seq + ((size_t)b * SS + start) * HHH);
        for (int idx = tid; idx < WW * (HHH / 4); idx += 256) {
            int w = idx / (HHH / 4), h4 = idx % (HHH / 4);
            float4 v = bp4[(size_t)w * (HHH / 4) + h4];
            sbuf[w * HHH + h4 * 4 + 0] = v.x; sbuf[w * HHH + h4 * 4 + 1] = v.y;
            sbuf[w * HHH + h4 * 4 + 2] = v.z; sbuf[w * HHH + h4 * 4 + 3] = v.w;
        }
        __syncthreads();

        float sc[WW];
#pragma unroll
        for (int w = 0; w < WW; w++) sc[w] = 0.f;
#pragma unroll
        for (int c = 0; c < 3; c++) {
            int h = tid + 256 * c;
            float s = 0.f;
#pragma unroll
            for (int w = 0; w < WW; w++) s += sbuf[w * HHH + h];
            float m = s * (1.0f / WW);
#pragma unroll
            for (int w = 0; w < WW; w++) sc[w] += sbuf[w * HHH + h] * m;
        }
        if (tid < WW) scred[tid] = 0.f;
        __syncthreads();
        int lane = tid & 63;
#pragma unroll
        for (int w = 0; w < WW; w++) {
            float v = sc[w];
            for (int o = 32; o > 0; o >>= 1) v += __shfl_down(v, o, 64);
            if (lane == 0) atomicAdd(&scred[w], v);
        }
        __syncthreads();
        if (tid == 0) {
            float mx = scred[0];
            for (int w = 1; w < WW; w++) mx = fmaxf(mx, scred[w]);
            float ssum = 0.f;
            float a[WW];
            for (int w = 0; w < WW; w++) { a[w] = __expf(scred[w] - mx); ssum += a[w]; }
            float inv = 1.f / ssum;
            for (int w = 0; w < WW; w++) attn_s[w] = a[w] * inv;
        }
        __syncthreads();

        int t = types[be];
        const float* emb = temb + (size_t)t * HHH;
#pragma unroll
        for (int c = 0; c < 3; c++) {
            int h = tid + 256 * c;
            float p = 0.f;
#pragma unroll
            for (int w = 0; w < WW; w++) p += attn_s[w] * sbuf[w * HHH + h];
            xout[(size_t)be * HHH + h] = f2bf(p + emb[h]);
        }
        return;
    }

    int blk = blockIdx.x - BB * EE;
    if (blk < 48) {
        int k0 = blk * 16;
        for (int i = tid; i < 16 * 256; i += 256)
            sbuf[i] = W1[(size_t)(k0 + (i >> 8)) * 256 + (i & 255)];
        __syncthreads();
        int n = tid;
        us8 v0, v1;
#pragma unroll
        for (int kk = 0; kk < 8; kk++) v0[kk] = f2bf(sbuf[kk * 256 + n]);
#pragma unroll
        for (int kk = 0; kk < 8; kk++) v1[kk] = f2bf(sbuf[(8 + kk) * 256 + n]);
        *(us8*)(Wt + (size_t)n * HHH + k0) = v0;
        *(us8*)(Wt + (size_t)n * HHH + k0 + 8) = v1;
    } else if (blk < 58) {
        int k0 = (blk - 48) * 16;
        for (int i = tid; i < 16 * 256; i += 256)
            sbuf[i] = Wr1[(size_t)(k0 + (i >> 8)) * 256 + (i & 255)];
        __syncthreads();
        int n = tid;
        us8 v0, v1;
#pragma unroll
        for (int kk = 0; kk < 8; kk++) v0[kk] = f2bf(sbuf[kk * 256 + n]);
#pragma unroll
        for (int kk = 0; kk < 8; kk++) v1[kk] = f2bf(sbuf[(8 + kk) * 256 + n]);
        *(us8*)(Wtr + (size_t)n * 160 + k0) = v0;
        *(us8*)(Wtr + (size_t)n * 160 + k0 + 8) = v1;
    } else if (blk < 74) {
        int k0 = (blk - 58) * 16;
        for (int i = tid; i < 16 * 64; i += 256)
            sbuf[(i >> 6) * 64 + (i & 63)] = W2[(size_t)(k0 + (i >> 6)) * 64 + (i & 63)];
        __syncthreads();
        if (tid < 64) {
            int n = tid;
            us8 v0, v1;
#pragma unroll
            for (int kk = 0; kk < 8; kk++) v0[kk] = f2bf(sbuf[kk * 64 + n]);
#pragma unroll
            for (int kk = 0; kk < 8; kk++) v1[kk] = f2bf(sbuf[(8 + kk) * 64 + n]);
            *(us8*)(W2t + (size_t)n * 256 + k0) = v0;
            *(us8*)(W2t + (size_t)n * 256 + k0 + 8) = v1;
        }
    } else if (blk == 74) {
        for (int i = tid; i < 9 * RDD; i += 256) rembb[i] = f2bf(remb[i]);
    } else {
        int pc = blk - 75;
        int kc = pc % 12;
        int b = pc / 12;
        int n = tid;
        if (n < 64) sbuf[4096 + n] = seq[(size_t)b * SS * HHH + kc * 64 + n];
        __syncthreads();
        float acc = 0.f;
        const float* w = Wr1 + (size_t)(160 + kc * 64) * 256 + n;
#pragma unroll 16
        for (int k = 0; k < 64; k++) acc += sbuf[4096 + k] * w[(size_t)k * 256];
        basep[((size_t)kc * 32 + b) * 256 + n] = acc;
    }
}

// ---------------------------------------------------------------------------
// K2: GEMM1 via MFMA bf16. Xb(4096x768) @ Wt^T -> h1(4096x256 fp32).
// ---------------------------------------------------------------------------
__global__ __launch_bounds__(256) void gemm1_mfma_kernel(
    const unsigned short* __restrict__ Xb, const unsigned short* __restrict__ Wt,
    float* __restrict__ C) {
    const int K = HHH;
    int n0 = blockIdx.x * 64;
    int m0 = blockIdx.y * 64;
    int tid = threadIdx.x;
    int wave = tid >> 6, lane = tid & 63;
    int wm = (wave >> 1) * 32, wn = (wave & 1) * 32;

    __shared__ __align__(16) unsigned short As[64][40];
    __shared__ __align__(16) unsigned short Bs[64][40];

    f32x4 acc[2][2] = {};
    int ar = tid >> 2;
    int ac = (tid & 3) * 8;
    int fr = lane & 15;
    int fk = (lane >> 4) * 8;

    for (int k0 = 0; k0 < K; k0 += 32) {
        us8 av = *(const us8*)(Xb + (size_t)(m0 + ar) * K + k0 + ac);
        us8 bv = *(const us8*)(Wt + (size_t)(n0 + ar) * K + k0 + ac);
        *(us8*)(&As[ar][ac]) = av;
        *(us8*)(&Bs[ar][ac]) = bv;
        __syncthreads();

        bf16x8 a0 = *(const bf16x8*)(&As[wm + fr][fk]);
        bf16x8 a1 = *(const bf16x8*)(&As[wm + 16 + fr][fk]);
        bf16x8 b0 = *(const bf16x8*)(&Bs[wn + fr][fk]);
        bf16x8 b1 = *(const bf16x8*)(&Bs[wn + 16 + fr][fk]);

        acc[0][0] = __builtin_amdgcn_mfma_f32_16x16x32_bf16(a0, b0, acc[0][0], 0, 0, 0);
        acc[0][1] = __builtin_amdgcn_mfma_f32_16x16x32_bf16(a0, b1, acc[0][1], 0, 0, 0);
        acc[1][0] = __builtin_amdgcn_mfma_f32_16x16x32_bf16(a1, b0, acc[1][0], 0, 0, 0);
        acc[1][1] = __builtin_amdgcn_mfma_f32_16x16x32_bf16(a1, b1, acc[1][1], 0, 0, 0);
        __syncthreads();
    }

    int crow = (lane >> 4) * 4;
    int ccol = lane & 15;
#pragma unroll
    for (int mi = 0; mi < 2; mi++)
#pragma unroll
        for (int ni = 0; ni < 2; ni++)
#pragma unroll
            for (int r = 0; r < 4; r++)
                C[(size_t)(m0 + wm + mi * 16 + crow + r) * 256 +
                  n0 + wn + ni * 16 + ccol] = acc[mi][ni][r];
}

// ---------------------------------------------------------------------------
// K3: GAT1 fully fused per batch (both heads): stage h1 (coalesced f4 ->
// LDS transpose bf16), s/d dots, softmax in A-frag regs, MFMA PV,
// bias + wave-local LayerNorm(256) + ELU -> g1b bf16.
// grid = 32 blocks, 256 threads.
// ---------------------------------------------------------------------------
__global__ __launch_bounds__(256) void gat1_fused_kernel(
    const float* __restrict__ h1, const float* __restrict__ a_src1,
    const float* __restrict__ a_dst1, const float* __restrict__ b1,
    const float* __restrict__ gamma, const float* __restrict__ beta,
    unsigned short* __restrict__ g1b) {
    int b = blockIdx.x;
    int tid = threadIdx.x;
    int wave = tid >> 6, lane = tid & 63;
    int wm = wave * 32;
    int fr = lane & 15;
    int fk = (lane >> 4) * 8;

    __shared__ __align__(16) unsigned short h1T[2][128][136];  // [h][d][j]
    __shared__ float ssh[2][128];
    __shared__ float dsh[2][128];

    // stage: coalesced f4 reads, transposed 2B LDS writes
    {
        const float4* src4 = (const float4*)(h1 + (size_t)b * 128 * 256);
        for (int it = 0; it < 32; it++) {
            int i4 = tid + it * 256;     // 0..8191
            int j = i4 >> 6;             // entity row
            int c4 = i4 & 63;
            float4 v = src4[(size_t)j * 64 + c4];
            int d = c4 * 4;
            int hh = d >> 7, dl = d & 127;
            h1T[hh][dl + 0][j] = f2bf(v.x);
            h1T[hh][dl + 1][j] = f2bf(v.y);
            h1T[hh][dl + 2][j] = f2bf(v.z);
            h1T[hh][dl + 3][j] = f2bf(v.w);
        }
    }
    __syncthreads();

    // s/d dots per (head, j)
    {
        int hh = tid >> 7, j = tid & 127;
        const float* as = a_src1 + hh * 128;
        const float* ad = a_dst1 + hh * 128;
        float s_ = 0.f, d_ = 0.f;
        for (int d2 = 0; d2 < 128; d2++) {
            float hv = bf2f(h1T[hh][d2][j]);
            s_ += hv * as[d2];
            d_ += hv * ad[d2];
        }
        ssh[hh][j] = s_;
        dsh[hh][j] = d_;
    }
    __syncthreads();

    // softmax -> A fragments (per head, per 16-row frag)
    bf16x8 afrag[2][2][4];
#pragma unroll
    for (int hh = 0; hh < 2; hh++)
#pragma unroll
        for (int mi = 0; mi < 2; mi++) {
            int i = wm + mi * 16 + fr;
            float dd = dsh[hh][i];
            float ev[4][8];
            float mx = -1e30f;
#pragma unroll
            for (int ks = 0; ks < 4; ks++)
#pragma unroll
                for (int jj = 0; jj < 8; jj++) {
                    float e = dd + ssh[hh][ks * 32 + fk + jj];
                    e = e >= 0.f ? e : 0.2f * e;
                    ev[ks][jj] = e;
                    mx = fmaxf(mx, e);
                }
            mx = fmaxf(mx, __shfl_xor(mx, 16, 64));
            mx = fmaxf(mx, __shfl_xor(mx, 32, 64));
            float sm = 0.f;
#pragma unroll
            for (int ks = 0; ks < 4; ks++)
#pragma unroll
                for (int jj = 0; jj < 8; jj++) {
                    float e = __expf(ev[ks][jj] - mx);
                    ev[ks][jj] = e;
                    sm += e;
                }
            sm += __shfl_xor(sm, 16, 64);
            sm += __shfl_xor(sm, 32, 64);
            float inv = 1.f / sm;
#pragma unroll
            for (int ks = 0; ks < 4; ks++) {
                bf16x8 a;
#pragma unroll
                for (int jj = 0; jj < 8; jj++)
                    a[jj] = (short)f2bf(ev[ks][jj] * inv);
                afrag[hh][mi][ks] = a;
            }
        }

    // MFMA: o[i][d], d 0..255 via 16 n-frags (8 per head)
    f32x4 acc[2][16] = {};
#pragma unroll
    for (int ks = 0; ks < 4; ks++)
#pragma unroll
        for (int ni = 0; ni < 16; ni++) {
            int hh = ni >> 3;
            bf16x8 bv = *(const bf16x8*)(&h1T[hh][(ni & 7) * 16 + fr][ks * 32 + fk]);
            acc[0][ni] = __builtin_amdgcn_mfma_f32_16x16x32_bf16(
                afrag[hh][0][ks], bv, acc[0][ni], 0, 0, 0);
            acc[1][ni] = __builtin_amdgcn_mfma_f32_16x16x32_bf16(
                afrag[hh][1][ks], bv, acc[1][ni], 0, 0, 0);
        }

    // epilogue: bias + wave-local LN(256) + ELU -> g1b
    int crow = (lane >> 4) * 4;
    int ccol = lane & 15;
    float bv_[16], gv[16], bev[16];
#pragma unroll
    for (int ni = 0; ni < 16; ni++) {
        int d = ni * 16 + ccol;
        bv_[ni] = b1[d]; gv[ni] = gamma[d]; bev[ni] = beta[d];
    }
#pragma unroll
    for (int mi = 0; mi < 2; mi++)
#pragma unroll
        for (int r = 0; r < 4; r++) {
            float v[16];
            float s = 0.f;
#pragma unroll
            for (int ni = 0; ni < 16; ni++) {
                v[ni] = acc[mi][ni][r] + bv_[ni];
                s += v[ni];
            }
            s += __shfl_xor(s, 1, 64); s += __shfl_xor(s, 2, 64);
            s += __shfl_xor(s, 4, 64); s += __shfl_xor(s, 8, 64);
            float mean = s * (1.f / 256.f);
            float sq = 0.f;
#pragma unroll
            for (int ni = 0; ni < 16; ni++) {
                float dv = v[ni] - mean;
                sq += dv * dv;
            }
            sq += __shfl_xor(sq, 1, 64); sq += __shfl_xor(sq, 2, 64);
            sq += __shfl_xor(sq, 4, 64); sq += __shfl_xor(sq, 8, 64);
            float rs = rsqrtf(sq * (1.f / 256.f) + 1e-5f);
            int i = wm + mi * 16 + crow + r;
            unsigned short* dst = g1b + (size_t)(b * 128 + i) * 256;
#pragma unroll
            for (int ni = 0; ni < 16; ni++) {
                float y = (v[ni] - mean) * rs * gv[ni] + bev[ni];
                y = y > 0.f ? y : (__expf(y) - 1.f);
                dst[ni * 16 + ccol] = f2bf(y);
            }
        }
}

// ---------------------------------------------------------------------------
// K4: GEMM2 via MFMA + fused sd2 dots. g1b(4096x256)@W2t^T -> h2 fp32.
// ---------------------------------------------------------------------------
__global__ __launch_bounds__(256) void gemm2_mfma_kernel(
    const unsigned short* __restrict__ g1b, const unsigned short* __restrict__ W2t,
    const float* __restrict__ asrc, const float* __restrict__ adst,
    float* __restrict__ h2, float* __restrict__ s2, float* __restrict__ d2) {
    int m0 = blockIdx.x * 64;
    int tid = threadIdx.x;
    int wave = tid >> 6, lane = tid & 63;
    int wm = (wave >> 1) * 32, wn = (wave & 1) * 32;

    __shared__ __align__(16) unsigned short As[64][72];
    __shared__ __align__(16) unsigned short Bs[64][72];
    __shared__ float sdred[64][2][2];

    f32x4 acc[2][2] = {};
    int fr = lane & 15;
    int fk = (lane >> 4) * 8;

    for (int kc = 0; kc < 4; kc++) {
        for (int it = 0; it < 2; it++) {
            int i = tid + it * 256;
            int row = i >> 3, c = i & 7;
            *(us8*)(&As[row][c * 8]) =
                *(const us8*)(g1b + (size_t)(m0 + row) * 256 + kc * 64 + c * 8);
            *(us8*)(&Bs[row][c * 8]) =
                *(const us8*)(W2t + (size_t)row * 256 + kc * 64 + c * 8);
        }
        __syncthreads();
#pragma unroll
        for (int ks = 0; ks < 2; ks++) {
            int kb = ks * 32 + fk;
            bf16x8 a0 = *(const bf16x8*)(&As[wm + fr][kb]);
            bf16x8 a1 = *(const bf16x8*)(&As[wm + 16 + fr][kb]);
            bf16x8 b0 = *(const bf16x8*)(&Bs[wn + fr][kb]);
            bf16x8 b1 = *(const bf16x8*)(&Bs[wn + 16 + fr][kb]);
            acc[0][0] = __builtin_amdgcn_mfma_f32_16x16x32_bf16(a0, b0, acc[0][0], 0, 0, 0);
            acc[0][1] = __builtin_amdgcn_mfma_f32_16x16x32_bf16(a0, b1, acc[0][1], 0, 0, 0);
            acc[1][0] = __builtin_amdgcn_mfma_f32_16x16x32_bf16(a1, b0, acc[1][0], 0, 0, 0);
            acc[1][1] = __builtin_amdgcn_mfma_f32_16x16x32_bf16(a1, b1, acc[1][1], 0, 0, 0);
        }
        __syncthreads();
    }

    int crow = (lane >> 4) * 4;
    int ccol = lane & 15;
    float asv[2], adv[2];
#pragma unroll
    for (int ni = 0; ni < 2; ni++) {
        int n = wn + ni * 16 + ccol;
        asv[ni] = asrc[n];
        adv[ni] = adst[n];
    }
#pragma unroll
    for (int mi = 0; mi < 2; mi++) {
#pragma unroll
        for (int r = 0; r < 4; r++) {
            float sp = 0.f, dp = 0.f;
#pragma unroll
            for (int ni = 0; ni < 2; ni++) {
                float v = acc[mi][ni][r];
                h2[(size_t)(m0 + wm + mi * 16 + crow + r) * 64 +
                   wn + ni * 16 + ccol] = v;
                sp += v * asv[ni];
                dp += v * adv[ni];
            }
            for (int msk = 1; msk < 16; msk <<= 1) {
                sp += __shfl_xor(sp, msk, 64);
                dp += __shfl_xor(dp, msk, 64);
            }
            if ((lane & 15) == 0) {
                int row = wm + mi * 16 + crow + r;
                sdred[row][wn >> 5][0] = sp;
                sdred[row][wn >> 5][1] = dp;
            }
        }
    }
    __syncthreads();
    if (tid < 64 && wave == 0) {
        s2[m0 + tid] = sdred[tid][0][0] + sdred[tid][1][0];
        d2[m0 + tid] = sdred[tid][0][1] + sdred[tid][1][1];
    }
}

// ---------------------------------------------------------------------------
// K5: GAT2 fused per batch: stage h2 transposed, softmax in A-frag regs,
// MFMA PV, bias + wave-local LN(64) + ELU -> x2b bf16. grid = 32 blocks.
// ---------------------------------------------------------------------------
__global__ __launch_bounds__(256) void gat2_fused_kernel(
    const float* __restrict__ h2, const float* __restrict__ s2,
    const float* __restrict__ d2, const float* __restrict__ b2v,
    const float* __restrict__ gamma, const float* __restrict__ beta,
    unsigned short* __restrict__ x2b) {
    int b = blockIdx.x;
    int tid = threadIdx.x;
    int wave = tid >> 6, lane = tid & 63;
    int wm = wave * 32;
    int fr = lane & 15;
    int fk = (lane >> 4) * 8;

    __shared__ __align__(16) unsigned short h2T[64][136];  // [d][j]
    __shared__ float ssh[128];
    __shared__ float dsh[128];

    {
        const float4* src4 = (const float4*)(h2 + (size_t)b * 128 * 64);
        for (int it = 0; it < 8; it++) {
            int i4 = tid + it * 256;   // 0..2047
            int j = i4 >> 4;
            int c4 = i4 & 15;
            float4 v = src4[(size_t)j * 16 + c4];
            int d = c4 * 4;
            h2T[d + 0][j] = f2bf(v.x);
            h2T[d + 1][j] = f2bf(v.y);
            h2T[d + 2][j] = f2bf(v.z);
            h2T[d + 3][j] = f2bf(v.w);
        }
        if (tid < 128) ssh[tid] = s2[(size_t)b * 128 + tid];
        else dsh[tid - 128] = d2[(size_t)b * 128 + (tid - 128)];
    }
    __syncthreads();

    bf16x8 afrag[2][4];
#pragma unroll
    for (int mi = 0; mi < 2; mi++) {
        int i = wm + mi * 16 + fr;
        float dd = dsh[i];
        float ev[4][8];
        float mx = -1e30f;
#pragma unroll
        for (int ks = 0; ks < 4; ks++)
#pragma unroll
            for (int jj = 0; jj < 8; jj++) {
                float e = dd + ssh[ks * 32 + fk + jj];
                e = e >= 0.f ? e : 0.2f * e;
                ev[ks][jj] = e;
                mx = fmaxf(mx, e);
            }
        mx = fmaxf(mx, __shfl_xor(mx, 16, 64));
        mx = fmaxf(mx, __shfl_xor(mx, 32, 64));
        float sm = 0.f;
#pragma unroll
        for (int ks = 0; ks < 4; ks++)
#pragma unroll
            for (int jj = 0; jj < 8; jj++) {
                float e = __expf(ev[ks][jj] - mx);
                ev[ks][jj] = e;
                sm += e;
            }
        sm += __shfl_xor(sm, 16, 64);
        sm += __shfl_xor(sm, 32, 64);
        float inv = 1.f / sm;
#pragma unroll
        for (int ks = 0; ks < 4; ks++) {
            bf16x8 a;
#pragma unroll
            for (int jj = 0; jj < 8; jj++)
                a[jj] = (short)f2bf(ev[ks][jj] * inv);
            afrag[mi][ks] = a;
        }
    }

    f32x4 acc[2][4] = {};
#pragma unroll
    for (int ks = 0; ks < 4; ks++)
#pragma unroll
        for (int ni = 0; ni < 4; ni++) {
            bf16x8 bv = *(const bf16x8*)(&h2T[ni * 16 + fr][ks * 32 + fk]);
            acc[0][ni] = __builtin_amdgcn_mfma_f32_16x16x32_bf16(
                afrag[0][ks], bv, acc[0][ni], 0, 0, 0);
            acc[1][ni] = __builtin_amdgcn_mfma_f32_16x16x32_bf16(
                afrag[1][ks], bv, acc[1][ni], 0, 0, 0);
        }

    int crow = (lane >> 4) * 4;
    int ccol = lane & 15;
    float bv_[4], gv[4], bev[4];
#pragma unroll
    for (int ni = 0; ni < 4; ni++) {
        int d = ni * 16 + ccol;
        bv_[ni] = b2v[d]; gv[ni] = gamma[d]; bev[ni] = beta[d];
    }
#pragma unroll
    for (int mi = 0; mi < 2; mi++)
#pragma unroll
        for (int r = 0; r < 4; r++) {
            float v[4];
            float s = 0.f;
#pragma unroll
            for (int ni = 0; ni < 4; ni++) {
                v[ni] = acc[mi][ni][r] + bv_[ni];
                s += v[ni];
            }
            s += __shfl_xor(s, 1, 64); s += __shfl_xor(s, 2, 64);
            s += __shfl_xor(s, 4, 64); s += __shfl_xor(s, 8, 64);
            float mean = s * (1.f / 64.f);
            float sq = 0.f;
#pragma unroll
            for (int ni = 0; ni < 4; ni++) {
                float dv = v[ni] - mean;
                sq += dv * dv;
            }
            sq += __shfl_xor(sq, 1, 64); sq += __shfl_xor(sq, 2, 64);
            sq += __shfl_xor(sq, 4, 64); sq += __shfl_xor(sq, 8, 64);
            float rs = rsqrtf(sq * (1.f / 64.f) + 1e-5f);
            int i = wm + mi * 16 + crow + r;
            unsigned short* dst = x2b + (size_t)(b * 128 + i) * 64;
#pragma unroll
            for (int ni = 0; ni < 4; ni++) {
                float y = (v[ni] - mean) * rs * gv[ni] + bev[ni];
                y = y > 0.f ? y : (__expf(y) - 1.f);
                dst[ni * 16 + ccol] = f2bf(y);
            }
        }
}

// ---------------------------------------------------------------------------
// K6: scores via MFMA. 64 pairs per block, N=256, K=160. Vectorized bf16
// staging; base = br1 + sum of 12 basep slots in epilogue.
// ---------------------------------------------------------------------------
__global__ __launch_bounds__(256) void score_mfma_kernel(
    const unsigned short* __restrict__ x2b, const float* __restrict__ basep,
    const float* __restrict__ br1,
    const int* __restrict__ pair_idx, const int* __restrict__ rel_ids,
    const unsigned short* __restrict__ rembb, const unsigned short* __restrict__ Wtr,
    const float* __restrict__ Wr2, const float* __restrict__ br2,
    float* __restrict__ out) {
    int blk = blockIdx.x;
    int b = blk >> 3;
    int p0 = (blk & 7) * 64;
    int tid = threadIdx.x;
    int wave = tid >> 6, lane = tid & 63;
    int wn = wave * 64;

    __shared__ __align__(16) unsigned short As[64][168];
    __shared__ __align__(16) unsigned short Bs[256][40];
    __shared__ float sred[64][4];
    __shared__ int prs[64][3];

    if (tid < 64) {
        int p = p0 + tid;
        prs[tid][0] = pair_idx[((size_t)b * PP + p) * 2 + 0];
        prs[tid][1] = pair_idx[((size_t)b * PP + p) * 2 + 1];
        prs[tid][2] = rel_ids[(size_t)b * PP + p];
    }
    __syncthreads();
    // stage As: 64 pairs x 160 bf16, us4 chunks
    for (int it = 0; it < 10; it++) {
        int idx = tid + it * 256;      // 0..2559
        int m = idx / 40, c = idx % 40;
        int k0 = c * 4;
        us4 v;
        if (k0 < 64)
            v = *(const us4*)(x2b + ((size_t)b * EE + prs[m][0]) * 64 + k0);
        else if (k0 < 128)
            v = *(const us4*)(x2b + ((size_t)b * EE + prs[m][1]) * 64 + (k0 - 64));
        else
            v = *(const us4*)(rembb + prs[m][2] * RDD + (k0 - 128));
        *(us4*)(&As[m][k0]) = v;
    }

    f32x4 acc[4][4] = {};
    int fr = lane & 15;
    int fk = (lane >> 4) * 8;

    for (int kc = 0; kc < 5; kc++) {
        for (int it = 0; it < 4; it++) {
            int i = tid + it * 256;
            int n = i >> 2, c = i & 3;
            *(us8*)(&Bs[n][c * 8]) =
                *(const us8*)(Wtr + (size_t)n * 160 + kc * 32 + c * 8);
        }
        __syncthreads();
        bf16x8 a[4], bv[4];
#pragma unroll
        for (int mi = 0; mi < 4; mi++)
            a[mi] = *(const bf16x8*)(&As[mi * 16 + fr][kc * 32 + fk]);
#pragma unroll
        for (int ni = 0; ni < 4; ni++)
            bv[ni] = *(const bf16x8*)(&Bs[wn + ni * 16 + fr][fk]);
#pragma unroll
        for (int mi = 0; mi < 4; mi++)
#pragma unroll
            for (int ni = 0; ni < 4; ni++)
                acc[mi][ni] = __builtin_amdgcn_mfma_f32_16x16x32_bf16(
                    a[mi], bv[ni], acc[mi][ni], 0, 0, 0);
        __syncthreads();
    }

    int crow = (lane >> 4) * 4;
    int ccol = lane & 15;
    float basev[4], w2v[4];
#pragma unroll
    for (int ni = 0; ni < 4; ni++) {
        int n = wn + ni * 16 + ccol;
        float bb = br1[n];
#pragma unroll
        for (int kc = 0; kc < 12; kc++)
            bb += basep[((size_t)kc * 32 + b) * 256 + n];
        basev[ni] = bb;
        w2v[ni] = Wr2[n];
    }
#pragma unroll
    for (int mi = 0; mi < 4; mi++) {
#pragma unroll
        for (int r = 0; r < 4; r++) {
            float p = 0.f;
#pragma unroll
            for (int ni = 0; ni < 4; ni++)
                p += fmaxf(acc[mi][ni][r] + basev[ni], 0.f) * w2v[ni];
            for (int msk = 1; msk < 16; msk <<= 1)
                p += __shfl_xor(p, msk, 64);
            if ((lane & 15) == 0)
                sred[mi * 16 + crow + r][wave] = p;
        }
    }
    __syncthreads();
    if (tid < 64) {
        float s = sred[tid][0] + sred[tid][1] + sred[tid][2] + sred[tid][3] + br2[0];
        out[(size_t)b * PP + p0 + tid] = s;
    }
}

// ---------------------------------------------------------------------------
extern "C" void kernel_launch(void* const* d_in, const int* in_sizes, int n_in,
                              void* d_out, int out_size, void* d_ws, size_t ws_size,
                              hipStream_t stream) {
    (void)in_sizes; (void)n_in; (void)out_size; (void)ws_size;
    const float* seq      = (const float*)d_in[0];
    const int*   starts   = (const int*)d_in[1];
    const int*   types    = (const int*)d_in[2];
    const int*   pair_idx = (const int*)d_in[3];
    const int*   rel_ids  = (const int*)d_in[4];
    const float* temb     = (const float*)d_in[5];
    const float* remb     = (const float*)d_in[6];
    const float* W1       = (const float*)d_in[7];
    const float* a_src1   = (const float*)d_in[8];
    const float* a_dst1   = (const float*)d_in[9];
    const float* b1       = (const float*)d_in[10];
    const float* ln1_g    = (const float*)d_in[11];
    const float* ln1_b    = (const float*)d_in[12];
    const float* W2       = (const float*)d_in[13];
    const float* a_src2   = (const float*)d_in[14];
    const float* a_dst2   = (const float*)d_in[15];
    const float* b2       = (const float*)d_in[16];
    const float* ln2_g    = (const float*)d_in[17];
    const float* ln2_b    = (const float*)d_in[18];
    const float* Wr1      = (const float*)d_in[19];
    const float* br1      = (const float*)d_in[20];
    const float* Wr2      = (const float*)d_in[21];
    const float* br2      = (const float*)d_in[22];
    float* out = (float*)d_out;

    unsigned short* xb    = (unsigned short*)d_ws;        // 4096*768
    unsigned short* Wt    = xb + (size_t)4096 * 768;      // 256*768
    unsigned short* Wtr   = Wt + (size_t)256 * 768;       // 256*160
    unsigned short* W2t   = Wtr + (size_t)256 * 160;      // 64*256
    unsigned short* rembb = W2t + (size_t)64 * 256;       // 512 (9*32 used)
    unsigned short* g1b   = rembb + 512;                  // 4096*256
    unsigned short* x2b   = g1b + (size_t)4096 * 256;     // 4096*64
    float* fbase = (float*)(x2b + (size_t)4096 * 64);
    float* h1    = fbase;                      // 4096*256
    float* h2    = h1 + (size_t)4096 * 256;    // 4096*64
    float* s2    = h2 + (size_t)4096 * 64;     // 4096
    float* d2    = s2 + 4096;                  // 4096
    float* basep = d2 + 4096;                  // 12*32*256

    pool_prep_kernel<<<BB * EE + 75 + 12 * 32, 256, 0, stream>>>(
        seq, starts, types, temb, xb, W1, Wt, Wr1, Wtr, W2, W2t, remb, rembb, basep);
    gemm1_mfma_kernel<<<dim3(4, 64), 256, 0, stream>>>(xb, Wt, h1);
    gat1_fused_kernel<<<BB, 256, 0, stream>>>(h1, a_src1, a_dst1, b1, ln1_g, ln1_b, g1b);
    gemm2_mfma_kernel<<<64, 256, 0, stream>>>(g1b, W2t, a_src2, a_dst2, h2, s2, d2);
    gat2_fused_kernel<<<BB, 256, 0, stream>>>(h2, s2, d2, b2, ln2_g, ln2_b, x2b);
    score_mfma_kernel<<<BB * PP / 64, 256, 0, stream>>>(x2b, basep, br1, pair_idx,
                                                        rel_ids, rembb, Wtr, Wr2,
                                                        br2, out);
}

// Round 10
// 242.261 us; speedup vs baseline: 1.8292x; 1.0357x over previous
//
#include <hip/hip_runtime.h>
#include <hip/hip_bf16.h>

#define BB 32
#define SS 1024
#define HHH 768
#define EE 128
#define WW 8
#define PP 512
#define RDD 32

typedef __attribute__((ext_vector_type(8))) short bf16x8;
typedef __attribute__((ext_vector_type(8))) unsigned short us8;
typedef __attribute__((ext_vector_type(4))) unsigned short us4;
typedef __attribute__((ext_vector_type(4))) float f32x4;

__device__ __forceinline__ unsigned short f2bf(float v) {
    __hip_bfloat16 h = __float2bfloat16(v);
    return *(unsigned short*)&h;
}
__device__ __forceinline__ float bf2f(unsigned short u) {
    unsigned int x = ((unsigned int)u) << 16;
    float f; __builtin_memcpy(&f, &x, 4);
    return f;
}

// ---------------------------------------------------------------------------
// K1: merged pool + prep (unchanged from round 9).
// ---------------------------------------------------------------------------
__global__ __launch_bounds__(256) void pool_prep_kernel(
    const float* __restrict__ seq, const int* __restrict__ starts,
    const int* __restrict__ types, const float* __restrict__ temb,
    unsigned short* __restrict__ xout,
    const float* __restrict__ W1, unsigned short* __restrict__ Wt,
    const float* __restrict__ Wr1, unsigned short* __restrict__ Wtr,
    const float* __restrict__ W2, unsigned short* __restrict__ W2t,
    const float* __restrict__ remb, unsigned short* __restrict__ rembb,
    float* __restrict__ basep) {
    int tid = threadIdx.x;
    __shared__ float sbuf[WW * HHH];
    __shared__ float scred[WW];
    __shared__ float attn_s[WW];

    if (blockIdx.x < BB * EE) {
        int be = blockIdx.x;
        int b = be >> 7;
        int start = starts[be];
        const float4* bp4 = (const float4*)(seq + ((size_t)b * SS + start) * HHH);
        for (int idx = tid; idx < WW * (HHH / 4); idx += 256) {
            int w = idx / (HHH / 4), h4 = idx % (HHH / 4);
            float4 v = bp4[(size_t)w * (HHH / 4) + h4];
            sbuf[w * HHH + h4 * 4 + 0] = v.x; sbuf[w * HHH + h4 * 4 + 1] = v.y;
            sbuf[w * HHH + h4 * 4 + 2] = v.z; sbuf[w * HHH + h4 * 4 + 3] = v.w;
        }
        __syncthreads();

        float sc[WW];
#pragma unroll
        for (int w = 0; w < WW; w++) sc[w] = 0.f;
#pragma unroll
        for (int c = 0; c < 3; c++) {
            int h = tid + 256 * c;
            float s = 0.f;
#pragma unroll
            for (int w = 0; w < WW; w++) s += sbuf[w * HHH + h];
            float m = s * (1.0f / WW);
#pragma unroll
            for (int w = 0; w < WW; w++) sc[w] += sbuf[w * HHH + h] * m;
        }
        if (tid < WW) scred[tid] = 0.f;
        __syncthreads();
        int lane = tid & 63;
#pragma unroll
        for (int w = 0; w < WW; w++) {
            float v = sc[w];
            for (int o = 32; o > 0; o >>= 1) v += __shfl_down(v, o, 64);
            if (lane == 0) atomicAdd(&scred[w], v);
        }
        __syncthreads();
        if (tid == 0) {
            float mx = scred[0];
            for (int w = 1; w < WW; w++) mx = fmaxf(mx, scred[w]);
            float ssum = 0.f;
            float a[WW];
            for (int w = 0; w < WW; w++) { a[w] = __expf(scred[w] - mx); ssum += a[w]; }
            float inv = 1.f / ssum;
            for (int w = 0; w < WW; w++) attn_s[w] = a[w] * inv;
        }
        __syncthreads();

        int t = types[be];
        const float* emb = temb + (size_t)t * HHH;
#pragma unroll
        for (int c = 0; c < 3; c++) {
            int h = tid + 256 * c;
            float p = 0.f;
#pragma unroll
            for (int w = 0; w < WW; w++) p += attn_s[w] * sbuf[w * HHH + h];
            xout[(size_t)be * HHH + h] = f2bf(p + emb[h]);
        }
        return;
    }

    int blk = blockIdx.x - BB * EE;
    if (blk < 48) {
        int k0 = blk * 16;
        for (int i = tid; i < 16 * 256; i += 256)
            sbuf[i] = W1[(size_t)(k0 + (i >> 8)) * 256 + (i & 255)];
        __syncthreads();
        int n = tid;
        us8 v0, v1;
#pragma unroll
        for (int kk = 0; kk < 8; kk++) v0[kk] = f2bf(sbuf[kk * 256 + n]);
#pragma unroll
        for (int kk = 0; kk < 8; kk++) v1[kk] = f2bf(sbuf[(8 + kk) * 256 + n]);
        *(us8*)(Wt + (size_t)n * HHH + k0) = v0;
        *(us8*)(Wt + (size_t)n * HHH + k0 + 8) = v1;
    } else if (blk < 58) {
        int k0 = (blk - 48) * 16;
        for (int i = tid; i < 16 * 256; i += 256)
            sbuf[i] = Wr1[(size_t)(k0 + (i >> 8)) * 256 + (i & 255)];
        __syncthreads();
        int n = tid;
        us8 v0, v1;
#pragma unroll
        for (int kk = 0; kk < 8; kk++) v0[kk] = f2bf(sbuf[kk * 256 + n]);
#pragma unroll
        for (int kk = 0; kk < 8; kk++) v1[kk] = f2bf(sbuf[(8 + kk) * 256 + n]);
        *(us8*)(Wtr + (size_t)n * 160 + k0) = v0;
        *(us8*)(Wtr + (size_t)n * 160 + k0 + 8) = v1;
    } else if (blk < 74) {
        int k0 = (blk - 58) * 16;
        for (int i = tid; i < 16 * 64; i += 256)
            sbuf[(i >> 6) * 64 + (i & 63)] = W2[(size_t)(k0 + (i >> 6)) * 64 + (i & 63)];
        __syncthreads();
        if (tid < 64) {
            int n = tid;
            us8 v0, v1;
#pragma unroll
            for (int kk = 0; kk < 8; kk++) v0[kk] = f2bf(sbuf[kk * 64 + n]);
#pragma unroll
            for (int kk = 0; kk < 8; kk++) v1[kk] = f2bf(sbuf[(8 + kk) * 64 + n]);
            *(us8*)(W2t + (size_t)n * 256 + k0) = v0;
            *(us8*)(W2t + (size_t)n * 256 + k0 + 8) = v1;
        }
    } else if (blk == 74) {
        for (int i = tid; i < 9 * RDD; i += 256) rembb[i] = f2bf(remb[i]);
    } else {
        int pc = blk - 75;
        int kc = pc % 12;
        int b = pc / 12;
        int n = tid;
        if (n < 64) sbuf[4096 + n] = seq[(size_t)b * SS * HHH + kc * 64 + n];
        __syncthreads();
        float acc = 0.f;
        const float* w = Wr1 + (size_t)(160 + kc * 64) * 256 + n;
#pragma unroll 16
        for (int k = 0; k < 64; k++) acc += sbuf[4096 + k] * w[(size_t)k * 256];
        basep[((size_t)kc * 32 + b) * 256 + n] = acc;
    }
}

// ---------------------------------------------------------------------------
// K2: GEMM1 via MFMA bf16. Xb(4096x768) @ Wt^T -> h1(4096x256 fp32).
// ---------------------------------------------------------------------------
__global__ __launch_bounds__(256) void gemm1_mfma_kernel(
    const unsigned short* __restrict__ Xb, const unsigned short* __restrict__ Wt,
    float* __restrict__ C) {
    const int K = HHH;
    int n0 = blockIdx.x * 64;
    int m0 = blockIdx.y * 64;
    int tid = threadIdx.x;
    int wave = tid >> 6, lane = tid & 63;
    int wm = (wave >> 1) * 32, wn = (wave & 1) * 32;

    __shared__ __align__(16) unsigned short As[64][40];
    __shared__ __align__(16) unsigned short Bs[64][40];

    f32x4 acc[2][2] = {};
    int ar = tid >> 2;
    int ac = (tid & 3) * 8;
    int fr = lane & 15;
    int fk = (lane >> 4) * 8;

    for (int k0 = 0; k0 < K; k0 += 32) {
        us8 av = *(const us8*)(Xb + (size_t)(m0 + ar) * K + k0 + ac);
        us8 bv = *(const us8*)(Wt + (size_t)(n0 + ar) * K + k0 + ac);
        *(us8*)(&As[ar][ac]) = av;
        *(us8*)(&Bs[ar][ac]) = bv;
        __syncthreads();

        bf16x8 a0 = *(const bf16x8*)(&As[wm + fr][fk]);
        bf16x8 a1 = *(const bf16x8*)(&As[wm + 16 + fr][fk]);
        bf16x8 b0 = *(const bf16x8*)(&Bs[wn + fr][fk]);
        bf16x8 b1 = *(const bf16x8*)(&Bs[wn + 16 + fr][fk]);

        acc[0][0] = __builtin_amdgcn_mfma_f32_16x16x32_bf16(a0, b0, acc[0][0], 0, 0, 0);
        acc[0][1] = __builtin_amdgcn_mfma_f32_16x16x32_bf16(a0, b1, acc[0][1], 0, 0, 0);
        acc[1][0] = __builtin_amdgcn_mfma_f32_16x16x32_bf16(a1, b0, acc[1][0], 0, 0, 0);
        acc[1][1] = __builtin_amdgcn_mfma_f32_16x16x32_bf16(a1, b1, acc[1][1], 0, 0, 0);
        __syncthreads();
    }

    int crow = (lane >> 4) * 4;
    int ccol = lane & 15;
#pragma unroll
    for (int mi = 0; mi < 2; mi++)
#pragma unroll
        for (int ni = 0; ni < 2; ni++)
#pragma unroll
            for (int r = 0; r < 4; r++)
                C[(size_t)(m0 + wm + mi * 16 + crow + r) * 256 +
                  n0 + wn + ni * 16 + ccol] = acc[mi][ni][r];
}

// ---------------------------------------------------------------------------
// K3: per-(b,e,head) src/dst dots over D1=128 from fp32 h1 (coalesced).
// grid = B*E*2 blocks of 64 threads.
// ---------------------------------------------------------------------------
__global__ void sd1_kernel(const float* __restrict__ h1, const float* __restrict__ asrc,
                           const float* __restrict__ adst, float* __restrict__ s1,
                           float* __restrict__ d1) {
    int beh = blockIdx.x;
    int h = beh & 1;
    int be = beh >> 1;
    int lane = threadIdx.x;
    const float* row = h1 + (size_t)be * 256 + h * 128;
    float v0 = row[lane], v1 = row[lane + 64];
    float ss = v0 * asrc[h * 128 + lane] + v1 * asrc[h * 128 + lane + 64];
    float dd = v0 * adst[h * 128 + lane] + v1 * adst[h * 128 + lane + 64];
    for (int o = 32; o > 0; o >>= 1) {
        ss += __shfl_down(ss, o, 64);
        dd += __shfl_down(dd, o, 64);
    }
    if (lane == 0) { s1[beh] = ss; d1[beh] = dd; }
}

// ---------------------------------------------------------------------------
// K4: GAT1 fused, grid = 32 b x 4 i-chunks = 128 blocks. Each wave owns one
// (head, m-frag): softmax in A-frag regs, 32 MFMAs. LN(256) via cross-wave
// sum/sumsq combine in LDS. -> g1b bf16.
// ---------------------------------------------------------------------------
__global__ __launch_bounds__(256) void gat1_fused_kernel(
    const float* __restrict__ h1, const float* __restrict__ s1,
    const float* __restrict__ d1, const float* __restrict__ b1,
    const float* __restrict__ gamma, const float* __restrict__ beta,
    unsigned short* __restrict__ g1b) {
    int b = blockIdx.x >> 2;
    int c = blockIdx.x & 3;            // i-chunk of 32 rows
    int tid = threadIdx.x;
    int wave = tid >> 6, lane = tid & 63;
    int h = wave >> 1, m = wave & 1;
    int fr = lane & 15;
    int fk = (lane >> 4) * 8;

    __shared__ __align__(16) unsigned short h1T[2][128][136];  // [h][d][j]
    __shared__ float ssh[2][128];
    __shared__ float dsh[2][128];
    __shared__ float lnred[32][2][2];   // [row][h][sum,sumsq]

    // stage full slab (coalesced f4 reads, transposed bf16 LDS writes)
    {
        const float4* src4 = (const float4*)(h1 + (size_t)b * 128 * 256);
        for (int it = 0; it < 32; it++) {
            int i4 = tid + it * 256;
            int j = i4 >> 6;
            int c4 = i4 & 63;
            float4 v = src4[(size_t)j * 64 + c4];
            int d = c4 * 4;
            int hh = d >> 7, dl = d & 127;
            h1T[hh][dl + 0][j] = f2bf(v.x);
            h1T[hh][dl + 1][j] = f2bf(v.y);
            h1T[hh][dl + 2][j] = f2bf(v.z);
            h1T[hh][dl + 3][j] = f2bf(v.w);
        }
        int hh = tid >> 7, j = tid & 127;
        ssh[hh][j] = s1[((size_t)b * 128 + j) * 2 + hh];
        dsh[hh][j] = d1[((size_t)b * 128 + j) * 2 + hh];
    }
    __syncthreads();

    // softmax for rows i = c*32 + m*16 + fr, head h
    bf16x8 afrag[4];
    {
        float dd = dsh[h][c * 32 + m * 16 + fr];
        float ev[4][8];
        float mx = -1e30f;
#pragma unroll
        for (int ks = 0; ks < 4; ks++)
#pragma unroll
            for (int jj = 0; jj < 8; jj++) {
                float e = dd + ssh[h][ks * 32 + fk + jj];
                e = e >= 0.f ? e : 0.2f * e;
                ev[ks][jj] = e;
                mx = fmaxf(mx, e);
            }
        mx = fmaxf(mx, __shfl_xor(mx, 16, 64));
        mx = fmaxf(mx, __shfl_xor(mx, 32, 64));
        float sm = 0.f;
#pragma unroll
        for (int ks = 0; ks < 4; ks++)
#pragma unroll
            for (int jj = 0; jj < 8; jj++) {
                float e = __expf(ev[ks][jj] - mx);
                ev[ks][jj] = e;
                sm += e;
            }
        sm += __shfl_xor(sm, 16, 64);
        sm += __shfl_xor(sm, 32, 64);
        float inv = 1.f / sm;
#pragma unroll
        for (int ks = 0; ks < 4; ks++) {
            bf16x8 a;
#pragma unroll
            for (int jj = 0; jj < 8; jj++)
                a[jj] = (short)f2bf(ev[ks][jj] * inv);
            afrag[ks] = a;
        }
    }

    // PV MFMA: o[16 rows][128 d of head h] = 8 n-frags
    f32x4 acc[8] = {};
#pragma unroll
    for (int ks = 0; ks < 4; ks++)
#pragma unroll
        for (int ni = 0; ni < 8; ni++) {
            bf16x8 bv = *(const bf16x8*)(&h1T[h][ni * 16 + fr][ks * 32 + fk]);
            acc[ni] = __builtin_amdgcn_mfma_f32_16x16x32_bf16(
                afrag[ks], bv, acc[ni], 0, 0, 0);
        }

    // epilogue: bias, cross-wave LN(256), ELU
    int crow = (lane >> 4) * 4;
    int ccol = lane & 15;
    float bv_[8], gv[8], bev[8];
#pragma unroll
    for (int ni = 0; ni < 8; ni++) {
        int d = h * 128 + ni * 16 + ccol;
        bv_[ni] = b1[d]; gv[ni] = gamma[d]; bev[ni] = beta[d];
    }
    float vv[4][8];
#pragma unroll
    for (int r = 0; r < 4; r++) {
        float s = 0.f, q = 0.f;
#pragma unroll
        for (int ni = 0; ni < 8; ni++) {
            float v = acc[ni][r] + bv_[ni];
            vv[r][ni] = v;
            s += v;
            q += v * v;
        }
        s += __shfl_xor(s, 1, 64); s += __shfl_xor(s, 2, 64);
        s += __shfl_xor(s, 4, 64); s += __shfl_xor(s, 8, 64);
        q += __shfl_xor(q, 1, 64); q += __shfl_xor(q, 2, 64);
        q += __shfl_xor(q, 4, 64); q += __shfl_xor(q, 8, 64);
        if ((lane & 15) == 0) {
            lnred[m * 16 + crow + r][h][0] = s;
            lnred[m * 16 + crow + r][h][1] = q;
        }
    }
    __syncthreads();
#pragma unroll
    for (int r = 0; r < 4; r++) {
        int row = m * 16 + crow + r;
        float s = lnred[row][0][0] + lnred[row][1][0];
        float q = lnred[row][0][1] + lnred[row][1][1];
        float mean = s * (1.f / 256.f);
        float var = q * (1.f / 256.f) - mean * mean;
        float rs = rsqrtf(var + 1e-5f);
        unsigned short* dst = g1b + (size_t)(b * 128 + c * 32 + row) * 256 + h * 128;
#pragma unroll
        for (int ni = 0; ni < 8; ni++) {
            float y = (vv[r][ni] - mean) * rs * gv[ni] + bev[ni];
            y = y > 0.f ? y : (__expf(y) - 1.f);
            dst[ni * 16 + ccol] = f2bf(y);
        }
    }
}

// ---------------------------------------------------------------------------
// K5: GEMM2 via MFMA + fused sd2 dots. g1b(4096x256)@W2t^T -> h2 fp32.
// ---------------------------------------------------------------------------
__global__ __launch_bounds__(256) void gemm2_mfma_kernel(
    const unsigned short* __restrict__ g1b, const unsigned short* __restrict__ W2t,
    const float* __restrict__ asrc, const float* __restrict__ adst,
    float* __restrict__ h2, float* __restrict__ s2, float* __restrict__ d2) {
    int m0 = blockIdx.x * 64;
    int tid = threadIdx.x;
    int wave = tid >> 6, lane = tid & 63;
    int wm = (wave >> 1) * 32, wn = (wave & 1) * 32;

    __shared__ __align__(16) unsigned short As[64][72];
    __shared__ __align__(16) unsigned short Bs[64][72];
    __shared__ float sdred[64][2][2];

    f32x4 acc[2][2] = {};
    int fr = lane & 15;
    int fk = (lane >> 4) * 8;

    for (int kc = 0; kc < 4; kc++) {
        for (int it = 0; it < 2; it++) {
            int i = tid + it * 256;
            int row = i >> 3, c = i & 7;
            *(us8*)(&As[row][c * 8]) =
                *(const us8*)(g1b + (size_t)(m0 + row) * 256 + kc * 64 + c * 8);
            *(us8*)(&Bs[row][c * 8]) =
                *(const us8*)(W2t + (size_t)row * 256 + kc * 64 + c * 8);
        }
        __syncthreads();
#pragma unroll
        for (int ks = 0; ks < 2; ks++) {
            int kb = ks * 32 + fk;
            bf16x8 a0 = *(const bf16x8*)(&As[wm + fr][kb]);
            bf16x8 a1 = *(const bf16x8*)(&As[wm + 16 + fr][kb]);
            bf16x8 b0 = *(const bf16x8*)(&Bs[wn + fr][kb]);
            bf16x8 b1 = *(const bf16x8*)(&Bs[wn + 16 + fr][kb]);
            acc[0][0] = __builtin_amdgcn_mfma_f32_16x16x32_bf16(a0, b0, acc[0][0], 0, 0, 0);
            acc[0][1] = __builtin_amdgcn_mfma_f32_16x16x32_bf16(a0, b1, acc[0][1], 0, 0, 0);
            acc[1][0] = __builtin_amdgcn_mfma_f32_16x16x32_bf16(a1, b0, acc[1][0], 0, 0, 0);
            acc[1][1] = __builtin_amdgcn_mfma_f32_16x16x32_bf16(a1, b1, acc[1][1], 0, 0, 0);
        }
        __syncthreads();
    }

    int crow = (lane >> 4) * 4;
    int ccol = lane & 15;
    float asv[2], adv[2];
#pragma unroll
    for (int ni = 0; ni < 2; ni++) {
        int n = wn + ni * 16 + ccol;
        asv[ni] = asrc[n];
        adv[ni] = adst[n];
    }
#pragma unroll
    for (int mi = 0; mi < 2; mi++) {
#pragma unroll
        for (int r = 0; r < 4; r++) {
            float sp = 0.f, dp = 0.f;
#pragma unroll
            for (int ni = 0; ni < 2; ni++) {
                float v = acc[mi][ni][r];
                h2[(size_t)(m0 + wm + mi * 16 + crow + r) * 64 +
                   wn + ni * 16 + ccol] = v;
                sp += v * asv[ni];
                dp += v * adv[ni];
            }
            for (int msk = 1; msk < 16; msk <<= 1) {
                sp += __shfl_xor(sp, msk, 64);
                dp += __shfl_xor(dp, msk, 64);
            }
            if ((lane & 15) == 0) {
                int row = wm + mi * 16 + crow + r;
                sdred[row][wn >> 5][0] = sp;
                sdred[row][wn >> 5][1] = dp;
            }
        }
    }
    __syncthreads();
    if (tid < 64 && wave == 0) {
        s2[m0 + tid] = sdred[tid][0][0] + sdred[tid][1][0];
        d2[m0 + tid] = sdred[tid][0][1] + sdred[tid][1][1];
    }
}

// ---------------------------------------------------------------------------
// K6: GAT2 fused, grid = 32 b x 2 i-chunks = 64 blocks. One m-frag per wave,
// wave-local LN(64) + ELU -> x2b bf16.
// ---------------------------------------------------------------------------
__global__ __launch_bounds__(256) void gat2_fused_kernel(
    const float* __restrict__ h2, const float* __restrict__ s2,
    const float* __restrict__ d2, const float* __restrict__ b2v,
    const float* __restrict__ gamma, const float* __restrict__ beta,
    unsigned short* __restrict__ x2b) {
    int b = blockIdx.x >> 1;
    int c = blockIdx.x & 1;            // i-chunk of 64 rows
    int tid = threadIdx.x;
    int wave = tid >> 6, lane = tid & 63;
    int fr = lane & 15;
    int fk = (lane >> 4) * 8;

    __shared__ __align__(16) unsigned short h2T[64][136];  // [d][j]
    __shared__ float ssh[128];
    __shared__ float dsh[128];

    {
        const float4* src4 = (const float4*)(h2 + (size_t)b * 128 * 64);
        for (int it = 0; it < 8; it++) {
            int i4 = tid + it * 256;
            int j = i4 >> 4;
            int c4 = i4 & 15;
            float4 v = src4[(size_t)j * 16 + c4];
            int d = c4 * 4;
            h2T[d + 0][j] = f2bf(v.x);
            h2T[d + 1][j] = f2bf(v.y);
            h2T[d + 2][j] = f2bf(v.z);
            h2T[d + 3][j] = f2bf(v.w);
        }
        if (tid < 128) ssh[tid] = s2[(size_t)b * 128 + tid];
        else dsh[tid - 128] = d2[(size_t)b * 128 + (tid - 128)];
    }
    __syncthreads();

    // softmax for rows i = c*64 + wave*16 + fr
    bf16x8 afrag[4];
    {
        float dd = dsh[c * 64 + wave * 16 + fr];
        float ev[4][8];
        float mx = -1e30f;
#pragma unroll
        for (int ks = 0; ks < 4; ks++)
#pragma unroll
            for (int jj = 0; jj < 8; jj++) {
                float e = dd + ssh[ks * 32 + fk + jj];
                e = e >= 0.f ? e : 0.2f * e;
                ev[ks][jj] = e;
                mx = fmaxf(mx, e);
            }
        mx = fmaxf(mx, __shfl_xor(mx, 16, 64));
        mx = fmaxf(mx, __shfl_xor(mx, 32, 64));
        float sm = 0.f;
#pragma unroll
        for (int ks = 0; ks < 4; ks++)
#pragma unroll
            for (int jj = 0; jj < 8; jj++) {
                float e = __expf(ev[ks][jj] - mx);
                ev[ks][jj] = e;
                sm += e;
            }
        sm += __shfl_xor(sm, 16, 64);
        sm += __shfl_xor(sm, 32, 64);
        float inv = 1.f / sm;
#pragma unroll
        for (int ks = 0; ks < 4; ks++) {
            bf16x8 a;
#pragma unroll
            for (int jj = 0; jj < 8; jj++)
                a[jj] = (short)f2bf(ev[ks][jj] * inv);
            afrag[ks] = a;
        }
    }

    f32x4 acc[4] = {};
#pragma unroll
    for (int ks = 0; ks < 4; ks++)
#pragma unroll
        for (int ni = 0; ni < 4; ni++) {
            bf16x8 bv = *(const bf16x8*)(&h2T[ni * 16 + fr][ks * 32 + fk]);
            acc[ni] = __builtin_amdgcn_mfma_f32_16x16x32_bf16(
                afrag[ks], bv, acc[ni], 0, 0, 0);
        }

    int crow = (lane >> 4) * 4;
    int ccol = lane & 15;
    float bv_[4], gv[4], bev[4];
#pragma unroll
    for (int ni = 0; ni < 4; ni++) {
        int d = ni * 16 + ccol;
        bv_[ni] = b2v[d]; gv[ni] = gamma[d]; bev[ni] = beta[d];
    }
#pragma unroll
    for (int r = 0; r < 4; r++) {
        float v[4];
        float s = 0.f;
#pragma unroll
        for (int ni = 0; ni < 4; ni++) {
            v[ni] = acc[ni][r] + bv_[ni];
            s += v[ni];
        }
        s += __shfl_xor(s, 1, 64); s += __shfl_xor(s, 2, 64);
        s += __shfl_xor(s, 4, 64); s += __shfl_xor(s, 8, 64);
        float mean = s * (1.f / 64.f);
        float sq = 0.f;
#pragma unroll
        for (int ni = 0; ni < 4; ni++) {
            float dv = v[ni] - mean;
            sq += dv * dv;
        }
        sq += __shfl_xor(sq, 1, 64); sq += __shfl_xor(sq, 2, 64);
        sq += __shfl_xor(sq, 4, 64); sq += __shfl_xor(sq, 8, 64);
        float rs = rsqrtf(sq * (1.f / 64.f) + 1e-5f);
        int i = c * 64 + wave * 16 + crow + r;
        unsigned short* dst = x2b + (size_t)(b * 128 + i) * 64;
#pragma unroll
        for (int ni = 0; ni < 4; ni++) {
            float y = (v[ni] - mean) * rs * gv[ni] + bev[ni];
            y = y > 0.f ? y : (__expf(y) - 1.f);
            dst[ni * 16 + ccol] = f2bf(y);
        }
    }
}

// ---------------------------------------------------------------------------
// K7: scores via MFMA. 64 pairs per block, N=256, K=160.
// ---------------------------------------------------------------------------
__global__ __launch_bounds__(256) void score_mfma_kernel(
    const unsigned short* __restrict__ x2b, const float* __restrict__ basep,
    const float* __restrict__ br1,
    const int* __restrict__ pair_idx, const int* __restrict__ rel_ids,
    const unsigned short* __restrict__ rembb, const unsigned short* __restrict__ Wtr,
    const float* __restrict__ Wr2, const float* __restrict__ br2,
    float* __restrict__ out) {
    int blk = blockIdx.x;
    int b = blk >> 3;
    int p0 = (blk & 7) * 64;
    int tid = threadIdx.x;
    int wave = tid >> 6, lane = tid & 63;
    int wn = wave * 64;

    __shared__ __align__(16) unsigned short As[64][168];
    __shared__ __align__(16) unsigned short Bs[256][40];
    __shared__ float sred[64][4];
    __shared__ int prs[64][3];

    if (tid < 64) {
        int p = p0 + tid;
        prs[tid][0] = pair_idx[((size_t)b * PP + p) * 2 + 0];
        prs[tid][1] = pair_idx[((size_t)b * PP + p) * 2 + 1];
        prs[tid][2] = rel_ids[(size_t)b * PP + p];
    }
    __syncthreads();
    for (int it = 0; it < 10; it++) {
        int idx = tid + it * 256;
        int m = idx / 40, c = idx % 40;
        int k0 = c * 4;
        us4 v;
        if (k0 < 64)
            v = *(const us4*)(x2b + ((size_t)b * EE + prs[m][0]) * 64 + k0);
        else if (k0 < 128)
            v = *(const us4*)(x2b + ((size_t)b * EE + prs[m][1]) * 64 + (k0 - 64));
        else
            v = *(const us4*)(rembb + prs[m][2] * RDD + (k0 - 128));
        *(us4*)(&As[m][k0]) = v;
    }

    f32x4 acc[4][4] = {};
    int fr = lane & 15;
    int fk = (lane >> 4) * 8;

    for (int kc = 0; kc < 5; kc++) {
        for (int it = 0; it < 4; it++) {
            int i = tid + it * 256;
            int n = i >> 2, c = i & 3;
            *(us8*)(&Bs[n][c * 8]) =
                *(const us8*)(Wtr + (size_t)n * 160 + kc * 32 + c * 8);
        }
        __syncthreads();
        bf16x8 a[4], bv[4];
#pragma unroll
        for (int mi = 0; mi < 4; mi++)
            a[mi] = *(const bf16x8*)(&As[mi * 16 + fr][kc * 32 + fk]);
#pragma unroll
        for (int ni = 0; ni < 4; ni++)
            bv[ni] = *(const bf16x8*)(&Bs[wn + ni * 16 + fr][fk]);
#pragma unroll
        for (int mi = 0; mi < 4; mi++)
#pragma unroll
            for (int ni = 0; ni < 4; ni++)
                acc[mi][ni] = __builtin_amdgcn_mfma_f32_16x16x32_bf16(
                    a[mi], bv[ni], acc[mi][ni], 0, 0, 0);
        __syncthreads();
    }

    int crow = (lane >> 4) * 4;
    int ccol = lane & 15;
    float basev[4], w2v[4];
#pragma unroll
    for (int ni = 0; ni < 4; ni++) {
        int n = wn + ni * 16 + ccol;
        float bb = br1[n];
#pragma unroll
        for (int kc = 0; kc < 12; kc++)
            bb += basep[((size_t)kc * 32 + b) * 256 + n];
        basev[ni] = bb;
        w2v[ni] = Wr2[n];
    }
#pragma unroll
    for (int mi = 0; mi < 4; mi++) {
#pragma unroll
        for (int r = 0; r < 4; r++) {
            float p = 0.f;
#pragma unroll
            for (int ni = 0; ni < 4; ni++)
                p += fmaxf(acc[mi][ni][r] + basev[ni], 0.f) * w2v[ni];
            for (int msk = 1; msk < 16; msk <<= 1)
                p += __shfl_xor(p, msk, 64);
            if ((lane & 15) == 0)
                sred[mi * 16 + crow + r][wave] = p;
        }
    }
    __syncthreads();
    if (tid < 64) {
        float s = sred[tid][0] + sred[tid][1] + sred[tid][2] + sred[tid][3] + br2[0];
        out[(size_t)b * PP + p0 + tid] = s;
    }
}

// ---------------------------------------------------------------------------
extern "C" void kernel_launch(void* const* d_in, const int* in_sizes, int n_in,
                              void* d_out, int out_size, void* d_ws, size_t ws_size,
                              hipStream_t stream) {
    (void)in_sizes; (void)n_in; (void)out_size; (void)ws_size;
    const float* seq      = (const float*)d_in[0];
    const int*   starts   = (const int*)d_in[1];
    const int*   types    = (const int*)d_in[2];
    const int*   pair_idx = (const int*)d_in[3];
    const int*   rel_ids  = (const int*)d_in[4];
    const float* temb     = (const float*)d_in[5];
    const float* remb     = (const float*)d_in[6];
    const float* W1       = (const float*)d_in[7];
    const float* a_src1   = (const float*)d_in[8];
    const float* a_dst1   = (const float*)d_in[9];
    const float* b1       = (const float*)d_in[10];
    const float* ln1_g    = (const float*)d_in[11];
    const float* ln1_b    = (const float*)d_in[12];
    const float* W2       = (const float*)d_in[13];
    const float* a_src2   = (const float*)d_in[14];
    const float* a_dst2   = (const float*)d_in[15];
    const float* b2       = (const float*)d_in[16];
    const float* ln2_g    = (const float*)d_in[17];
    const float* ln2_b    = (const float*)d_in[18];
    const float* Wr1      = (const float*)d_in[19];
    const float* br1      = (const float*)d_in[20];
    const float* Wr2      = (const float*)d_in[21];
    const float* br2      = (const float*)d_in[22];
    float* out = (float*)d_out;

    unsigned short* xb    = (unsigned short*)d_ws;        // 4096*768
    unsigned short* Wt    = xb + (size_t)4096 * 768;      // 256*768
    unsigned short* Wtr   = Wt + (size_t)256 * 768;       // 256*160
    unsigned short* W2t   = Wtr + (size_t)256 * 160;      // 64*256
    unsigned short* rembb = W2t + (size_t)64 * 256;       // 512
    unsigned short* g1b   = rembb + 512;                  // 4096*256
    unsigned short* x2b   = g1b + (size_t)4096 * 256;     // 4096*64
    float* fbase = (float*)(x2b + (size_t)4096 * 64);
    float* h1    = fbase;                      // 4096*256
    float* s1    = h1 + (size_t)4096 * 256;    // 8192
    float* d1    = s1 + 8192;                  // 8192
    float* h2    = d1 + 8192;                  // 4096*64
    float* s2    = h2 + (size_t)4096 * 64;     // 4096
    float* d2    = s2 + 4096;                  // 4096
    float* basep = d2 + 4096;                  // 12*32*256

    pool_prep_kernel<<<BB * EE + 75 + 12 * 32, 256, 0, stream>>>(
        seq, starts, types, temb, xb, W1, Wt, Wr1, Wtr, W2, W2t, remb, rembb, basep);
    gemm1_mfma_kernel<<<dim3(4, 64), 256, 0, stream>>>(xb, Wt, h1);
    sd1_kernel<<<BB * EE * 2, 64, 0, stream>>>(h1, a_src1, a_dst1, s1, d1);
    gat1_fused_kernel<<<BB * 4, 256, 0, stream>>>(h1, s1, d1, b1, ln1_g, ln1_b, g1b);
    gemm2_mfma_kernel<<<64, 256, 0, stream>>>(g1b, W2t, a_src2, a_dst2, h2, s2, d2);
    gat2_fused_kernel<<<BB * 2, 256, 0, stream>>>(h2, s2, d2, b2, ln2_g, ln2_b, x2b);
    score_mfma_kernel<<<BB * PP / 64, 256, 0, stream>>>(x2b, basep, br1, pair_idx,
                                                        rel_ids, rembb, Wtr, Wr2,
                                                        br2, out);
}